// Round 2
// baseline (4275.529 us; speedup 1.0000x reference)
//
#include <hip/hip_runtime.h>
#include <stdint.h>

// ---------------- helpers ----------------
__device__ __forceinline__ float sigm(float x) { return 1.0f / (1.0f + expf(-x)); }
__device__ __forceinline__ float silu(float x) { return x / (1.0f + expf(-x)); }

// spherical bessel j_l, matches reference _jl
__device__ __forceinline__ float jl_eval(int l, float x) {
  float s, c;
  sincosf(x, &s, &c);
  float ix = 1.0f / x, ix2 = ix * ix;
  if (l == 0) return s * ix;
  if (l == 1) return s * ix2 - c * ix;
  if (l == 2) return (3.0f * ix2 * ix - ix) * s - 3.0f * ix2 * c;
  return (15.0f * ix2 * ix2 - 6.0f * ix2) * s - (15.0f * ix2 * ix - ix) * c;
}

// ---------------- init / geometry kernels ----------------
__global__ void node_init_kernel(const int* __restrict__ nt, const float* __restrict__ emb,
                                 float* __restrict__ nf, int N) {
  int i = blockIdx.x * 256 + threadIdx.x;
  if (i >= N * 128) return;
  int n = i >> 7, c = i & 127;
  nf[i] = emb[nt[n] * 128 + c];
}

__global__ void edge_geom_kernel(const float* __restrict__ pos, const int* __restrict__ src,
                                 const int* __restrict__ dst, float* __restrict__ bvec,
                                 float* __restrict__ bdist, float* __restrict__ rbf,
                                 float* __restrict__ cut3, int E) {
  int e = blockIdx.x * 256 + threadIdx.x;
  if (e >= E) return;
  int s = src[e], d = dst[e];
  float dx = pos[d * 3 + 0] - pos[s * 3 + 0];
  float dy = pos[d * 3 + 1] - pos[s * 3 + 1];
  float dz = pos[d * 3 + 2] - pos[s * 3 + 2];
  float r = sqrtf(dx * dx + dy * dy + dz * dz + 1e-12f);
  bvec[e * 3 + 0] = dx; bvec[e * 3 + 1] = dy; bvec[e * 3 + 2] = dz;
  bdist[e] = r;
  const float roots[3][3] = {
      {3.141592653589793f, 6.283185307179586f, 9.42477796076938f},
      {4.493409457909064f, 7.725251836937707f, 10.904121659428899f},
      {5.763459196894550f, 9.095011330476355f, 12.322940970566582f}};
#pragma unroll
  for (int l = 0; l < 3; ++l) {
#pragma unroll
    for (int n = 0; n < 3; ++n) {
      float root = roots[l][n];
      float x = r * (root * 0.2f);                  // r * root / CUTOFF(5)
      float norm = fabsf(jl_eval(l + 1, root));     // SBF_NORM
      rbf[e * 9 + l * 3 + n] = jl_eval(l, x) * (0.12649110640673518f / norm);
    }
  }
  float xx = r * 0.25f;  // r / TB_CUTOFF(4)
  float x3 = xx * xx * xx;
  cut3[e] = 1.0f - 6.0f * x3 * xx * xx + 15.0f * x3 * xx - 10.0f * x3;
}

__global__ void edge_emb_kernel(const float* __restrict__ rbf, const float* __restrict__ W,
                                const float* __restrict__ B, float* __restrict__ ef, int E) {
  int i = blockIdx.x * 256 + threadIdx.x;
  if (i >= E * 128) return;
  int e = i >> 7, c = i & 127;
  float acc = B[c];
#pragma unroll
  for (int d = 0; d < 9; ++d) acc += rbf[e * 9 + d] * W[d * 128 + c];
  ef[i] = silu(acc);
}

// triplet precompute: tbp[t][l*3+n] = rbf[t_dst][l*3+n] * Y_l0(cos) * cut3[i]*cut3[j]
__global__ void trip_kernel(const int* __restrict__ t_src, const int* __restrict__ t_dst,
                            const int* __restrict__ dst, const float* __restrict__ bvec,
                            const float* __restrict__ bdist, const float* __restrict__ rbf,
                            const float* __restrict__ cut3, float* __restrict__ tbp,
                            int* __restrict__ ea, int T) {
  int t = blockIdx.x * 256 + threadIdx.x;
  if (t >= T) return;
  int i = t_src[t], j = t_dst[t];
  float ax = bvec[i * 3], ay = bvec[i * 3 + 1], az = bvec[i * 3 + 2];
  float bx = bvec[j * 3], by = bvec[j * 3 + 1], bz = bvec[j * 3 + 2];
  float ct = (ax * bx + ay * by + az * bz) / (bdist[i] * bdist[j]);
  float tw = cut3[i] * cut3[j];
  float sh[3];
  sh[0] = 0.28209479177387814f * tw;
  sh[1] = 0.4886025119029199f * ct * tw;
  sh[2] = 0.31539156525252005f * (3.0f * ct * ct - 1.0f) * tw;
#pragma unroll
  for (int l = 0; l < 3; ++l)
#pragma unroll
    for (int n = 0; n < 3; ++n)
      tbp[t * 9 + l * 3 + n] = rbf[j * 9 + l * 3 + n] * sh[l];
  ea[t] = dst[j];
}

// ---------------- three-body block kernels ----------------
__global__ void atoms_kernel(const float* __restrict__ nf, const float* __restrict__ W,
                             const float* __restrict__ B, float* __restrict__ atoms, int N) {
  int i = blockIdx.x * 256 + threadIdx.x;
  if (i >= N * 9) return;
  int n = i / 9, d = i - n * 9;
  float acc = B[d];
  for (int c = 0; c < 128; ++c) acc += nf[n * 128 + c] * W[c * 9 + d];
  atoms[i] = sigm(acc);
}

__global__ void tb_scatter_kernel(const float* __restrict__ tbp, const int* __restrict__ t_src,
                                  const int* __restrict__ ea, const float* __restrict__ atoms,
                                  float* __restrict__ nb, int T) {
  int t = blockIdx.x * 256 + threadIdx.x;
  if (t >= T) return;
  int e = t_src[t], a = ea[t];
#pragma unroll
  for (int d = 0; d < 9; ++d)
    atomicAdd(&nb[e * 9 + d], tbp[t * 9 + d] * atoms[a * 9 + d]);
}

__global__ void tb_update_kernel(const float* __restrict__ nb, const float* __restrict__ W,
                                 const float* __restrict__ Wg, float* __restrict__ ef, int E) {
  int i = blockIdx.x * 256 + threadIdx.x;
  if (i >= E * 128) return;
  int e = i >> 7, c = i & 127;
  float n9[9];
#pragma unroll
  for (int d = 0; d < 9; ++d) n9[d] = nb[e * 9 + d];
  float a = 0.f, b = 0.f;
#pragma unroll
  for (int d = 0; d < 9; ++d) {
    a += n9[d] * W[d * 128 + c];
    b += n9[d] * Wg[d * 128 + c];
  }
  ef[i] += silu(a) * sigm(b);
}

// ---------------- fused gated-MLP ----------------
#define TE 16

template <int K>
__device__ __forceinline__ void gemm_frag(const float* __restrict__ inH,
                                          const float* __restrict__ inG, int ldi,
                                          const float* __restrict__ Wh,
                                          const float* __restrict__ Wg, int c0, int r0,
                                          float (&ah)[4][2], float (&ag)[4][2]) {
  for (int k = 0; k < K; k += 4) {
    float2 wh[4], wg[4];
#pragma unroll
    for (int kk = 0; kk < 4; ++kk) {
      wh[kk] = *(const float2*)(Wh + (k + kk) * 128 + c0);
      wg[kk] = *(const float2*)(Wg + (k + kk) * 128 + c0);
    }
#pragma unroll
    for (int r = 0; r < 4; ++r) {
      const float4 xh = *(const float4*)(inH + (r0 + r) * ldi + k);
      ah[r][0] = fmaf(xh.x, wh[0].x, ah[r][0]);
      ah[r][1] = fmaf(xh.x, wh[0].y, ah[r][1]);
      ah[r][0] = fmaf(xh.y, wh[1].x, ah[r][0]);
      ah[r][1] = fmaf(xh.y, wh[1].y, ah[r][1]);
      ah[r][0] = fmaf(xh.z, wh[2].x, ah[r][0]);
      ah[r][1] = fmaf(xh.z, wh[2].y, ah[r][1]);
      ah[r][0] = fmaf(xh.w, wh[3].x, ah[r][0]);
      ah[r][1] = fmaf(xh.w, wh[3].y, ah[r][1]);
      const float4 xg = *(const float4*)(inG + (r0 + r) * ldi + k);
      ag[r][0] = fmaf(xg.x, wg[0].x, ag[r][0]);
      ag[r][1] = fmaf(xg.x, wg[0].y, ag[r][1]);
      ag[r][0] = fmaf(xg.y, wg[1].x, ag[r][0]);
      ag[r][1] = fmaf(xg.y, wg[1].y, ag[r][1]);
      ag[r][0] = fmaf(xg.z, wg[2].x, ag[r][0]);
      ag[r][1] = fmaf(xg.z, wg[2].y, ag[r][1]);
      ag[r][0] = fmaf(xg.w, wg[3].x, ag[r][0]);
      ag[r][1] = fmaf(xg.w, wg[3].y, ag[r][1]);
    }
  }
}

// MODE 0: edge update  ef[e] += h*g*(rbf@wt)   (block owns its edges -> plain RMW)
// MODE 1: node update  atomicAdd(msg[dst[e]], h*g*(rbf@wt))
template <int MODE>
__global__ __launch_bounds__(256) void gmlp_kernel(
    const float* __restrict__ nf, float* __restrict__ ef, const float* __restrict__ rbf,
    const int* __restrict__ src, const int* __restrict__ dst,
    const float* __restrict__ W0, const float* __restrict__ B0,
    const float* __restrict__ W1, const float* __restrict__ B1,
    const float* __restrict__ W2, const float* __restrict__ B2,
    const float* __restrict__ G0, const float* __restrict__ Gb0,
    const float* __restrict__ G1, const float* __restrict__ Gb1,
    const float* __restrict__ G2, const float* __restrict__ Gb2,
    const float* __restrict__ WT, float* __restrict__ msg, int E) {
  __shared__ float xs[TE][384];
  __shared__ float hs[TE][128];
  __shared__ float gs[TE][128];
  __shared__ float rs[TE][12];
  __shared__ int es[TE];
  const int tid = threadIdx.x;
  const int e0 = blockIdx.x * TE;

  // gather x = [nf[src], nf[dst], ef]
  for (int r = 0; r < TE; ++r) {
    int e = e0 + r;
    int ec = e < E ? e : E - 1;
    int sn = src[ec], dn = dst[ec];
    for (int c = tid; c < 384; c += 256) {
      float v;
      if (c < 128)      v = nf[sn * 128 + c];
      else if (c < 256) v = nf[dn * 128 + (c - 128)];
      else              v = ef[ec * 128 + (c - 256)];
      xs[r][c] = v;
    }
  }
  for (int idx = tid; idx < TE * 9; idx += 256) {
    int r = idx / 9, d = idx - r * 9;
    int ec = (e0 + r) < E ? (e0 + r) : E - 1;
    rs[r][d] = rbf[ec * 9 + d];
  }
  if (tid < TE) {
    int ec = (e0 + tid) < E ? (e0 + tid) : E - 1;
    es[tid] = (MODE == 0) ? 0 : dst[ec] * 128;
  }
  __syncthreads();

  const int c0 = (tid & 63) * 2;
  const int r0 = (tid >> 6) * 4;
  float ah[4][2], ag[4][2];

  // layer 0: K=384
  {
    float2 hb = *(const float2*)(B0 + c0), gb = *(const float2*)(Gb0 + c0);
#pragma unroll
    for (int r = 0; r < 4; ++r) { ah[r][0] = hb.x; ah[r][1] = hb.y; ag[r][0] = gb.x; ag[r][1] = gb.y; }
    gemm_frag<384>(&xs[0][0], &xs[0][0], 384, W0, G0, c0, r0, ah, ag);
#pragma unroll
    for (int r = 0; r < 4; ++r) {
      hs[r0 + r][c0] = silu(ah[r][0]); hs[r0 + r][c0 + 1] = silu(ah[r][1]);
      gs[r0 + r][c0] = silu(ag[r][0]); gs[r0 + r][c0 + 1] = silu(ag[r][1]);
    }
  }
  __syncthreads();

  float* h1 = &xs[0][0];          // reuse xs as [TE][128] x2
  float* g1 = &xs[0][0] + TE * 128;

  // layer 1: K=128
  {
    float2 hb = *(const float2*)(B1 + c0), gb = *(const float2*)(Gb1 + c0);
#pragma unroll
    for (int r = 0; r < 4; ++r) { ah[r][0] = hb.x; ah[r][1] = hb.y; ag[r][0] = gb.x; ag[r][1] = gb.y; }
    gemm_frag<128>(&hs[0][0], &gs[0][0], 128, W1, G1, c0, r0, ah, ag);
    __syncthreads();  // all reads of hs/gs done before xs-space reuse is written
#pragma unroll
    for (int r = 0; r < 4; ++r) {
      h1[(r0 + r) * 128 + c0] = silu(ah[r][0]); h1[(r0 + r) * 128 + c0 + 1] = silu(ah[r][1]);
      g1[(r0 + r) * 128 + c0] = silu(ag[r][0]); g1[(r0 + r) * 128 + c0 + 1] = silu(ag[r][1]);
    }
  }
  __syncthreads();

  // layer 2: K=128 (h: silu, g: sigmoid)
  {
    float2 hb = *(const float2*)(B2 + c0), gb = *(const float2*)(Gb2 + c0);
#pragma unroll
    for (int r = 0; r < 4; ++r) { ah[r][0] = hb.x; ah[r][1] = hb.y; ag[r][0] = gb.x; ag[r][1] = gb.y; }
    gemm_frag<128>(h1, g1, 128, W2, G2, c0, r0, ah, ag);
  }

  // epilogue: out = silu(h2)*sigmoid(g2) * (rbf @ wt)
  float2 wt9[9];
#pragma unroll
  for (int d = 0; d < 9; ++d) wt9[d] = *(const float2*)(WT + d * 128 + c0);
#pragma unroll
  for (int r = 0; r < 4; ++r) {
    int e = e0 + r0 + r;
    if (e >= E) continue;
    float o0 = silu(ah[r][0]) * sigm(ag[r][0]);
    float o1 = silu(ah[r][1]) * sigm(ag[r][1]);
    float w0 = 0.f, w1 = 0.f;
#pragma unroll
    for (int d = 0; d < 9; ++d) {
      w0 = fmaf(rs[r0 + r][d], wt9[d].x, w0);
      w1 = fmaf(rs[r0 + r][d], wt9[d].y, w1);
    }
    float v0 = o0 * w0, v1 = o1 * w1;
    if (MODE == 0) {
      float2* p = (float2*)&ef[(size_t)e * 128 + c0];
      float2 old = *p;
      old.x += v0; old.y += v1;
      *p = old;
    } else {
      atomicAdd(&msg[es[r0 + r] + c0], v0);
      atomicAdd(&msg[es[r0 + r] + c0 + 1], v1);
    }
  }
}

__global__ void node_add_kernel(float* __restrict__ nf, const float* __restrict__ msg, int N) {
  int i = blockIdx.x * 256 + threadIdx.x;
  if (i < N * 128) nf[i] += msg[i];
}

// ---------------- readout ----------------
__global__ void mean_kernel(const float* __restrict__ nf, float* __restrict__ partial, int N) {
  __shared__ float sm[256];
  int n0 = blockIdx.x * 256;
  int col = threadIdx.x & 127, half = threadIdx.x >> 7;
  int nend = n0 + 256 < N ? n0 + 256 : N;
  float s = 0.f;
  for (int n = n0 + half; n < nend; n += 2) s += nf[n * 128 + col];
  sm[threadIdx.x] = s;
  __syncthreads();
  if (threadIdx.x < 128)
    partial[blockIdx.x * 128 + threadIdx.x] = sm[threadIdx.x] + sm[threadIdx.x + 128];
}

__global__ void final_kernel(const float* __restrict__ partial, int nchunks, float Nf,
                             const float* __restrict__ fW0, const float* __restrict__ fb0,
                             const float* __restrict__ fW1, const float* __restrict__ fb1,
                             const float* __restrict__ fW2, const float* __restrict__ fb2,
                             float* __restrict__ out) {
  __shared__ float v[128], h[128], red[128];
  int tid = threadIdx.x;  // 128 threads
  float s = 0.f;
  for (int b = 0; b < nchunks; ++b) s += partial[b * 128 + tid];
  v[tid] = s / Nf;
  __syncthreads();
  float acc = fb0[tid];
  for (int c = 0; c < 128; ++c) acc += v[c] * fW0[c * 128 + tid];
  h[tid] = silu(acc);
  __syncthreads();
  acc = fb1[tid];
  for (int c = 0; c < 128; ++c) acc += h[c] * fW1[c * 128 + tid];
  __syncthreads();
  v[tid] = silu(acc);
  __syncthreads();
  red[tid] = v[tid] * fW2[tid];
  __syncthreads();
  for (int st = 64; st > 0; st >>= 1) {
    if (tid < st) red[tid] += red[tid + st];
    __syncthreads();
  }
  if (tid == 0) out[0] = red[0] + fb2[0];
}

// ---------------- launch ----------------
extern "C" void kernel_launch(void* const* d_in, const int* in_sizes, int n_in,
                              void* d_out, int out_size, void* d_ws, size_t ws_size,
                              hipStream_t stream) {
  const float* pos = (const float*)d_in[0];
  const int* node_type = (const int*)d_in[1];
  const int* src = (const int*)d_in[2];
  const int* dst = (const int*)d_in[3];
  const int* t_src = (const int*)d_in[4];
  const int* t_dst = (const int*)d_in[5];
  const float* emb = (const float*)d_in[6];
  const float* eW = (const float*)d_in[7];
  const float* eB = (const float*)d_in[8];
  const float* taW = (const float*)d_in[9];
  const float* taB = (const float*)d_in[10];
  const float* tbW = (const float*)d_in[11];
  const float* tbG = (const float*)d_in[12];
  const float* W0 = (const float*)d_in[13]; const float* B0 = (const float*)d_in[14];
  const float* W1 = (const float*)d_in[15]; const float* B1 = (const float*)d_in[16];
  const float* W2 = (const float*)d_in[17]; const float* B2 = (const float*)d_in[18];
  const float* G0 = (const float*)d_in[19]; const float* Gb0 = (const float*)d_in[20];
  const float* G1 = (const float*)d_in[21]; const float* Gb1 = (const float*)d_in[22];
  const float* G2 = (const float*)d_in[23]; const float* Gb2 = (const float*)d_in[24];
  const float* WT = (const float*)d_in[25];
  const float* fW0 = (const float*)d_in[26]; const float* fb0 = (const float*)d_in[27];
  const float* fW1 = (const float*)d_in[28]; const float* fb1 = (const float*)d_in[29];
  const float* fW2 = (const float*)d_in[30]; const float* fb2 = (const float*)d_in[31];

  const int N = in_sizes[1];
  const int E = in_sizes[2];
  const int T = in_sizes[4];

  char* p = (char*)d_ws;
  auto alloc = [&](size_t bytes) -> char* {
    char* r = p;
    p += (bytes + 255) & ~(size_t)255;
    return r;
  };
  float* nf    = (float*)alloc((size_t)N * 128 * 4);
  float* msg   = (float*)alloc((size_t)N * 128 * 4);
  float* ef    = (float*)alloc((size_t)E * 128 * 4);
  float* rbf   = (float*)alloc((size_t)E * 9 * 4);
  float* bvec  = (float*)alloc((size_t)E * 3 * 4);
  float* bdist = (float*)alloc((size_t)E * 4);
  float* cut3  = (float*)alloc((size_t)E * 4);
  float* tbp   = (float*)alloc((size_t)T * 9 * 4);
  int*   ea    = (int*)alloc((size_t)T * 4);
  float* atoms = (float*)alloc((size_t)N * 9 * 4);
  float* nb    = (float*)alloc((size_t)E * 9 * 4);
  float* part  = (float*)alloc((size_t)64 * 128 * 4);
  (void)ws_size; (void)n_in; (void)out_size;

  node_init_kernel<<<(N * 128 + 255) / 256, 256, 0, stream>>>(node_type, emb, nf, N);
  edge_geom_kernel<<<(E + 255) / 256, 256, 0, stream>>>(pos, src, dst, bvec, bdist, rbf, cut3, E);
  edge_emb_kernel<<<(E * 128 + 255) / 256, 256, 0, stream>>>(rbf, eW, eB, ef, E);
  trip_kernel<<<(T + 255) / 256, 256, 0, stream>>>(t_src, t_dst, dst, bvec, bdist, rbf, cut3, tbp, ea, T);

  for (int k = 0; k < 3; ++k) {
    atoms_kernel<<<(N * 9 + 255) / 256, 256, 0, stream>>>(nf, taW + (size_t)k * 128 * 9,
                                                          taB + (size_t)k * 9, atoms, N);
    hipMemsetAsync(nb, 0, (size_t)E * 9 * 4, stream);
    tb_scatter_kernel<<<(T + 255) / 256, 256, 0, stream>>>(tbp, t_src, ea, atoms, nb, T);
    tb_update_kernel<<<(E * 128 + 255) / 256, 256, 0, stream>>>(
        nb, tbW + (size_t)k * 9 * 128, tbG + (size_t)k * 9 * 128, ef, E);

    size_t u0 = (size_t)(k * 2 + 0);
    gmlp_kernel<0><<<(E + TE - 1) / TE, 256, 0, stream>>>(
        nf, ef, rbf, src, dst,
        W0 + u0 * 384 * 128, B0 + u0 * 128, W1 + u0 * 128 * 128, B1 + u0 * 128,
        W2 + u0 * 128 * 128, B2 + u0 * 128,
        G0 + u0 * 384 * 128, Gb0 + u0 * 128, G1 + u0 * 128 * 128, Gb1 + u0 * 128,
        G2 + u0 * 128 * 128, Gb2 + u0 * 128,
        WT + u0 * 9 * 128, msg, E);

    size_t u1 = u0 + 1;
    hipMemsetAsync(msg, 0, (size_t)N * 128 * 4, stream);
    gmlp_kernel<1><<<(E + TE - 1) / TE, 256, 0, stream>>>(
        nf, ef, rbf, src, dst,
        W0 + u1 * 384 * 128, B0 + u1 * 128, W1 + u1 * 128 * 128, B1 + u1 * 128,
        W2 + u1 * 128 * 128, B2 + u1 * 128,
        G0 + u1 * 384 * 128, Gb0 + u1 * 128, G1 + u1 * 128 * 128, Gb1 + u1 * 128,
        G2 + u1 * 128 * 128, Gb2 + u1 * 128,
        WT + u1 * 9 * 128, msg, E);
    node_add_kernel<<<(N * 128 + 255) / 256, 256, 0, stream>>>(nf, msg, N);
  }

  int nchunks = (N + 255) / 256;
  mean_kernel<<<nchunks, 256, 0, stream>>>(nf, part, N);
  final_kernel<<<1, 128, 0, stream>>>(part, nchunks, (float)N, fW0, fb0, fW1, fb1, fW2, fb2,
                                      (float*)d_out);
}

// Round 3
// 1196.585 us; speedup vs baseline: 3.5731x; 3.5731x over previous
//
#include <hip/hip_runtime.h>
#include <stdint.h>

typedef __attribute__((ext_vector_type(8))) short bf16x8;
typedef __attribute__((ext_vector_type(4))) float f32x4;

// ---------------- helpers ----------------
__device__ __forceinline__ float sigm(float x) { return 1.0f / (1.0f + expf(-x)); }
__device__ __forceinline__ float silu(float x) { return x / (1.0f + expf(-x)); }
__device__ __forceinline__ short f2bf(float f) {  // RNE f32->bf16
  uint32_t u = __float_as_uint(f);
  u = (u + 0x7fffu + ((u >> 16) & 1u)) >> 16;
  return (short)u;
}

// spherical bessel j_l, matches reference _jl
__device__ __forceinline__ float jl_eval(int l, float x) {
  float s, c;
  sincosf(x, &s, &c);
  float ix = 1.0f / x, ix2 = ix * ix;
  if (l == 0) return s * ix;
  if (l == 1) return s * ix2 - c * ix;
  if (l == 2) return (3.0f * ix2 * ix - ix) * s - 3.0f * ix2 * c;
  return (15.0f * ix2 * ix2 - 6.0f * ix2) * s - (15.0f * ix2 * ix - ix) * c;
}

// ---------------- init / geometry kernels ----------------
__global__ void node_init_kernel(const int* __restrict__ nt, const float* __restrict__ emb,
                                 float* __restrict__ nf, int N) {
  int i = blockIdx.x * 256 + threadIdx.x;
  if (i >= N * 128) return;
  int n = i >> 7, c = i & 127;
  nf[i] = emb[nt[n] * 128 + c];
}

__global__ void edge_geom_kernel(const float* __restrict__ pos, const int* __restrict__ src,
                                 const int* __restrict__ dst, float* __restrict__ bvec,
                                 float* __restrict__ bdist, float* __restrict__ rbf,
                                 float* __restrict__ cut3, int E) {
  int e = blockIdx.x * 256 + threadIdx.x;
  if (e >= E) return;
  int s = src[e], d = dst[e];
  float dx = pos[d * 3 + 0] - pos[s * 3 + 0];
  float dy = pos[d * 3 + 1] - pos[s * 3 + 1];
  float dz = pos[d * 3 + 2] - pos[s * 3 + 2];
  float r = sqrtf(dx * dx + dy * dy + dz * dz + 1e-12f);
  bvec[e * 3 + 0] = dx; bvec[e * 3 + 1] = dy; bvec[e * 3 + 2] = dz;
  bdist[e] = r;
  const float roots[3][3] = {
      {3.141592653589793f, 6.283185307179586f, 9.42477796076938f},
      {4.493409457909064f, 7.725251836937707f, 10.904121659428899f},
      {5.763459196894550f, 9.095011330476355f, 12.322940970566582f}};
#pragma unroll
  for (int l = 0; l < 3; ++l) {
#pragma unroll
    for (int n = 0; n < 3; ++n) {
      float root = roots[l][n];
      float x = r * (root * 0.2f);                  // r * root / CUTOFF(5)
      float norm = fabsf(jl_eval(l + 1, root));     // SBF_NORM
      rbf[e * 9 + l * 3 + n] = jl_eval(l, x) * (0.12649110640673518f / norm);
    }
  }
  float xx = r * 0.25f;  // r / TB_CUTOFF(4)
  float x3 = xx * xx * xx;
  cut3[e] = 1.0f - 6.0f * x3 * xx * xx + 15.0f * x3 * xx - 10.0f * x3;
}

__global__ void edge_emb_kernel(const float* __restrict__ rbf, const float* __restrict__ W,
                                const float* __restrict__ B, float* __restrict__ ef, int E) {
  int i = blockIdx.x * 256 + threadIdx.x;
  if (i >= E * 128) return;
  int e = i >> 7, c = i & 127;
  float acc = B[c];
#pragma unroll
  for (int d = 0; d < 9; ++d) acc += rbf[e * 9 + d] * W[d * 128 + c];
  ef[i] = silu(acc);
}

__global__ void trip_kernel(const int* __restrict__ t_src, const int* __restrict__ t_dst,
                            const int* __restrict__ dst, const float* __restrict__ bvec,
                            const float* __restrict__ bdist, const float* __restrict__ rbf,
                            const float* __restrict__ cut3, float* __restrict__ tbp,
                            int* __restrict__ ea, int T) {
  int t = blockIdx.x * 256 + threadIdx.x;
  if (t >= T) return;
  int i = t_src[t], j = t_dst[t];
  float ax = bvec[i * 3], ay = bvec[i * 3 + 1], az = bvec[i * 3 + 2];
  float bx = bvec[j * 3], by = bvec[j * 3 + 1], bz = bvec[j * 3 + 2];
  float ct = (ax * bx + ay * by + az * bz) / (bdist[i] * bdist[j]);
  float tw = cut3[i] * cut3[j];
  float sh[3];
  sh[0] = 0.28209479177387814f * tw;
  sh[1] = 0.4886025119029199f * ct * tw;
  sh[2] = 0.31539156525252005f * (3.0f * ct * ct - 1.0f) * tw;
#pragma unroll
  for (int l = 0; l < 3; ++l)
#pragma unroll
    for (int n = 0; n < 3; ++n)
      tbp[t * 9 + l * 3 + n] = rbf[j * 9 + l * 3 + n] * sh[l];
  ea[t] = dst[j];
}

// ---------------- three-body block kernels ----------------
__global__ void atoms_kernel(const float* __restrict__ nf, const float* __restrict__ W,
                             const float* __restrict__ B, float* __restrict__ atoms, int N) {
  int i = blockIdx.x * 256 + threadIdx.x;
  if (i >= N * 9) return;
  int n = i / 9, d = i - n * 9;
  float acc = B[d];
  for (int c = 0; c < 128; ++c) acc += nf[n * 128 + c] * W[c * 9 + d];
  atoms[i] = sigm(acc);
}

__global__ void tb_scatter_kernel(const float* __restrict__ tbp, const int* __restrict__ t_src,
                                  const int* __restrict__ ea, const float* __restrict__ atoms,
                                  float* __restrict__ nb, int T) {
  int t = blockIdx.x * 256 + threadIdx.x;
  if (t >= T) return;
  int e = t_src[t], a = ea[t];
#pragma unroll
  for (int d = 0; d < 9; ++d)
    atomicAdd(&nb[e * 9 + d], tbp[t * 9 + d] * atoms[a * 9 + d]);
}

__global__ void tb_update_kernel(const float* __restrict__ nb, const float* __restrict__ W,
                                 const float* __restrict__ Wg, float* __restrict__ ef, int E) {
  int i = blockIdx.x * 256 + threadIdx.x;
  if (i >= E * 128) return;
  int e = i >> 7, c = i & 127;
  float n9[9];
#pragma unroll
  for (int d = 0; d < 9; ++d) n9[d] = nb[e * 9 + d];
  float a = 0.f, b = 0.f;
#pragma unroll
  for (int d = 0; d < 9; ++d) {
    a += n9[d] * W[d * 128 + c];
    b += n9[d] * Wg[d * 128 + c];
  }
  ef[i] += silu(a) * sigm(b);
}

// ---------------- weight packing: f32 [K][128] -> bf16 fragment-major ----------------
// layout: per unit, tile = nt*(K/32)+kt; tile holds 64 lanes x 8 bf16 contiguous.
// lane l of tile (nt,kt) holds W[kt*32 + (l>>4)*8 + e][nt*16 + (l&15)], e=0..7.
__global__ void pack_kernel(const float* __restrict__ Wf, short* __restrict__ Wp, int K,
                            int units) {
  int per = 8 * (K / 32) * 64;  // fragment-threads per unit
  int idx = blockIdx.x * 256 + threadIdx.x;
  if (idx >= units * per) return;
  int u = idx / per, r = idx - u * per;
  int lane = r & 63, tile = r >> 6;
  int kt = tile % (K / 32), nt = tile / (K / 32);
  int n = nt * 16 + (lane & 15);
  int k0 = kt * 32 + (lane >> 4) * 8;
  const float* src = Wf + (size_t)u * K * 128;
  bf16x8 v;
#pragma unroll
  for (int e = 0; e < 8; ++e) v[e] = f2bf(src[(size_t)(k0 + e) * 128 + n]);
  *(bf16x8*)(Wp + (size_t)u * K * 128 + (size_t)tile * 512 + lane * 8) = v;
}

// ---------------- fused gated-MLP on MFMA ----------------
#define TE 32  // edges per block; E=60000 -> 1875 blocks exactly

__device__ __forceinline__ f32x4 mfma16(bf16x8 a, bf16x8 b, f32x4 c) {
  return __builtin_amdgcn_mfma_f32_16x16x32_bf16(a, b, c, 0, 0, 0);
}

// one K=128 gated layer: A_h from hin, A_g from gin (bf16 LDS, row stride `ld`),
// B from packed pW/pG; acc initialized with bias.
__device__ __forceinline__ void layer128(const short* hin, const short* gin, int ld,
                                         const short* __restrict__ pW,
                                         const short* __restrict__ pG,
                                         const float* __restrict__ Bh,
                                         const float* __restrict__ Bg, int wave, int lane,
                                         f32x4 (&aW)[2][2], f32x4 (&aG)[2][2]) {
  const int lrow = lane & 15, lk = lane >> 4;
#pragma unroll
  for (int nt = 0; nt < 2; ++nt) {
    float bw = Bh[wave * 32 + nt * 16 + lrow];
    float bg = Bg[wave * 32 + nt * 16 + lrow];
#pragma unroll
    for (int mt = 0; mt < 2; ++mt) {
      aW[mt][nt] = {bw, bw, bw, bw};
      aG[mt][nt] = {bg, bg, bg, bg};
    }
  }
#pragma unroll
  for (int kt = 0; kt < 4; ++kt) {
    int aoff = kt * 32 + lk * 8;
    bf16x8 ah0 = *(const bf16x8*)(hin + (size_t)lrow * ld + aoff);
    bf16x8 ah1 = *(const bf16x8*)(hin + (size_t)(16 + lrow) * ld + aoff);
    bf16x8 ag0 = *(const bf16x8*)(gin + (size_t)lrow * ld + aoff);
    bf16x8 ag1 = *(const bf16x8*)(gin + (size_t)(16 + lrow) * ld + aoff);
    bf16x8 bw0 = *(const bf16x8*)(pW + ((wave * 2 + 0) * 4 + kt) * 512 + lane * 8);
    bf16x8 bw1 = *(const bf16x8*)(pW + ((wave * 2 + 1) * 4 + kt) * 512 + lane * 8);
    bf16x8 bg0 = *(const bf16x8*)(pG + ((wave * 2 + 0) * 4 + kt) * 512 + lane * 8);
    bf16x8 bg1 = *(const bf16x8*)(pG + ((wave * 2 + 1) * 4 + kt) * 512 + lane * 8);
    aW[0][0] = mfma16(ah0, bw0, aW[0][0]);
    aW[1][0] = mfma16(ah1, bw0, aW[1][0]);
    aW[0][1] = mfma16(ah0, bw1, aW[0][1]);
    aW[1][1] = mfma16(ah1, bw1, aW[1][1]);
    aG[0][0] = mfma16(ag0, bg0, aG[0][0]);
    aG[1][0] = mfma16(ag1, bg0, aG[1][0]);
    aG[0][1] = mfma16(ag0, bg1, aG[0][1]);
    aG[1][1] = mfma16(ag1, bg1, aG[1][1]);
  }
}

// MODE 0: ef[e] += out (block owns edges); MODE 1: atomicAdd(msg[dst[e]], out)
template <int MODE>
__global__ __launch_bounds__(256) void gmlp_mfma(
    const float* __restrict__ nf, float* __restrict__ ef, const float* __restrict__ rbf,
    const int* __restrict__ src, const int* __restrict__ dst,
    const short* __restrict__ pW0, const short* __restrict__ pG0,
    const short* __restrict__ pW1, const short* __restrict__ pG1,
    const short* __restrict__ pW2, const short* __restrict__ pG2,
    const float* __restrict__ B0, const float* __restrict__ Gb0,
    const float* __restrict__ B1, const float* __restrict__ Gb1,
    const float* __restrict__ B2, const float* __restrict__ Gb2,
    const float* __restrict__ WT, float* __restrict__ msg, int E) {
  __shared__ __align__(16) short xs[32][392];  // x bf16, +8 pad (stride 196 dw % 32 = 4)
  __shared__ __align__(16) short hs[32][136];
  __shared__ __align__(16) short gs[32][136];
  __shared__ float rs[32][12];
  __shared__ int es[32];
  const int tid = threadIdx.x;
  const int e0 = blockIdx.x * TE;

  // ---- gather x = [nf[src] | nf[dst] | ef] as bf16 ----
  {
    int r = tid >> 3, q = tid & 7;
    int e = e0 + r;
    if (e >= E) e = E - 1;
    const float* sp0 = nf + (size_t)src[e] * 128;
    const float* sp1 = nf + (size_t)dst[e] * 128;
    const float* sp2 = ef + (size_t)e * 128;
#pragma unroll
    for (int seg = 0; seg < 3; ++seg) {
      const float* sp = seg == 0 ? sp0 : (seg == 1 ? sp1 : sp2);
      int col = q * 16;
      float4 f0 = *(const float4*)(sp + col);
      float4 f1 = *(const float4*)(sp + col + 4);
      float4 f2 = *(const float4*)(sp + col + 8);
      float4 f3 = *(const float4*)(sp + col + 12);
      bf16x8 v0, v1;
      v0[0] = f2bf(f0.x); v0[1] = f2bf(f0.y); v0[2] = f2bf(f0.z); v0[3] = f2bf(f0.w);
      v0[4] = f2bf(f1.x); v0[5] = f2bf(f1.y); v0[6] = f2bf(f1.z); v0[7] = f2bf(f1.w);
      v1[0] = f2bf(f2.x); v1[1] = f2bf(f2.y); v1[2] = f2bf(f2.z); v1[3] = f2bf(f2.w);
      v1[4] = f2bf(f3.x); v1[5] = f2bf(f3.y); v1[6] = f2bf(f3.z); v1[7] = f2bf(f3.w);
      *(bf16x8*)&xs[r][seg * 128 + col] = v0;
      *(bf16x8*)&xs[r][seg * 128 + col + 8] = v1;
    }
    if (tid < 32) {
      int ee = e0 + tid; if (ee >= E) ee = E - 1;
      es[tid] = dst[ee] * 128;
    }
    for (int idx = tid; idx < 32 * 9; idx += 256) {
      int rr = idx / 9, d = idx - rr * 9;
      int ee = e0 + rr; if (ee >= E) ee = E - 1;
      rs[rr][d] = rbf[ee * 9 + d];
    }
  }
  __syncthreads();

  const int wave = tid >> 6;
  const int lane = tid & 63;
  const int lrow = lane & 15, lk = lane >> 4;
  f32x4 aW[2][2], aG[2][2];

  // ---- layer 0: K=384, shared A ----
#pragma unroll
  for (int nt = 0; nt < 2; ++nt) {
    float bw = B0[wave * 32 + nt * 16 + lrow];
    float bg = Gb0[wave * 32 + nt * 16 + lrow];
#pragma unroll
    for (int mt = 0; mt < 2; ++mt) {
      aW[mt][nt] = {bw, bw, bw, bw};
      aG[mt][nt] = {bg, bg, bg, bg};
    }
  }
  for (int kt = 0; kt < 12; ++kt) {
    int aoff = kt * 32 + lk * 8;
    bf16x8 a0 = *(const bf16x8*)&xs[lrow][aoff];
    bf16x8 a1 = *(const bf16x8*)&xs[16 + lrow][aoff];
    bf16x8 bw0 = *(const bf16x8*)(pW0 + ((wave * 2 + 0) * 12 + kt) * 512 + lane * 8);
    bf16x8 bw1 = *(const bf16x8*)(pW0 + ((wave * 2 + 1) * 12 + kt) * 512 + lane * 8);
    bf16x8 bg0 = *(const bf16x8*)(pG0 + ((wave * 2 + 0) * 12 + kt) * 512 + lane * 8);
    bf16x8 bg1 = *(const bf16x8*)(pG0 + ((wave * 2 + 1) * 12 + kt) * 512 + lane * 8);
    aW[0][0] = mfma16(a0, bw0, aW[0][0]);
    aW[1][0] = mfma16(a1, bw0, aW[1][0]);
    aW[0][1] = mfma16(a0, bw1, aW[0][1]);
    aW[1][1] = mfma16(a1, bw1, aW[1][1]);
    aG[0][0] = mfma16(a0, bg0, aG[0][0]);
    aG[1][0] = mfma16(a1, bg0, aG[1][0]);
    aG[0][1] = mfma16(a0, bg1, aG[0][1]);
    aG[1][1] = mfma16(a1, bg1, aG[1][1]);
  }
  // silu -> hs, gs   (C layout: row = lk*4+reg, col = lrow)
#pragma unroll
  for (int mt = 0; mt < 2; ++mt)
#pragma unroll
    for (int nt = 0; nt < 2; ++nt) {
      int col = wave * 32 + nt * 16 + lrow;
#pragma unroll
      for (int rg = 0; rg < 4; ++rg) {
        int row = mt * 16 + lk * 4 + rg;
        hs[row][col] = f2bf(silu(aW[mt][nt][rg]));
        gs[row][col] = f2bf(silu(aG[mt][nt][rg]));
      }
    }
  __syncthreads();

  // ---- layer 1: K=128 ----
  layer128(&hs[0][0], &gs[0][0], 136, pW1, pG1, B1, Gb1, wave, lane, aW, aG);
  // write h1,g1 into reused xs space
  short* h1 = &xs[0][0];
  short* g1 = h1 + 32 * 136;
#pragma unroll
  for (int mt = 0; mt < 2; ++mt)
#pragma unroll
    for (int nt = 0; nt < 2; ++nt) {
      int col = wave * 32 + nt * 16 + lrow;
#pragma unroll
      for (int rg = 0; rg < 4; ++rg) {
        int row = mt * 16 + lk * 4 + rg;
        h1[row * 136 + col] = f2bf(silu(aW[mt][nt][rg]));
        g1[row * 136 + col] = f2bf(silu(aG[mt][nt][rg]));
      }
    }
  __syncthreads();

  // ---- layer 2: K=128 (activations applied in epilogue) ----
  layer128(h1, g1, 136, pW2, pG2, B2, Gb2, wave, lane, aW, aG);

  // ---- epilogue: silu(h2)*sigmoid(g2) * (rbf @ wt) ----
  float wtc[2][9];
#pragma unroll
  for (int nt = 0; nt < 2; ++nt) {
    int col = wave * 32 + nt * 16 + lrow;
#pragma unroll
    for (int d = 0; d < 9; ++d) wtc[nt][d] = WT[d * 128 + col];
  }
#pragma unroll
  for (int mt = 0; mt < 2; ++mt)
#pragma unroll
    for (int rg = 0; rg < 4; ++rg) {
      int row = mt * 16 + lk * 4 + rg;
      int e = e0 + row;
      float rv[9];
#pragma unroll
      for (int d = 0; d < 9; ++d) rv[d] = rs[row][d];
#pragma unroll
      for (int nt = 0; nt < 2; ++nt) {
        int col = wave * 32 + nt * 16 + lrow;
        float wv = 0.f;
#pragma unroll
        for (int d = 0; d < 9; ++d) wv = fmaf(rv[d], wtc[nt][d], wv);
        float v = silu(aW[mt][nt][rg]) * sigm(aG[mt][nt][rg]) * wv;
        if (e < E) {
          if (MODE == 0) ef[(size_t)e * 128 + col] += v;
          else atomicAdd(&msg[es[row] + col], v);
        }
      }
    }
}

__global__ void node_add_kernel(float* __restrict__ nf, const float* __restrict__ msg, int N) {
  int i = blockIdx.x * 256 + threadIdx.x;
  if (i < N * 128) nf[i] += msg[i];
}

// ---------------- readout ----------------
__global__ void mean_kernel(const float* __restrict__ nf, float* __restrict__ partial, int N) {
  __shared__ float sm[256];
  int n0 = blockIdx.x * 256;
  int col = threadIdx.x & 127, half = threadIdx.x >> 7;
  int nend = n0 + 256 < N ? n0 + 256 : N;
  float s = 0.f;
  for (int n = n0 + half; n < nend; n += 2) s += nf[n * 128 + col];
  sm[threadIdx.x] = s;
  __syncthreads();
  if (threadIdx.x < 128)
    partial[blockIdx.x * 128 + threadIdx.x] = sm[threadIdx.x] + sm[threadIdx.x + 128];
}

__global__ void final_kernel(const float* __restrict__ partial, int nchunks, float Nf,
                             const float* __restrict__ fW0, const float* __restrict__ fb0,
                             const float* __restrict__ fW1, const float* __restrict__ fb1,
                             const float* __restrict__ fW2, const float* __restrict__ fb2,
                             float* __restrict__ out) {
  __shared__ float v[128], h[128], red[128];
  int tid = threadIdx.x;  // 128 threads
  float s = 0.f;
  for (int b = 0; b < nchunks; ++b) s += partial[b * 128 + tid];
  v[tid] = s / Nf;
  __syncthreads();
  float acc = fb0[tid];
  for (int c = 0; c < 128; ++c) acc += v[c] * fW0[c * 128 + tid];
  h[tid] = silu(acc);
  __syncthreads();
  acc = fb1[tid];
  for (int c = 0; c < 128; ++c) acc += h[c] * fW1[c * 128 + tid];
  __syncthreads();
  v[tid] = silu(acc);
  __syncthreads();
  red[tid] = v[tid] * fW2[tid];
  __syncthreads();
  for (int st = 64; st > 0; st >>= 1) {
    if (tid < st) red[tid] += red[tid + st];
    __syncthreads();
  }
  if (tid == 0) out[0] = red[0] + fb2[0];
}

// ---------------- launch ----------------
extern "C" void kernel_launch(void* const* d_in, const int* in_sizes, int n_in,
                              void* d_out, int out_size, void* d_ws, size_t ws_size,
                              hipStream_t stream) {
  const float* pos = (const float*)d_in[0];
  const int* node_type = (const int*)d_in[1];
  const int* src = (const int*)d_in[2];
  const int* dst = (const int*)d_in[3];
  const int* t_src = (const int*)d_in[4];
  const int* t_dst = (const int*)d_in[5];
  const float* emb = (const float*)d_in[6];
  const float* eW = (const float*)d_in[7];
  const float* eB = (const float*)d_in[8];
  const float* taW = (const float*)d_in[9];
  const float* taB = (const float*)d_in[10];
  const float* tbW = (const float*)d_in[11];
  const float* tbG = (const float*)d_in[12];
  const float* W0 = (const float*)d_in[13]; const float* B0 = (const float*)d_in[14];
  const float* W1 = (const float*)d_in[15]; const float* B1 = (const float*)d_in[16];
  const float* W2 = (const float*)d_in[17]; const float* B2 = (const float*)d_in[18];
  const float* G0 = (const float*)d_in[19]; const float* Gb0 = (const float*)d_in[20];
  const float* G1 = (const float*)d_in[21]; const float* Gb1 = (const float*)d_in[22];
  const float* G2 = (const float*)d_in[23]; const float* Gb2 = (const float*)d_in[24];
  const float* WT = (const float*)d_in[25];
  const float* fW0 = (const float*)d_in[26]; const float* fb0 = (const float*)d_in[27];
  const float* fW1 = (const float*)d_in[28]; const float* fb1 = (const float*)d_in[29];
  const float* fW2 = (const float*)d_in[30]; const float* fb2 = (const float*)d_in[31];

  const int N = in_sizes[1];
  const int E = in_sizes[2];
  const int T = in_sizes[4];

  char* p = (char*)d_ws;
  auto alloc = [&](size_t bytes) -> char* {
    char* r = p;
    p += (bytes + 255) & ~(size_t)255;
    return r;
  };
  float* nf    = (float*)alloc((size_t)N * 128 * 4);
  float* msg   = (float*)alloc((size_t)N * 128 * 4);
  float* ef    = (float*)alloc((size_t)E * 128 * 4);
  float* rbf   = (float*)alloc((size_t)E * 9 * 4);
  float* bvec  = (float*)alloc((size_t)E * 3 * 4);
  float* bdist = (float*)alloc((size_t)E * 4);
  float* cut3  = (float*)alloc((size_t)E * 4);
  float* tbp   = (float*)alloc((size_t)T * 9 * 4);
  int*   ea    = (int*)alloc((size_t)T * 4);
  float* atoms = (float*)alloc((size_t)N * 9 * 4);
  float* nb    = (float*)alloc((size_t)E * 9 * 4);
  float* part  = (float*)alloc((size_t)64 * 128 * 4);
  // packed bf16 weights (fragment-major), 6 units each
  short* pW0s = (short*)alloc((size_t)6 * 384 * 128 * 2);
  short* pG0s = (short*)alloc((size_t)6 * 384 * 128 * 2);
  short* pW1s = (short*)alloc((size_t)6 * 128 * 128 * 2);
  short* pG1s = (short*)alloc((size_t)6 * 128 * 128 * 2);
  short* pW2s = (short*)alloc((size_t)6 * 128 * 128 * 2);
  short* pG2s = (short*)alloc((size_t)6 * 128 * 128 * 2);
  (void)ws_size; (void)n_in; (void)out_size;

  // pack all gMLP weights once (W0/G0: [6][384][128], rest: [6][128][128])
  {
    int t384 = 6 * 8 * 12 * 64, t128 = 6 * 8 * 4 * 64;
    pack_kernel<<<(t384 + 255) / 256, 256, 0, stream>>>(W0, pW0s, 384, 6);
    pack_kernel<<<(t384 + 255) / 256, 256, 0, stream>>>(G0, pG0s, 384, 6);
    pack_kernel<<<(t128 + 255) / 256, 256, 0, stream>>>(W1, pW1s, 128, 6);
    pack_kernel<<<(t128 + 255) / 256, 256, 0, stream>>>(G1, pG1s, 128, 6);
    pack_kernel<<<(t128 + 255) / 256, 256, 0, stream>>>(W2, pW2s, 128, 6);
    pack_kernel<<<(t128 + 255) / 256, 256, 0, stream>>>(G2, pG2s, 128, 6);
  }

  node_init_kernel<<<(N * 128 + 255) / 256, 256, 0, stream>>>(node_type, emb, nf, N);
  edge_geom_kernel<<<(E + 255) / 256, 256, 0, stream>>>(pos, src, dst, bvec, bdist, rbf, cut3, E);
  edge_emb_kernel<<<(E * 128 + 255) / 256, 256, 0, stream>>>(rbf, eW, eB, ef, E);
  trip_kernel<<<(T + 255) / 256, 256, 0, stream>>>(t_src, t_dst, dst, bvec, bdist, rbf, cut3, tbp, ea, T);

  const int gblocks = (E + TE - 1) / TE;
  for (int k = 0; k < 3; ++k) {
    atoms_kernel<<<(N * 9 + 255) / 256, 256, 0, stream>>>(nf, taW + (size_t)k * 128 * 9,
                                                          taB + (size_t)k * 9, atoms, N);
    hipMemsetAsync(nb, 0, (size_t)E * 9 * 4, stream);
    tb_scatter_kernel<<<(T + 255) / 256, 256, 0, stream>>>(tbp, t_src, ea, atoms, nb, T);
    tb_update_kernel<<<(E * 128 + 255) / 256, 256, 0, stream>>>(
        nb, tbW + (size_t)k * 9 * 128, tbG + (size_t)k * 9 * 128, ef, E);

    size_t u0 = (size_t)(k * 2 + 0);
    gmlp_mfma<0><<<gblocks, 256, 0, stream>>>(
        nf, ef, rbf, src, dst,
        pW0s + u0 * 384 * 128, pG0s + u0 * 384 * 128,
        pW1s + u0 * 128 * 128, pG1s + u0 * 128 * 128,
        pW2s + u0 * 128 * 128, pG2s + u0 * 128 * 128,
        B0 + u0 * 128, Gb0 + u0 * 128, B1 + u0 * 128, Gb1 + u0 * 128,
        B2 + u0 * 128, Gb2 + u0 * 128,
        WT + u0 * 9 * 128, msg, E);

    size_t u1 = u0 + 1;
    hipMemsetAsync(msg, 0, (size_t)N * 128 * 4, stream);
    gmlp_mfma<1><<<gblocks, 256, 0, stream>>>(
        nf, ef, rbf, src, dst,
        pW0s + u1 * 384 * 128, pG0s + u1 * 384 * 128,
        pW1s + u1 * 128 * 128, pG1s + u1 * 128 * 128,
        pW2s + u1 * 128 * 128, pG2s + u1 * 128 * 128,
        B0 + u1 * 128, Gb0 + u1 * 128, B1 + u1 * 128, Gb1 + u1 * 128,
        B2 + u1 * 128, Gb2 + u1 * 128,
        WT + u1 * 9 * 128, msg, E);
    node_add_kernel<<<(N * 128 + 255) / 256, 256, 0, stream>>>(nf, msg, N);
  }

  int nchunks = (N + 255) / 256;
  mean_kernel<<<nchunks, 256, 0, stream>>>(nf, part, N);
  final_kernel<<<1, 128, 0, stream>>>(part, nchunks, (float)N, fW0, fb0, fW1, fb1, fW2, fb2,
                                      (float*)d_out);
}

// Round 4
// 748.581 us; speedup vs baseline: 5.7115x; 1.5985x over previous
//
#include <hip/hip_runtime.h>
#include <stdint.h>

typedef __attribute__((ext_vector_type(8))) short bf16x8;
typedef __attribute__((ext_vector_type(4))) float f32x4;

// ---------------- helpers ----------------
__device__ __forceinline__ float sigm(float x) { return 1.0f / (1.0f + expf(-x)); }
__device__ __forceinline__ float silu(float x) { return x / (1.0f + expf(-x)); }
__device__ __forceinline__ short f2bf(float f) {  // RNE f32->bf16
  uint32_t u = __float_as_uint(f);
  u = (u + 0x7fffu + ((u >> 16) & 1u)) >> 16;
  return (short)u;
}

// spherical bessel j_l, matches reference _jl
__device__ __forceinline__ float jl_eval(int l, float x) {
  float s, c;
  sincosf(x, &s, &c);
  float ix = 1.0f / x, ix2 = ix * ix;
  if (l == 0) return s * ix;
  if (l == 1) return s * ix2 - c * ix;
  if (l == 2) return (3.0f * ix2 * ix - ix) * s - 3.0f * ix2 * c;
  return (15.0f * ix2 * ix2 - 6.0f * ix2) * s - (15.0f * ix2 * ix - ix) * c;
}

// ---------------- init / geometry kernels ----------------
__global__ void node_init_kernel(const int* __restrict__ nt, const float* __restrict__ emb,
                                 float* __restrict__ nf, int N) {
  int i = blockIdx.x * 256 + threadIdx.x;
  if (i >= N * 128) return;
  int n = i >> 7, c = i & 127;
  nf[i] = emb[nt[n] * 128 + c];
}

__global__ void edge_geom_kernel(const float* __restrict__ pos, const int* __restrict__ src,
                                 const int* __restrict__ dst, float* __restrict__ bvec,
                                 float* __restrict__ bdist, float* __restrict__ rbf,
                                 float* __restrict__ cut3, int E) {
  int e = blockIdx.x * 256 + threadIdx.x;
  if (e >= E) return;
  int s = src[e], d = dst[e];
  float dx = pos[d * 3 + 0] - pos[s * 3 + 0];
  float dy = pos[d * 3 + 1] - pos[s * 3 + 1];
  float dz = pos[d * 3 + 2] - pos[s * 3 + 2];
  float r = sqrtf(dx * dx + dy * dy + dz * dz + 1e-12f);
  bvec[e * 3 + 0] = dx; bvec[e * 3 + 1] = dy; bvec[e * 3 + 2] = dz;
  bdist[e] = r;
  const float roots[3][3] = {
      {3.141592653589793f, 6.283185307179586f, 9.42477796076938f},
      {4.493409457909064f, 7.725251836937707f, 10.904121659428899f},
      {5.763459196894550f, 9.095011330476355f, 12.322940970566582f}};
#pragma unroll
  for (int l = 0; l < 3; ++l) {
#pragma unroll
    for (int n = 0; n < 3; ++n) {
      float root = roots[l][n];
      float x = r * (root * 0.2f);                  // r * root / CUTOFF(5)
      float norm = fabsf(jl_eval(l + 1, root));     // SBF_NORM
      rbf[e * 9 + l * 3 + n] = jl_eval(l, x) * (0.12649110640673518f / norm);
    }
  }
  float xx = r * 0.25f;  // r / TB_CUTOFF(4)
  float x3 = xx * xx * xx;
  cut3[e] = 1.0f - 6.0f * x3 * xx * xx + 15.0f * x3 * xx - 10.0f * x3;
}

__global__ void edge_emb_kernel(const float* __restrict__ rbf, const float* __restrict__ W,
                                const float* __restrict__ B, float* __restrict__ ef, int E) {
  int i = blockIdx.x * 256 + threadIdx.x;
  if (i >= E * 128) return;
  int e = i >> 7, c = i & 127;
  float acc = B[c];
#pragma unroll
  for (int d = 0; d < 9; ++d) acc += rbf[e * 9 + d] * W[d * 128 + c];
  ef[i] = silu(acc);
}

// ---------------- CSR build: count / scan / finalize ----------------
__global__ void count_kernel(const int* __restrict__ idx, int* __restrict__ cnt, int L) {
  int i = blockIdx.x * 256 + threadIdx.x;
  if (i < L) atomicAdd(&cnt[idx[i]], 1);
}

__global__ void scan_block_kernel(const int* __restrict__ in, int* __restrict__ incl,
                                  int* __restrict__ bsum, int L) {
  __shared__ int sm[256];
  int i = blockIdx.x * 256 + threadIdx.x;
  int v = i < L ? in[i] : 0;
  sm[threadIdx.x] = v;
  __syncthreads();
  for (int st = 1; st < 256; st <<= 1) {
    int t = threadIdx.x >= st ? sm[threadIdx.x - st] : 0;
    __syncthreads();
    sm[threadIdx.x] += t;
    __syncthreads();
  }
  if (i < L) incl[i] = sm[threadIdx.x];
  if (threadIdx.x == 255) bsum[blockIdx.x] = sm[255];
}

__global__ void scan_top_kernel(int* __restrict__ bsum, int nb) {  // in-place exclusive
  __shared__ int sm[1024];
  int tid = threadIdx.x;
  int orig = tid < nb ? bsum[tid] : 0;
  sm[tid] = orig;
  __syncthreads();
  for (int st = 1; st < 1024; st <<= 1) {
    int t = tid >= st ? sm[tid - st] : 0;
    __syncthreads();
    sm[tid] += t;
    __syncthreads();
  }
  if (tid < nb) bsum[tid] = sm[tid] - orig;
}

__global__ void scan_finalize_kernel(const int* __restrict__ cnt, const int* __restrict__ incl,
                                     const int* __restrict__ bexcl, int* __restrict__ off,
                                     int* __restrict__ cur, int L) {
  int i = blockIdx.x * 256 + threadIdx.x;
  if (i >= L) return;
  int o = incl[i] - cnt[i] + bexcl[blockIdx.x];
  off[i] = o;
  cur[i] = o;
}

__global__ void fill_eperm_kernel(const int* __restrict__ dst, int* __restrict__ cur_n,
                                  int* __restrict__ eperm, int E) {
  int e = blockIdx.x * 256 + threadIdx.x;
  if (e >= E) return;
  int pos = atomicAdd(&cur_n[dst[e]], 1);
  eperm[pos] = e;
}

// triplet precompute, written directly to CSR-sorted position (by t_src)
__global__ void trip_sorted_kernel(const int* __restrict__ t_src, const int* __restrict__ t_dst,
                                   const int* __restrict__ dst, const float* __restrict__ bvec,
                                   const float* __restrict__ bdist, const float* __restrict__ rbf,
                                   const float* __restrict__ cut3, int* __restrict__ cur_e,
                                   float* __restrict__ stbp, int* __restrict__ sa, int T) {
  int t = blockIdx.x * 256 + threadIdx.x;
  if (t >= T) return;
  int i = t_src[t], j = t_dst[t];
  float ax = bvec[i * 3], ay = bvec[i * 3 + 1], az = bvec[i * 3 + 2];
  float bx = bvec[j * 3], by = bvec[j * 3 + 1], bz = bvec[j * 3 + 2];
  float ct = (ax * bx + ay * by + az * bz) / (bdist[i] * bdist[j]);
  float tw = cut3[i] * cut3[j];
  float sh[3];
  sh[0] = 0.28209479177387814f * tw;
  sh[1] = 0.4886025119029199f * ct * tw;
  sh[2] = 0.31539156525252005f * (3.0f * ct * ct - 1.0f) * tw;
  int pos = atomicAdd(&cur_e[i], 1);
#pragma unroll
  for (int l = 0; l < 3; ++l)
#pragma unroll
    for (int n = 0; n < 3; ++n)
      stbp[(size_t)pos * 9 + l * 3 + n] = rbf[j * 9 + l * 3 + n] * sh[l];
  sa[pos] = dst[j];
}

// nb[e][d] = sum over triplets p of edge e: stbp[p][d] * atoms[sa[p]][d]
__global__ void nb_reduce_kernel(const float* __restrict__ stbp, const int* __restrict__ sa,
                                 const float* __restrict__ atoms, const int* __restrict__ off_e,
                                 const int* __restrict__ cnt_e, float* __restrict__ nb, int E) {
  int i = blockIdx.x * 256 + threadIdx.x;
  if (i >= E * 9) return;
  int e = i / 9, d = i - e * 9;
  int o = off_e[e], c = cnt_e[e];
  float acc = 0.f;
  for (int p = o; p < o + c; ++p) acc += stbp[(size_t)p * 9 + d] * atoms[sa[p] * 9 + d];
  nb[i] = acc;
}

// ---------------- three-body block kernels ----------------
__global__ void atoms_kernel(const float* __restrict__ nf, const float* __restrict__ W,
                             const float* __restrict__ B, float* __restrict__ atoms, int N) {
  int i = blockIdx.x * 256 + threadIdx.x;
  if (i >= N * 9) return;
  int n = i / 9, d = i - n * 9;
  float acc = B[d];
  for (int c = 0; c < 128; ++c) acc += nf[n * 128 + c] * W[c * 9 + d];
  atoms[i] = sigm(acc);
}

__global__ void tb_update_kernel(const float* __restrict__ nb, const float* __restrict__ W,
                                 const float* __restrict__ Wg, float* __restrict__ ef, int E) {
  int i = blockIdx.x * 256 + threadIdx.x;
  if (i >= E * 128) return;
  int e = i >> 7, c = i & 127;
  float n9[9];
#pragma unroll
  for (int d = 0; d < 9; ++d) n9[d] = nb[e * 9 + d];
  float a = 0.f, b = 0.f;
#pragma unroll
  for (int d = 0; d < 9; ++d) {
    a += n9[d] * W[d * 128 + c];
    b += n9[d] * Wg[d * 128 + c];
  }
  ef[i] += silu(a) * sigm(b);
}

// ---------------- weight packing: f32 [K][128] -> bf16 fragment-major ----------------
__global__ void pack_kernel(const float* __restrict__ Wf, short* __restrict__ Wp, int K,
                            int units) {
  int per = 8 * (K / 32) * 64;
  int idx = blockIdx.x * 256 + threadIdx.x;
  if (idx >= units * per) return;
  int u = idx / per, r = idx - u * per;
  int lane = r & 63, tile = r >> 6;
  int kt = tile % (K / 32), nt = tile / (K / 32);
  int n = nt * 16 + (lane & 15);
  int k0 = kt * 32 + (lane >> 4) * 8;
  const float* src = Wf + (size_t)u * K * 128;
  bf16x8 v;
#pragma unroll
  for (int e = 0; e < 8; ++e) v[e] = f2bf(src[(size_t)(k0 + e) * 128 + n]);
  *(bf16x8*)(Wp + (size_t)u * K * 128 + (size_t)tile * 512 + lane * 8) = v;
}

// ---------------- fused gated-MLP on MFMA ----------------
#define TE 32

__device__ __forceinline__ f32x4 mfma16(bf16x8 a, bf16x8 b, f32x4 c) {
  return __builtin_amdgcn_mfma_f32_16x16x32_bf16(a, b, c, 0, 0, 0);
}

__device__ __forceinline__ void layer128(const short* hin, const short* gin, int ld,
                                         const short* __restrict__ pW,
                                         const short* __restrict__ pG,
                                         const float* __restrict__ Bh,
                                         const float* __restrict__ Bg, int wave, int lane,
                                         f32x4 (&aW)[2][2], f32x4 (&aG)[2][2]) {
  const int lrow = lane & 15, lk = lane >> 4;
#pragma unroll
  for (int nt = 0; nt < 2; ++nt) {
    float bw = Bh[wave * 32 + nt * 16 + lrow];
    float bg = Bg[wave * 32 + nt * 16 + lrow];
#pragma unroll
    for (int mt = 0; mt < 2; ++mt) {
      aW[mt][nt] = {bw, bw, bw, bw};
      aG[mt][nt] = {bg, bg, bg, bg};
    }
  }
#pragma unroll
  for (int kt = 0; kt < 4; ++kt) {
    int aoff = kt * 32 + lk * 8;
    bf16x8 ah0 = *(const bf16x8*)(hin + (size_t)lrow * ld + aoff);
    bf16x8 ah1 = *(const bf16x8*)(hin + (size_t)(16 + lrow) * ld + aoff);
    bf16x8 ag0 = *(const bf16x8*)(gin + (size_t)lrow * ld + aoff);
    bf16x8 ag1 = *(const bf16x8*)(gin + (size_t)(16 + lrow) * ld + aoff);
    bf16x8 bw0 = *(const bf16x8*)(pW + ((wave * 2 + 0) * 4 + kt) * 512 + lane * 8);
    bf16x8 bw1 = *(const bf16x8*)(pW + ((wave * 2 + 1) * 4 + kt) * 512 + lane * 8);
    bf16x8 bg0 = *(const bf16x8*)(pG + ((wave * 2 + 0) * 4 + kt) * 512 + lane * 8);
    bf16x8 bg1 = *(const bf16x8*)(pG + ((wave * 2 + 1) * 4 + kt) * 512 + lane * 8);
    aW[0][0] = mfma16(ah0, bw0, aW[0][0]);
    aW[1][0] = mfma16(ah1, bw0, aW[1][0]);
    aW[0][1] = mfma16(ah0, bw1, aW[0][1]);
    aW[1][1] = mfma16(ah1, bw1, aW[1][1]);
    aG[0][0] = mfma16(ag0, bg0, aG[0][0]);
    aG[1][0] = mfma16(ag1, bg0, aG[1][0]);
    aG[0][1] = mfma16(ag0, bg1, aG[0][1]);
    aG[1][1] = mfma16(ag1, bg1, aG[1][1]);
  }
}

// MODE 0: ef[e] += out (block owns edges); MODE 1: mbuf[e][col] = out (plain store)
template <int MODE>
__global__ __launch_bounds__(256) void gmlp_mfma(
    const float* __restrict__ nf, float* __restrict__ ef, const float* __restrict__ rbf,
    const int* __restrict__ src, const int* __restrict__ dst,
    const short* __restrict__ pW0, const short* __restrict__ pG0,
    const short* __restrict__ pW1, const short* __restrict__ pG1,
    const short* __restrict__ pW2, const short* __restrict__ pG2,
    const float* __restrict__ B0, const float* __restrict__ Gb0,
    const float* __restrict__ B1, const float* __restrict__ Gb1,
    const float* __restrict__ B2, const float* __restrict__ Gb2,
    const float* __restrict__ WT, float* __restrict__ mbuf, int E) {
  __shared__ __align__(16) short xs[32][392];
  __shared__ __align__(16) short hs[32][136];
  __shared__ __align__(16) short gs[32][136];
  __shared__ float rs[32][12];
  const int tid = threadIdx.x;
  const int e0 = blockIdx.x * TE;

  // ---- gather x = [nf[src] | nf[dst] | ef] as bf16 ----
  {
    int r = tid >> 3, q = tid & 7;
    int e = e0 + r;
    if (e >= E) e = E - 1;
    const float* sp0 = nf + (size_t)src[e] * 128;
    const float* sp1 = nf + (size_t)dst[e] * 128;
    const float* sp2 = ef + (size_t)e * 128;
#pragma unroll
    for (int seg = 0; seg < 3; ++seg) {
      const float* sp = seg == 0 ? sp0 : (seg == 1 ? sp1 : sp2);
      int col = q * 16;
      float4 f0 = *(const float4*)(sp + col);
      float4 f1 = *(const float4*)(sp + col + 4);
      float4 f2 = *(const float4*)(sp + col + 8);
      float4 f3 = *(const float4*)(sp + col + 12);
      bf16x8 v0, v1;
      v0[0] = f2bf(f0.x); v0[1] = f2bf(f0.y); v0[2] = f2bf(f0.z); v0[3] = f2bf(f0.w);
      v0[4] = f2bf(f1.x); v0[5] = f2bf(f1.y); v0[6] = f2bf(f1.z); v0[7] = f2bf(f1.w);
      v1[0] = f2bf(f2.x); v1[1] = f2bf(f2.y); v1[2] = f2bf(f2.z); v1[3] = f2bf(f2.w);
      v1[4] = f2bf(f3.x); v1[5] = f2bf(f3.y); v1[6] = f2bf(f3.z); v1[7] = f2bf(f3.w);
      *(bf16x8*)&xs[r][seg * 128 + col] = v0;
      *(bf16x8*)&xs[r][seg * 128 + col + 8] = v1;
    }
    for (int idx = tid; idx < 32 * 9; idx += 256) {
      int rr = idx / 9, d = idx - rr * 9;
      int ee = e0 + rr; if (ee >= E) ee = E - 1;
      rs[rr][d] = rbf[ee * 9 + d];
    }
  }
  __syncthreads();

  const int wave = tid >> 6;
  const int lane = tid & 63;
  const int lrow = lane & 15, lk = lane >> 4;
  f32x4 aW[2][2], aG[2][2];

  // ---- layer 0: K=384, shared A ----
#pragma unroll
  for (int nt = 0; nt < 2; ++nt) {
    float bw = B0[wave * 32 + nt * 16 + lrow];
    float bg = Gb0[wave * 32 + nt * 16 + lrow];
#pragma unroll
    for (int mt = 0; mt < 2; ++mt) {
      aW[mt][nt] = {bw, bw, bw, bw};
      aG[mt][nt] = {bg, bg, bg, bg};
    }
  }
  for (int kt = 0; kt < 12; ++kt) {
    int aoff = kt * 32 + lk * 8;
    bf16x8 a0 = *(const bf16x8*)&xs[lrow][aoff];
    bf16x8 a1 = *(const bf16x8*)&xs[16 + lrow][aoff];
    bf16x8 bw0 = *(const bf16x8*)(pW0 + ((wave * 2 + 0) * 12 + kt) * 512 + lane * 8);
    bf16x8 bw1 = *(const bf16x8*)(pW0 + ((wave * 2 + 1) * 12 + kt) * 512 + lane * 8);
    bf16x8 bg0 = *(const bf16x8*)(pG0 + ((wave * 2 + 0) * 12 + kt) * 512 + lane * 8);
    bf16x8 bg1 = *(const bf16x8*)(pG0 + ((wave * 2 + 1) * 12 + kt) * 512 + lane * 8);
    aW[0][0] = mfma16(a0, bw0, aW[0][0]);
    aW[1][0] = mfma16(a1, bw0, aW[1][0]);
    aW[0][1] = mfma16(a0, bw1, aW[0][1]);
    aW[1][1] = mfma16(a1, bw1, aW[1][1]);
    aG[0][0] = mfma16(a0, bg0, aG[0][0]);
    aG[1][0] = mfma16(a1, bg0, aG[1][0]);
    aG[0][1] = mfma16(a0, bg1, aG[0][1]);
    aG[1][1] = mfma16(a1, bg1, aG[1][1]);
  }
#pragma unroll
  for (int mt = 0; mt < 2; ++mt)
#pragma unroll
    for (int nt = 0; nt < 2; ++nt) {
      int col = wave * 32 + nt * 16 + lrow;
#pragma unroll
      for (int rg = 0; rg < 4; ++rg) {
        int row = mt * 16 + lk * 4 + rg;
        hs[row][col] = f2bf(silu(aW[mt][nt][rg]));
        gs[row][col] = f2bf(silu(aG[mt][nt][rg]));
      }
    }
  __syncthreads();

  // ---- layer 1: K=128 ----
  layer128(&hs[0][0], &gs[0][0], 136, pW1, pG1, B1, Gb1, wave, lane, aW, aG);
  short* h1 = &xs[0][0];
  short* g1 = h1 + 32 * 136;
#pragma unroll
  for (int mt = 0; mt < 2; ++mt)
#pragma unroll
    for (int nt = 0; nt < 2; ++nt) {
      int col = wave * 32 + nt * 16 + lrow;
#pragma unroll
      for (int rg = 0; rg < 4; ++rg) {
        int row = mt * 16 + lk * 4 + rg;
        h1[row * 136 + col] = f2bf(silu(aW[mt][nt][rg]));
        g1[row * 136 + col] = f2bf(silu(aG[mt][nt][rg]));
      }
    }
  __syncthreads();

  // ---- layer 2: K=128 ----
  layer128(h1, g1, 136, pW2, pG2, B2, Gb2, wave, lane, aW, aG);

  // ---- epilogue: silu(h2)*sigmoid(g2) * (rbf @ wt) ----
  float wtc[2][9];
#pragma unroll
  for (int nt = 0; nt < 2; ++nt) {
    int col = wave * 32 + nt * 16 + lrow;
#pragma unroll
    for (int d = 0; d < 9; ++d) wtc[nt][d] = WT[d * 128 + col];
  }
#pragma unroll
  for (int mt = 0; mt < 2; ++mt)
#pragma unroll
    for (int rg = 0; rg < 4; ++rg) {
      int row = mt * 16 + lk * 4 + rg;
      int e = e0 + row;
      float rv[9];
#pragma unroll
      for (int d = 0; d < 9; ++d) rv[d] = rs[row][d];
#pragma unroll
      for (int nt = 0; nt < 2; ++nt) {
        int col = wave * 32 + nt * 16 + lrow;
        float wv = 0.f;
#pragma unroll
        for (int d = 0; d < 9; ++d) wv = fmaf(rv[d], wtc[nt][d], wv);
        float v = silu(aW[mt][nt][rg]) * sigm(aG[mt][nt][rg]) * wv;
        if (e < E) {
          if (MODE == 0) ef[(size_t)e * 128 + col] += v;
          else mbuf[(size_t)e * 128 + col] = v;
        }
      }
    }
}

// nf[n] += sum over edges e with dst[e]==n of mbuf[e]
__global__ void node_gather_kernel(float* __restrict__ nf, const float* __restrict__ mbuf,
                                   const int* __restrict__ off_n, const int* __restrict__ cnt_n,
                                   const int* __restrict__ eperm, int N) {
  int n = blockIdx.x * 2 + (threadIdx.x >> 7);
  int c = threadIdx.x & 127;
  if (n >= N) return;
  int o = off_n[n], cnt = cnt_n[n];
  float acc = 0.f;
  for (int p = o; p < o + cnt; ++p) acc += mbuf[(size_t)eperm[p] * 128 + c];
  nf[(size_t)n * 128 + c] += acc;
}

// ---------------- readout ----------------
__global__ void mean_kernel(const float* __restrict__ nf, float* __restrict__ partial, int N) {
  __shared__ float sm[256];
  int n0 = blockIdx.x * 256;
  int col = threadIdx.x & 127, half = threadIdx.x >> 7;
  int nend = n0 + 256 < N ? n0 + 256 : N;
  float s = 0.f;
  for (int n = n0 + half; n < nend; n += 2) s += nf[n * 128 + col];
  sm[threadIdx.x] = s;
  __syncthreads();
  if (threadIdx.x < 128)
    partial[blockIdx.x * 128 + threadIdx.x] = sm[threadIdx.x] + sm[threadIdx.x + 128];
}

__global__ void final_kernel(const float* __restrict__ partial, int nchunks, float Nf,
                             const float* __restrict__ fW0, const float* __restrict__ fb0,
                             const float* __restrict__ fW1, const float* __restrict__ fb1,
                             const float* __restrict__ fW2, const float* __restrict__ fb2,
                             float* __restrict__ out) {
  __shared__ float v[128], h[128], red[128];
  int tid = threadIdx.x;  // 128 threads
  float s = 0.f;
  for (int b = 0; b < nchunks; ++b) s += partial[b * 128 + tid];
  v[tid] = s / Nf;
  __syncthreads();
  float acc = fb0[tid];
  for (int c = 0; c < 128; ++c) acc += v[c] * fW0[c * 128 + tid];
  h[tid] = silu(acc);
  __syncthreads();
  acc = fb1[tid];
  for (int c = 0; c < 128; ++c) acc += h[c] * fW1[c * 128 + tid];
  __syncthreads();
  v[tid] = silu(acc);
  __syncthreads();
  red[tid] = v[tid] * fW2[tid];
  __syncthreads();
  for (int st = 64; st > 0; st >>= 1) {
    if (tid < st) red[tid] += red[tid + st];
    __syncthreads();
  }
  if (tid == 0) out[0] = red[0] + fb2[0];
}

// ---------------- launch ----------------
extern "C" void kernel_launch(void* const* d_in, const int* in_sizes, int n_in,
                              void* d_out, int out_size, void* d_ws, size_t ws_size,
                              hipStream_t stream) {
  const float* pos = (const float*)d_in[0];
  const int* node_type = (const int*)d_in[1];
  const int* src = (const int*)d_in[2];
  const int* dst = (const int*)d_in[3];
  const int* t_src = (const int*)d_in[4];
  const int* t_dst = (const int*)d_in[5];
  const float* emb = (const float*)d_in[6];
  const float* eW = (const float*)d_in[7];
  const float* eB = (const float*)d_in[8];
  const float* taW = (const float*)d_in[9];
  const float* taB = (const float*)d_in[10];
  const float* tbW = (const float*)d_in[11];
  const float* tbG = (const float*)d_in[12];
  const float* W0 = (const float*)d_in[13]; const float* B0 = (const float*)d_in[14];
  const float* W1 = (const float*)d_in[15]; const float* B1 = (const float*)d_in[16];
  const float* W2 = (const float*)d_in[17]; const float* B2 = (const float*)d_in[18];
  const float* G0 = (const float*)d_in[19]; const float* Gb0 = (const float*)d_in[20];
  const float* G1 = (const float*)d_in[21]; const float* Gb1 = (const float*)d_in[22];
  const float* G2 = (const float*)d_in[23]; const float* Gb2 = (const float*)d_in[24];
  const float* WT = (const float*)d_in[25];
  const float* fW0 = (const float*)d_in[26]; const float* fb0 = (const float*)d_in[27];
  const float* fW1 = (const float*)d_in[28]; const float* fb1 = (const float*)d_in[29];
  const float* fW2 = (const float*)d_in[30]; const float* fb2 = (const float*)d_in[31];

  const int N = in_sizes[1];
  const int E = in_sizes[2];
  const int T = in_sizes[4];

  char* p = (char*)d_ws;
  auto alloc = [&](size_t bytes) -> char* {
    char* r = p;
    p += (bytes + 255) & ~(size_t)255;
    return r;
  };
  float* nf    = (float*)alloc((size_t)N * 128 * 4);
  float* ef    = (float*)alloc((size_t)E * 128 * 4);
  float* mbuf  = (float*)alloc((size_t)E * 128 * 4);
  float* rbf   = (float*)alloc((size_t)E * 9 * 4);
  float* bvec  = (float*)alloc((size_t)E * 3 * 4);
  float* bdist = (float*)alloc((size_t)E * 4);
  float* cut3  = (float*)alloc((size_t)E * 4);
  float* stbp  = (float*)alloc((size_t)T * 9 * 4);
  int*   sa    = (int*)alloc((size_t)T * 4);
  float* atoms = (float*)alloc((size_t)N * 9 * 4);
  float* nb    = (float*)alloc((size_t)E * 9 * 4);
  float* part  = (float*)alloc((size_t)64 * 128 * 4);
  // CSR arrays
  int* cnt_e  = (int*)alloc((size_t)E * 4);
  int* incl_e = (int*)alloc((size_t)E * 4);
  int* off_e  = (int*)alloc((size_t)E * 4);
  int* cur_e  = (int*)alloc((size_t)E * 4);
  int* cnt_n  = (int*)alloc((size_t)N * 4);
  int* incl_n = (int*)alloc((size_t)N * 4);
  int* off_n  = (int*)alloc((size_t)N * 4);
  int* cur_n  = (int*)alloc((size_t)N * 4);
  int* eperm  = (int*)alloc((size_t)E * 4);
  int* bsum   = (int*)alloc((size_t)1024 * 4);
  // packed bf16 weights
  short* pW0s = (short*)alloc((size_t)6 * 384 * 128 * 2);
  short* pG0s = (short*)alloc((size_t)6 * 384 * 128 * 2);
  short* pW1s = (short*)alloc((size_t)6 * 128 * 128 * 2);
  short* pG1s = (short*)alloc((size_t)6 * 128 * 128 * 2);
  short* pW2s = (short*)alloc((size_t)6 * 128 * 128 * 2);
  short* pG2s = (short*)alloc((size_t)6 * 128 * 128 * 2);
  (void)ws_size; (void)n_in; (void)out_size;

  // pack all gMLP weights once
  {
    int t384 = 6 * 8 * 12 * 64, t128 = 6 * 8 * 4 * 64;
    pack_kernel<<<(t384 + 255) / 256, 256, 0, stream>>>(W0, pW0s, 384, 6);
    pack_kernel<<<(t384 + 255) / 256, 256, 0, stream>>>(G0, pG0s, 384, 6);
    pack_kernel<<<(t128 + 255) / 256, 256, 0, stream>>>(W1, pW1s, 128, 6);
    pack_kernel<<<(t128 + 255) / 256, 256, 0, stream>>>(G1, pG1s, 128, 6);
    pack_kernel<<<(t128 + 255) / 256, 256, 0, stream>>>(W2, pW2s, 128, 6);
    pack_kernel<<<(t128 + 255) / 256, 256, 0, stream>>>(G2, pG2s, 128, 6);
  }

  node_init_kernel<<<(N * 128 + 255) / 256, 256, 0, stream>>>(node_type, emb, nf, N);
  edge_geom_kernel<<<(E + 255) / 256, 256, 0, stream>>>(pos, src, dst, bvec, bdist, rbf, cut3, E);
  edge_emb_kernel<<<(E * 128 + 255) / 256, 256, 0, stream>>>(rbf, eW, eB, ef, E);

  // ---- build edge-CSR (triplets by t_src) and node-CSR (edges by dst) ----
  const int ebk = (E + 255) / 256, nbk = (N + 255) / 256;
  hipMemsetAsync(cnt_e, 0, (size_t)E * 4, stream);
  hipMemsetAsync(cnt_n, 0, (size_t)N * 4, stream);
  count_kernel<<<(T + 255) / 256, 256, 0, stream>>>(t_src, cnt_e, T);
  count_kernel<<<ebk, 256, 0, stream>>>(dst, cnt_n, E);
  scan_block_kernel<<<ebk, 256, 0, stream>>>(cnt_e, incl_e, bsum, E);
  scan_top_kernel<<<1, 1024, 0, stream>>>(bsum, ebk);
  scan_finalize_kernel<<<ebk, 256, 0, stream>>>(cnt_e, incl_e, bsum, off_e, cur_e, E);
  scan_block_kernel<<<nbk, 256, 0, stream>>>(cnt_n, incl_n, bsum, N);
  scan_top_kernel<<<1, 1024, 0, stream>>>(bsum, nbk);
  scan_finalize_kernel<<<nbk, 256, 0, stream>>>(cnt_n, incl_n, bsum, off_n, cur_n, N);
  trip_sorted_kernel<<<(T + 255) / 256, 256, 0, stream>>>(t_src, t_dst, dst, bvec, bdist, rbf,
                                                          cut3, cur_e, stbp, sa, T);
  fill_eperm_kernel<<<ebk, 256, 0, stream>>>(dst, cur_n, eperm, E);

  const int gblocks = (E + TE - 1) / TE;
  for (int k = 0; k < 3; ++k) {
    atoms_kernel<<<(N * 9 + 255) / 256, 256, 0, stream>>>(nf, taW + (size_t)k * 128 * 9,
                                                          taB + (size_t)k * 9, atoms, N);
    nb_reduce_kernel<<<(E * 9 + 255) / 256, 256, 0, stream>>>(stbp, sa, atoms, off_e, cnt_e, nb, E);
    tb_update_kernel<<<(E * 128 + 255) / 256, 256, 0, stream>>>(
        nb, tbW + (size_t)k * 9 * 128, tbG + (size_t)k * 9 * 128, ef, E);

    size_t u0 = (size_t)(k * 2 + 0);
    gmlp_mfma<0><<<gblocks, 256, 0, stream>>>(
        nf, ef, rbf, src, dst,
        pW0s + u0 * 384 * 128, pG0s + u0 * 384 * 128,
        pW1s + u0 * 128 * 128, pG1s + u0 * 128 * 128,
        pW2s + u0 * 128 * 128, pG2s + u0 * 128 * 128,
        B0 + u0 * 128, Gb0 + u0 * 128, B1 + u0 * 128, Gb1 + u0 * 128,
        B2 + u0 * 128, Gb2 + u0 * 128,
        WT + u0 * 9 * 128, mbuf, E);

    size_t u1 = u0 + 1;
    gmlp_mfma<1><<<gblocks, 256, 0, stream>>>(
        nf, ef, rbf, src, dst,
        pW0s + u1 * 384 * 128, pG0s + u1 * 384 * 128,
        pW1s + u1 * 128 * 128, pG1s + u1 * 128 * 128,
        pW2s + u1 * 128 * 128, pG2s + u1 * 128 * 128,
        B0 + u1 * 128, Gb0 + u1 * 128, B1 + u1 * 128, Gb1 + u1 * 128,
        B2 + u1 * 128, Gb2 + u1 * 128,
        WT + u1 * 9 * 128, mbuf, E);
    node_gather_kernel<<<(N + 1) / 2, 256, 0, stream>>>(nf, mbuf, off_n, cnt_n, eperm, N);
  }

  int nchunks = (N + 255) / 256;
  mean_kernel<<<nchunks, 256, 0, stream>>>(nf, part, N);
  final_kernel<<<1, 128, 0, stream>>>(part, nchunks, (float)N, fW0, fb0, fW1, fb1, fW2, fb2,
                                      (float*)d_out);
}

// Round 5
// 725.382 us; speedup vs baseline: 5.8942x; 1.0320x over previous
//
#include <hip/hip_runtime.h>
#include <stdint.h>

typedef __attribute__((ext_vector_type(8))) short bf16x8;
typedef __attribute__((ext_vector_type(4))) float f32x4;

// ---------------- helpers ----------------
__device__ __forceinline__ float sigm(float x) { return __fdividef(1.0f, 1.0f + __expf(-x)); }
__device__ __forceinline__ float silu(float x) { return __fdividef(x, 1.0f + __expf(-x)); }
__device__ __forceinline__ short f2bf(float f) {  // RNE f32->bf16
  uint32_t u = __float_as_uint(f);
  u = (u + 0x7fffu + ((u >> 16) & 1u)) >> 16;
  return (short)u;
}

// spherical bessel j_l, matches reference _jl
__device__ __forceinline__ float jl_eval(int l, float x) {
  float s, c;
  sincosf(x, &s, &c);
  float ix = 1.0f / x, ix2 = ix * ix;
  if (l == 0) return s * ix;
  if (l == 1) return s * ix2 - c * ix;
  if (l == 2) return (3.0f * ix2 * ix - ix) * s - 3.0f * ix2 * c;
  return (15.0f * ix2 * ix2 - 6.0f * ix2) * s - (15.0f * ix2 * ix - ix) * c;
}

// ---------------- init / geometry kernels ----------------
__global__ void node_init_kernel(const int* __restrict__ nt, const float* __restrict__ emb,
                                 float* __restrict__ nf, int N) {
  int i = blockIdx.x * 256 + threadIdx.x;
  if (i >= N * 128) return;
  int n = i >> 7, c = i & 127;
  nf[i] = emb[nt[n] * 128 + c];
}

__global__ void edge_geom_kernel(const float* __restrict__ pos, const int* __restrict__ src,
                                 const int* __restrict__ dst, float* __restrict__ bvec,
                                 float* __restrict__ bdist, float* __restrict__ rbf,
                                 float* __restrict__ cut3, int E) {
  int e = blockIdx.x * 256 + threadIdx.x;
  if (e >= E) return;
  int s = src[e], d = dst[e];
  float dx = pos[d * 3 + 0] - pos[s * 3 + 0];
  float dy = pos[d * 3 + 1] - pos[s * 3 + 1];
  float dz = pos[d * 3 + 2] - pos[s * 3 + 2];
  float r = sqrtf(dx * dx + dy * dy + dz * dz + 1e-12f);
  bvec[e * 3 + 0] = dx; bvec[e * 3 + 1] = dy; bvec[e * 3 + 2] = dz;
  bdist[e] = r;
  const float roots[3][3] = {
      {3.141592653589793f, 6.283185307179586f, 9.42477796076938f},
      {4.493409457909064f, 7.725251836937707f, 10.904121659428899f},
      {5.763459196894550f, 9.095011330476355f, 12.322940970566582f}};
#pragma unroll
  for (int l = 0; l < 3; ++l) {
#pragma unroll
    for (int n = 0; n < 3; ++n) {
      float root = roots[l][n];
      float x = r * (root * 0.2f);                  // r * root / CUTOFF(5)
      float norm = fabsf(jl_eval(l + 1, root));     // SBF_NORM
      rbf[e * 9 + l * 3 + n] = jl_eval(l, x) * (0.12649110640673518f / norm);
    }
  }
  float xx = r * 0.25f;  // r / TB_CUTOFF(4)
  float x3 = xx * xx * xx;
  cut3[e] = 1.0f - 6.0f * x3 * xx * xx + 15.0f * x3 * xx - 10.0f * x3;
}

__global__ void edge_emb_kernel(const float* __restrict__ rbf, const float* __restrict__ W,
                                const float* __restrict__ B, float* __restrict__ ef, int E) {
  int i = blockIdx.x * 256 + threadIdx.x;
  if (i >= E * 128) return;
  int e = i >> 7, c = i & 127;
  float acc = B[c];
#pragma unroll
  for (int d = 0; d < 9; ++d) acc += rbf[e * 9 + d] * W[d * 128 + c];
  ef[i] = silu(acc);
}

// ---------------- CSR build: count / scan / finalize ----------------
__global__ void count_kernel(const int* __restrict__ idx, int* __restrict__ cnt, int L) {
  int i = blockIdx.x * 256 + threadIdx.x;
  if (i < L) atomicAdd(&cnt[idx[i]], 1);
}

__global__ void scan_block_kernel(const int* __restrict__ in, int* __restrict__ incl,
                                  int* __restrict__ bsum, int L) {
  __shared__ int sm[256];
  int i = blockIdx.x * 256 + threadIdx.x;
  int v = i < L ? in[i] : 0;
  sm[threadIdx.x] = v;
  __syncthreads();
  for (int st = 1; st < 256; st <<= 1) {
    int t = threadIdx.x >= st ? sm[threadIdx.x - st] : 0;
    __syncthreads();
    sm[threadIdx.x] += t;
    __syncthreads();
  }
  if (i < L) incl[i] = sm[threadIdx.x];
  if (threadIdx.x == 255) bsum[blockIdx.x] = sm[255];
}

__global__ void scan_top_kernel(int* __restrict__ bsum, int nb) {  // in-place exclusive
  __shared__ int sm[1024];
  int tid = threadIdx.x;
  int orig = tid < nb ? bsum[tid] : 0;
  sm[tid] = orig;
  __syncthreads();
  for (int st = 1; st < 1024; st <<= 1) {
    int t = tid >= st ? sm[tid - st] : 0;
    __syncthreads();
    sm[tid] += t;
    __syncthreads();
  }
  if (tid < nb) bsum[tid] = sm[tid] - orig;
}

__global__ void scan_finalize_kernel(const int* __restrict__ cnt, const int* __restrict__ incl,
                                     const int* __restrict__ bexcl, int* __restrict__ off,
                                     int* __restrict__ cur, int L) {
  int i = blockIdx.x * 256 + threadIdx.x;
  if (i >= L) return;
  int o = incl[i] - cnt[i] + bexcl[blockIdx.x];
  off[i] = o;
  cur[i] = o;
}

__global__ void fill_eperm_kernel(const int* __restrict__ dst, int* __restrict__ cur_n,
                                  int* __restrict__ eperm, int E) {
  int e = blockIdx.x * 256 + threadIdx.x;
  if (e >= E) return;
  int pos = atomicAdd(&cur_n[dst[e]], 1);
  eperm[pos] = e;
}

// triplet precompute, written directly to CSR-sorted position (by t_src)
__global__ void trip_sorted_kernel(const int* __restrict__ t_src, const int* __restrict__ t_dst,
                                   const int* __restrict__ dst, const float* __restrict__ bvec,
                                   const float* __restrict__ bdist, const float* __restrict__ rbf,
                                   const float* __restrict__ cut3, int* __restrict__ cur_e,
                                   float* __restrict__ stbp, int* __restrict__ sa, int T) {
  int t = blockIdx.x * 256 + threadIdx.x;
  if (t >= T) return;
  int i = t_src[t], j = t_dst[t];
  float ax = bvec[i * 3], ay = bvec[i * 3 + 1], az = bvec[i * 3 + 2];
  float bx = bvec[j * 3], by = bvec[j * 3 + 1], bz = bvec[j * 3 + 2];
  float ct = (ax * bx + ay * by + az * bz) / (bdist[i] * bdist[j]);
  float tw = cut3[i] * cut3[j];
  float sh[3];
  sh[0] = 0.28209479177387814f * tw;
  sh[1] = 0.4886025119029199f * ct * tw;
  sh[2] = 0.31539156525252005f * (3.0f * ct * ct - 1.0f) * tw;
  int pos = atomicAdd(&cur_e[i], 1);
#pragma unroll
  for (int l = 0; l < 3; ++l)
#pragma unroll
    for (int n = 0; n < 3; ++n)
      stbp[(size_t)pos * 9 + l * 3 + n] = rbf[j * 9 + l * 3 + n] * sh[l];
  sa[pos] = dst[j];
}

// nb[e][d] = sum over triplets p of edge e: stbp[p][d] * atoms[sa[p]][d]
__global__ void nb_reduce_kernel(const float* __restrict__ stbp, const int* __restrict__ sa,
                                 const float* __restrict__ atoms, const int* __restrict__ off_e,
                                 const int* __restrict__ cnt_e, float* __restrict__ nb, int E) {
  int i = blockIdx.x * 256 + threadIdx.x;
  if (i >= E * 9) return;
  int e = i / 9, d = i - e * 9;
  int o = off_e[e], c = cnt_e[e];
  float acc = 0.f;
  for (int p = o; p < o + c; ++p) acc += stbp[(size_t)p * 9 + d] * atoms[sa[p] * 9 + d];
  nb[i] = acc;
}

__global__ void atoms_kernel(const float* __restrict__ nf, const float* __restrict__ W,
                             const float* __restrict__ B, float* __restrict__ atoms, int N) {
  int i = blockIdx.x * 256 + threadIdx.x;
  if (i >= N * 9) return;
  int n = i / 9, d = i - n * 9;
  float acc = B[d];
  for (int c = 0; c < 128; ++c) acc += nf[n * 128 + c] * W[c * 9 + d];
  atoms[i] = sigm(acc);
}

// ---------------- weight packing: f32 [K][128] -> bf16 fragment-major ----------------
__global__ void pack_kernel(const float* __restrict__ Wf, short* __restrict__ Wp, int K,
                            int units) {
  int per = 8 * (K / 32) * 64;
  int idx = blockIdx.x * 256 + threadIdx.x;
  if (idx >= units * per) return;
  int u = idx / per, r = idx - u * per;
  int lane = r & 63, tile = r >> 6;
  int kt = tile % (K / 32), nt = tile / (K / 32);
  int n = nt * 16 + (lane & 15);
  int k0 = kt * 32 + (lane >> 4) * 8;
  const float* src = Wf + (size_t)u * K * 128;
  bf16x8 v;
#pragma unroll
  for (int e = 0; e < 8; ++e) v[e] = f2bf(src[(size_t)(k0 + e) * 128 + n]);
  *(bf16x8*)(Wp + (size_t)u * K * 128 + (size_t)tile * 512 + lane * 8) = v;
}

// ---------------- fused gated-MLP on MFMA ----------------
#define TE 32

__device__ __forceinline__ f32x4 mfma16(bf16x8 a, bf16x8 b, f32x4 c) {
  return __builtin_amdgcn_mfma_f32_16x16x32_bf16(a, b, c, 0, 0, 0);
}

__device__ __forceinline__ void layer128(const short* hin, const short* gin, int ld,
                                         const short* __restrict__ pW,
                                         const short* __restrict__ pG,
                                         const float* __restrict__ Bh,
                                         const float* __restrict__ Bg, int wave, int lane,
                                         f32x4 (&aW)[2][2], f32x4 (&aG)[2][2]) {
  const int lrow = lane & 15, lk = lane >> 4;
#pragma unroll
  for (int nt = 0; nt < 2; ++nt) {
    float bw = Bh[wave * 32 + nt * 16 + lrow];
    float bg = Bg[wave * 32 + nt * 16 + lrow];
#pragma unroll
    for (int mt = 0; mt < 2; ++mt) {
      aW[mt][nt] = {bw, bw, bw, bw};
      aG[mt][nt] = {bg, bg, bg, bg};
    }
  }
#pragma unroll
  for (int kt = 0; kt < 4; ++kt) {
    int aoff = kt * 32 + lk * 8;
    bf16x8 ah0 = *(const bf16x8*)(hin + (size_t)lrow * ld + aoff);
    bf16x8 ah1 = *(const bf16x8*)(hin + (size_t)(16 + lrow) * ld + aoff);
    bf16x8 ag0 = *(const bf16x8*)(gin + (size_t)lrow * ld + aoff);
    bf16x8 ag1 = *(const bf16x8*)(gin + (size_t)(16 + lrow) * ld + aoff);
    bf16x8 bw0 = *(const bf16x8*)(pW + ((wave * 2 + 0) * 4 + kt) * 512 + lane * 8);
    bf16x8 bw1 = *(const bf16x8*)(pW + ((wave * 2 + 1) * 4 + kt) * 512 + lane * 8);
    bf16x8 bg0 = *(const bf16x8*)(pG + ((wave * 2 + 0) * 4 + kt) * 512 + lane * 8);
    bf16x8 bg1 = *(const bf16x8*)(pG + ((wave * 2 + 1) * 4 + kt) * 512 + lane * 8);
    aW[0][0] = mfma16(ah0, bw0, aW[0][0]);
    aW[1][0] = mfma16(ah1, bw0, aW[1][0]);
    aW[0][1] = mfma16(ah0, bw1, aW[0][1]);
    aW[1][1] = mfma16(ah1, bw1, aW[1][1]);
    aG[0][0] = mfma16(ag0, bg0, aG[0][0]);
    aG[1][0] = mfma16(ag1, bg0, aG[1][0]);
    aG[0][1] = mfma16(ag0, bg1, aG[0][1]);
    aG[1][1] = mfma16(ag1, bg1, aG[1][1]);
  }
}

// full 3-layer gated chain; xs preserved, hs/gs used as double-duty scratch.
__device__ __forceinline__ void run_chain(
    const short* xsb, short* hsb, short* gsb,
    const short* __restrict__ pW0, const short* __restrict__ pG0,
    const short* __restrict__ pW1, const short* __restrict__ pG1,
    const short* __restrict__ pW2, const short* __restrict__ pG2,
    const float* __restrict__ B0, const float* __restrict__ Gb0,
    const float* __restrict__ B1, const float* __restrict__ Gb1,
    const float* __restrict__ B2, const float* __restrict__ Gb2,
    int wave, int lane, f32x4 (&aW)[2][2], f32x4 (&aG)[2][2]) {
  const int lrow = lane & 15, lk = lane >> 4;
  // ---- layer 0: K=384 ----
#pragma unroll
  for (int nt = 0; nt < 2; ++nt) {
    float bw = B0[wave * 32 + nt * 16 + lrow];
    float bg = Gb0[wave * 32 + nt * 16 + lrow];
#pragma unroll
    for (int mt = 0; mt < 2; ++mt) {
      aW[mt][nt] = {bw, bw, bw, bw};
      aG[mt][nt] = {bg, bg, bg, bg};
    }
  }
  for (int kt = 0; kt < 12; ++kt) {
    int aoff = kt * 32 + lk * 8;
    bf16x8 a0 = *(const bf16x8*)(xsb + (size_t)lrow * 392 + aoff);
    bf16x8 a1 = *(const bf16x8*)(xsb + (size_t)(16 + lrow) * 392 + aoff);
    bf16x8 bw0 = *(const bf16x8*)(pW0 + ((wave * 2 + 0) * 12 + kt) * 512 + lane * 8);
    bf16x8 bw1 = *(const bf16x8*)(pW0 + ((wave * 2 + 1) * 12 + kt) * 512 + lane * 8);
    bf16x8 bg0 = *(const bf16x8*)(pG0 + ((wave * 2 + 0) * 12 + kt) * 512 + lane * 8);
    bf16x8 bg1 = *(const bf16x8*)(pG0 + ((wave * 2 + 1) * 12 + kt) * 512 + lane * 8);
    aW[0][0] = mfma16(a0, bw0, aW[0][0]);
    aW[1][0] = mfma16(a1, bw0, aW[1][0]);
    aW[0][1] = mfma16(a0, bw1, aW[0][1]);
    aW[1][1] = mfma16(a1, bw1, aW[1][1]);
    aG[0][0] = mfma16(a0, bg0, aG[0][0]);
    aG[1][0] = mfma16(a1, bg0, aG[1][0]);
    aG[0][1] = mfma16(a0, bg1, aG[0][1]);
    aG[1][1] = mfma16(a1, bg1, aG[1][1]);
  }
#pragma unroll
  for (int mt = 0; mt < 2; ++mt)
#pragma unroll
    for (int nt = 0; nt < 2; ++nt) {
      int col = wave * 32 + nt * 16 + lrow;
#pragma unroll
      for (int rg = 0; rg < 4; ++rg) {
        int row = mt * 16 + lk * 4 + rg;
        hsb[row * 136 + col] = f2bf(silu(aW[mt][nt][rg]));
        gsb[row * 136 + col] = f2bf(silu(aG[mt][nt][rg]));
      }
    }
  __syncthreads();
  // ---- layer 1 (reads fully into regs, then overwrite hs/gs) ----
  layer128(hsb, gsb, 136, pW1, pG1, B1, Gb1, wave, lane, aW, aG);
  __syncthreads();
#pragma unroll
  for (int mt = 0; mt < 2; ++mt)
#pragma unroll
    for (int nt = 0; nt < 2; ++nt) {
      int col = wave * 32 + nt * 16 + lrow;
#pragma unroll
      for (int rg = 0; rg < 4; ++rg) {
        int row = mt * 16 + lk * 4 + rg;
        hsb[row * 136 + col] = f2bf(silu(aW[mt][nt][rg]));
        gsb[row * 136 + col] = f2bf(silu(aG[mt][nt][rg]));
      }
    }
  __syncthreads();
  // ---- layer 2 ----
  layer128(hsb, gsb, 136, pW2, pG2, B2, Gb2, wave, lane, aW, aG);
}

// Fused: tb_update (in gather) + edge-update chain + ef store + node-update chain.
__global__ __launch_bounds__(256) void gmlp_fused(
    const float* __restrict__ nf, float* __restrict__ ef, const float* __restrict__ rbf,
    const int* __restrict__ src, const int* __restrict__ dst,
    const float* __restrict__ nb, const float* __restrict__ tbW, const float* __restrict__ tbG,
    const short* __restrict__ pW0a, const short* __restrict__ pG0a,
    const short* __restrict__ pW1a, const short* __restrict__ pG1a,
    const short* __restrict__ pW2a, const short* __restrict__ pG2a,
    const float* __restrict__ B0a, const float* __restrict__ Gb0a,
    const float* __restrict__ B1a, const float* __restrict__ Gb1a,
    const float* __restrict__ B2a, const float* __restrict__ Gb2a,
    const float* __restrict__ WTa,
    const short* __restrict__ pW0b, const short* __restrict__ pG0b,
    const short* __restrict__ pW1b, const short* __restrict__ pG1b,
    const short* __restrict__ pW2b, const short* __restrict__ pG2b,
    const float* __restrict__ B0b, const float* __restrict__ Gb0b,
    const float* __restrict__ B1b, const float* __restrict__ Gb1b,
    const float* __restrict__ B2b, const float* __restrict__ Gb2b,
    const float* __restrict__ WTb,
    float* __restrict__ mbuf, int E) {
  __shared__ __align__(16) short xs[32][392];
  __shared__ __align__(16) short hs[32][136];
  __shared__ __align__(16) short gs[32][136];
  __shared__ float rs[32][12];
  __shared__ float stW[9 * 128], stG[9 * 128];
  const int tid = threadIdx.x;
  const int e0 = blockIdx.x * TE;
  const int r = tid >> 3, q = tid & 7;
  int eg = e0 + r; if (eg >= E) eg = E - 1;

  // stage tb weights + gather nf segments
  for (int i = tid; i < 9 * 128; i += 256) { stW[i] = tbW[i]; stG[i] = tbG[i]; }
  {
    const float* sp0 = nf + (size_t)src[eg] * 128;
    const float* sp1 = nf + (size_t)dst[eg] * 128;
#pragma unroll
    for (int seg = 0; seg < 2; ++seg) {
      const float* sp = seg == 0 ? sp0 : sp1;
      int col = q * 16;
      float4 f0 = *(const float4*)(sp + col);
      float4 f1 = *(const float4*)(sp + col + 4);
      float4 f2 = *(const float4*)(sp + col + 8);
      float4 f3 = *(const float4*)(sp + col + 12);
      bf16x8 v0, v1;
      v0[0] = f2bf(f0.x); v0[1] = f2bf(f0.y); v0[2] = f2bf(f0.z); v0[3] = f2bf(f0.w);
      v0[4] = f2bf(f1.x); v0[5] = f2bf(f1.y); v0[6] = f2bf(f1.z); v0[7] = f2bf(f1.w);
      v1[0] = f2bf(f2.x); v1[1] = f2bf(f2.y); v1[2] = f2bf(f2.z); v1[3] = f2bf(f2.w);
      v1[4] = f2bf(f3.x); v1[5] = f2bf(f3.y); v1[6] = f2bf(f3.z); v1[7] = f2bf(f3.w);
      *(bf16x8*)&xs[r][seg * 128 + col] = v0;
      *(bf16x8*)&xs[r][seg * 128 + col + 8] = v1;
    }
    for (int idx = tid; idx < 32 * 9; idx += 256) {
      int rr = idx / 9, d = idx - rr * 9;
      int ee = e0 + rr; if (ee >= E) ee = E - 1;
      rs[rr][d] = rbf[ee * 9 + d];
    }
  }
  __syncthreads();

  // ef segment with fused tb_update: ef_tb = ef + silu(nb@W)*sigm(nb@Wg)
  {
    float nb9[9];
#pragma unroll
    for (int d = 0; d < 9; ++d) nb9[d] = nb[eg * 9 + d];
    float fv[16];
    {
      const float4* fp = (const float4*)(ef + (size_t)eg * 128 + q * 16);
#pragma unroll
      for (int j = 0; j < 4; ++j) { float4 f = fp[j]; fv[4*j]=f.x; fv[4*j+1]=f.y; fv[4*j+2]=f.z; fv[4*j+3]=f.w; }
    }
    float a16[16], b16[16];
#pragma unroll
    for (int c = 0; c < 16; ++c) { a16[c] = 0.f; b16[c] = 0.f; }
#pragma unroll
    for (int d = 0; d < 9; ++d) {
      float nbd = nb9[d];
      const float4* wr = (const float4*)&stW[d * 128 + q * 16];
      const float4* gr = (const float4*)&stG[d * 128 + q * 16];
#pragma unroll
      for (int j = 0; j < 4; ++j) {
        float4 w = wr[j], g = gr[j];
        a16[4*j]   = fmaf(nbd, w.x, a16[4*j]);
        a16[4*j+1] = fmaf(nbd, w.y, a16[4*j+1]);
        a16[4*j+2] = fmaf(nbd, w.z, a16[4*j+2]);
        a16[4*j+3] = fmaf(nbd, w.w, a16[4*j+3]);
        b16[4*j]   = fmaf(nbd, g.x, b16[4*j]);
        b16[4*j+1] = fmaf(nbd, g.y, b16[4*j+1]);
        b16[4*j+2] = fmaf(nbd, g.z, b16[4*j+2]);
        b16[4*j+3] = fmaf(nbd, g.w, b16[4*j+3]);
      }
    }
    bf16x8 v0, v1;
#pragma unroll
    for (int c = 0; c < 16; ++c) {
      float val = fv[c] + silu(a16[c]) * sigm(b16[c]);
      if (c < 8) v0[c] = f2bf(val); else v1[c - 8] = f2bf(val);
    }
    *(bf16x8*)&xs[r][256 + q * 16] = v0;
    *(bf16x8*)&xs[r][256 + q * 16 + 8] = v1;
  }
  __syncthreads();

  const int wave = tid >> 6;
  const int lane = tid & 63;
  const int lrow = lane & 15, lk = lane >> 4;
  f32x4 aW[2][2], aG[2][2];

  // ---- chain 0: edge update ----
  run_chain(&xs[0][0], &hs[0][0], &gs[0][0], pW0a, pG0a, pW1a, pG1a, pW2a, pG2a,
            B0a, Gb0a, B1a, Gb1a, B2a, Gb2a, wave, lane, aW, aG);
  // epilogue 0: ef_new = ef_tb + silu*sigm*(rbf@wt); store ef, update xs ef-segment
  {
    float wtc[2][9];
#pragma unroll
    for (int nt = 0; nt < 2; ++nt) {
      int col = wave * 32 + nt * 16 + lrow;
#pragma unroll
      for (int d = 0; d < 9; ++d) wtc[nt][d] = WTa[d * 128 + col];
    }
#pragma unroll
    for (int mt = 0; mt < 2; ++mt)
#pragma unroll
      for (int rg = 0; rg < 4; ++rg) {
        int row = mt * 16 + lk * 4 + rg;
        int e = e0 + row;
        float rv[9];
#pragma unroll
        for (int d = 0; d < 9; ++d) rv[d] = rs[row][d];
#pragma unroll
        for (int nt = 0; nt < 2; ++nt) {
          int col = wave * 32 + nt * 16 + lrow;
          float wv = 0.f;
#pragma unroll
          for (int d = 0; d < 9; ++d) wv = fmaf(rv[d], wtc[nt][d], wv);
          float v = silu(aW[mt][nt][rg]) * sigm(aG[mt][nt][rg]) * wv;
          // xs ef-segment holds ef_tb (bf16); recover f32 approx from it
          uint32_t ub = ((uint32_t)(uint16_t)xs[row][256 + col]) << 16;
          float base = __uint_as_float(ub);
          float nv = base + v;
          if (e < E) ef[(size_t)e * 128 + col] = nv;
          xs[row][256 + col] = f2bf(nv);
        }
      }
  }
  __syncthreads();

  // ---- chain 1: node update ----
  run_chain(&xs[0][0], &hs[0][0], &gs[0][0], pW0b, pG0b, pW1b, pG1b, pW2b, pG2b,
            B0b, Gb0b, B1b, Gb1b, B2b, Gb2b, wave, lane, aW, aG);
  // epilogue 1: message -> mbuf
  {
    float wtc[2][9];
#pragma unroll
    for (int nt = 0; nt < 2; ++nt) {
      int col = wave * 32 + nt * 16 + lrow;
#pragma unroll
      for (int d = 0; d < 9; ++d) wtc[nt][d] = WTb[d * 128 + col];
    }
#pragma unroll
    for (int mt = 0; mt < 2; ++mt)
#pragma unroll
      for (int rg = 0; rg < 4; ++rg) {
        int row = mt * 16 + lk * 4 + rg;
        int e = e0 + row;
        float rv[9];
#pragma unroll
        for (int d = 0; d < 9; ++d) rv[d] = rs[row][d];
#pragma unroll
        for (int nt = 0; nt < 2; ++nt) {
          int col = wave * 32 + nt * 16 + lrow;
          float wv = 0.f;
#pragma unroll
          for (int d = 0; d < 9; ++d) wv = fmaf(rv[d], wtc[nt][d], wv);
          float v = silu(aW[mt][nt][rg]) * sigm(aG[mt][nt][rg]) * wv;
          if (e < E) mbuf[(size_t)e * 128 + col] = v;
        }
      }
  }
}

// nf[n] += sum over edges e with dst[e]==n of mbuf[e]
__global__ void node_gather_kernel(float* __restrict__ nf, const float* __restrict__ mbuf,
                                   const int* __restrict__ off_n, const int* __restrict__ cnt_n,
                                   const int* __restrict__ eperm, int N) {
  int n = blockIdx.x * 2 + (threadIdx.x >> 7);
  int c = threadIdx.x & 127;
  if (n >= N) return;
  int o = off_n[n], cnt = cnt_n[n];
  float acc = 0.f;
  for (int p = o; p < o + cnt; ++p) acc += mbuf[(size_t)eperm[p] * 128 + c];
  nf[(size_t)n * 128 + c] += acc;
}

// ---------------- readout ----------------
__global__ void mean_kernel(const float* __restrict__ nf, float* __restrict__ partial, int N) {
  __shared__ float sm[256];
  int n0 = blockIdx.x * 256;
  int col = threadIdx.x & 127, half = threadIdx.x >> 7;
  int nend = n0 + 256 < N ? n0 + 256 : N;
  float s = 0.f;
  for (int n = n0 + half; n < nend; n += 2) s += nf[n * 128 + col];
  sm[threadIdx.x] = s;
  __syncthreads();
  if (threadIdx.x < 128)
    partial[blockIdx.x * 128 + threadIdx.x] = sm[threadIdx.x] + sm[threadIdx.x + 128];
}

__global__ void final_kernel(const float* __restrict__ partial, int nchunks, float Nf,
                             const float* __restrict__ fW0, const float* __restrict__ fb0,
                             const float* __restrict__ fW1, const float* __restrict__ fb1,
                             const float* __restrict__ fW2, const float* __restrict__ fb2,
                             float* __restrict__ out) {
  __shared__ float v[128], h[128], red[128];
  int tid = threadIdx.x;  // 128 threads
  float s = 0.f;
  for (int b = 0; b < nchunks; ++b) s += partial[b * 128 + tid];
  v[tid] = s / Nf;
  __syncthreads();
  float acc = fb0[tid];
  for (int c = 0; c < 128; ++c) acc += v[c] * fW0[c * 128 + tid];
  h[tid] = silu(acc);
  __syncthreads();
  acc = fb1[tid];
  for (int c = 0; c < 128; ++c) acc += h[c] * fW1[c * 128 + tid];
  __syncthreads();
  v[tid] = silu(acc);
  __syncthreads();
  red[tid] = v[tid] * fW2[tid];
  __syncthreads();
  for (int st = 64; st > 0; st >>= 1) {
    if (tid < st) red[tid] += red[tid + st];
    __syncthreads();
  }
  if (tid == 0) out[0] = red[0] + fb2[0];
}

// ---------------- launch ----------------
extern "C" void kernel_launch(void* const* d_in, const int* in_sizes, int n_in,
                              void* d_out, int out_size, void* d_ws, size_t ws_size,
                              hipStream_t stream) {
  const float* pos = (const float*)d_in[0];
  const int* node_type = (const int*)d_in[1];
  const int* src = (const int*)d_in[2];
  const int* dst = (const int*)d_in[3];
  const int* t_src = (const int*)d_in[4];
  const int* t_dst = (const int*)d_in[5];
  const float* emb = (const float*)d_in[6];
  const float* eW = (const float*)d_in[7];
  const float* eB = (const float*)d_in[8];
  const float* taW = (const float*)d_in[9];
  const float* taB = (const float*)d_in[10];
  const float* tbW = (const float*)d_in[11];
  const float* tbG = (const float*)d_in[12];
  const float* W0 = (const float*)d_in[13]; const float* B0 = (const float*)d_in[14];
  const float* W1 = (const float*)d_in[15]; const float* B1 = (const float*)d_in[16];
  const float* W2 = (const float*)d_in[17]; const float* B2 = (const float*)d_in[18];
  const float* G0 = (const float*)d_in[19]; const float* Gb0 = (const float*)d_in[20];
  const float* G1 = (const float*)d_in[21]; const float* Gb1 = (const float*)d_in[22];
  const float* G2 = (const float*)d_in[23]; const float* Gb2 = (const float*)d_in[24];
  const float* WT = (const float*)d_in[25];
  const float* fW0 = (const float*)d_in[26]; const float* fb0 = (const float*)d_in[27];
  const float* fW1 = (const float*)d_in[28]; const float* fb1 = (const float*)d_in[29];
  const float* fW2 = (const float*)d_in[30]; const float* fb2 = (const float*)d_in[31];

  const int N = in_sizes[1];
  const int E = in_sizes[2];
  const int T = in_sizes[4];

  char* p = (char*)d_ws;
  auto alloc = [&](size_t bytes) -> char* {
    char* r = p;
    p += (bytes + 255) & ~(size_t)255;
    return r;
  };
  float* nf    = (float*)alloc((size_t)N * 128 * 4);
  float* ef    = (float*)alloc((size_t)E * 128 * 4);
  float* mbuf  = (float*)alloc((size_t)E * 128 * 4);
  float* rbf   = (float*)alloc((size_t)E * 9 * 4);
  float* bvec  = (float*)alloc((size_t)E * 3 * 4);
  float* bdist = (float*)alloc((size_t)E * 4);
  float* cut3  = (float*)alloc((size_t)E * 4);
  float* stbp  = (float*)alloc((size_t)T * 9 * 4);
  int*   sa    = (int*)alloc((size_t)T * 4);
  float* atoms = (float*)alloc((size_t)N * 9 * 4);
  float* nb    = (float*)alloc((size_t)E * 9 * 4);
  float* part  = (float*)alloc((size_t)64 * 128 * 4);
  int* cnt_e  = (int*)alloc((size_t)E * 4);
  int* incl_e = (int*)alloc((size_t)E * 4);
  int* off_e  = (int*)alloc((size_t)E * 4);
  int* cur_e  = (int*)alloc((size_t)E * 4);
  int* cnt_n  = (int*)alloc((size_t)N * 4);
  int* incl_n = (int*)alloc((size_t)N * 4);
  int* off_n  = (int*)alloc((size_t)N * 4);
  int* cur_n  = (int*)alloc((size_t)N * 4);
  int* eperm  = (int*)alloc((size_t)E * 4);
  int* bsum   = (int*)alloc((size_t)1024 * 4);
  short* pW0s = (short*)alloc((size_t)6 * 384 * 128 * 2);
  short* pG0s = (short*)alloc((size_t)6 * 384 * 128 * 2);
  short* pW1s = (short*)alloc((size_t)6 * 128 * 128 * 2);
  short* pG1s = (short*)alloc((size_t)6 * 128 * 128 * 2);
  short* pW2s = (short*)alloc((size_t)6 * 128 * 128 * 2);
  short* pG2s = (short*)alloc((size_t)6 * 128 * 128 * 2);
  (void)ws_size; (void)n_in; (void)out_size;

  {
    int t384 = 6 * 8 * 12 * 64, t128 = 6 * 8 * 4 * 64;
    pack_kernel<<<(t384 + 255) / 256, 256, 0, stream>>>(W0, pW0s, 384, 6);
    pack_kernel<<<(t384 + 255) / 256, 256, 0, stream>>>(G0, pG0s, 384, 6);
    pack_kernel<<<(t128 + 255) / 256, 256, 0, stream>>>(W1, pW1s, 128, 6);
    pack_kernel<<<(t128 + 255) / 256, 256, 0, stream>>>(G1, pG1s, 128, 6);
    pack_kernel<<<(t128 + 255) / 256, 256, 0, stream>>>(W2, pW2s, 128, 6);
    pack_kernel<<<(t128 + 255) / 256, 256, 0, stream>>>(G2, pG2s, 128, 6);
  }

  node_init_kernel<<<(N * 128 + 255) / 256, 256, 0, stream>>>(node_type, emb, nf, N);
  edge_geom_kernel<<<(E + 255) / 256, 256, 0, stream>>>(pos, src, dst, bvec, bdist, rbf, cut3, E);
  edge_emb_kernel<<<(E * 128 + 255) / 256, 256, 0, stream>>>(rbf, eW, eB, ef, E);

  const int ebk = (E + 255) / 256, nbk = (N + 255) / 256;
  hipMemsetAsync(cnt_e, 0, (size_t)E * 4, stream);
  hipMemsetAsync(cnt_n, 0, (size_t)N * 4, stream);
  count_kernel<<<(T + 255) / 256, 256, 0, stream>>>(t_src, cnt_e, T);
  count_kernel<<<ebk, 256, 0, stream>>>(dst, cnt_n, E);
  scan_block_kernel<<<ebk, 256, 0, stream>>>(cnt_e, incl_e, bsum, E);
  scan_top_kernel<<<1, 1024, 0, stream>>>(bsum, ebk);
  scan_finalize_kernel<<<ebk, 256, 0, stream>>>(cnt_e, incl_e, bsum, off_e, cur_e, E);
  scan_block_kernel<<<nbk, 256, 0, stream>>>(cnt_n, incl_n, bsum, N);
  scan_top_kernel<<<1, 1024, 0, stream>>>(bsum, nbk);
  scan_finalize_kernel<<<nbk, 256, 0, stream>>>(cnt_n, incl_n, bsum, off_n, cur_n, N);
  trip_sorted_kernel<<<(T + 255) / 256, 256, 0, stream>>>(t_src, t_dst, dst, bvec, bdist, rbf,
                                                          cut3, cur_e, stbp, sa, T);
  fill_eperm_kernel<<<ebk, 256, 0, stream>>>(dst, cur_n, eperm, E);

  const int gblocks = (E + TE - 1) / TE;
  for (int k = 0; k < 3; ++k) {
    atoms_kernel<<<(N * 9 + 255) / 256, 256, 0, stream>>>(nf, taW + (size_t)k * 128 * 9,
                                                          taB + (size_t)k * 9, atoms, N);
    nb_reduce_kernel<<<(E * 9 + 255) / 256, 256, 0, stream>>>(stbp, sa, atoms, off_e, cnt_e, nb, E);

    size_t u0 = (size_t)(k * 2 + 0), u1 = u0 + 1;
    gmlp_fused<<<gblocks, 256, 0, stream>>>(
        nf, ef, rbf, src, dst, nb, tbW + (size_t)k * 9 * 128, tbG + (size_t)k * 9 * 128,
        pW0s + u0 * 384 * 128, pG0s + u0 * 384 * 128, pW1s + u0 * 128 * 128,
        pG1s + u0 * 128 * 128, pW2s + u0 * 128 * 128, pG2s + u0 * 128 * 128,
        B0 + u0 * 128, Gb0 + u0 * 128, B1 + u0 * 128, Gb1 + u0 * 128, B2 + u0 * 128,
        Gb2 + u0 * 128, WT + u0 * 9 * 128,
        pW0s + u1 * 384 * 128, pG0s + u1 * 384 * 128, pW1s + u1 * 128 * 128,
        pG1s + u1 * 128 * 128, pW2s + u1 * 128 * 128, pG2s + u1 * 128 * 128,
        B0 + u1 * 128, Gb0 + u1 * 128, B1 + u1 * 128, Gb1 + u1 * 128, B2 + u1 * 128,
        Gb2 + u1 * 128, WT + u1 * 9 * 128,
        mbuf, E);
    node_gather_kernel<<<(N + 1) / 2, 256, 0, stream>>>(nf, mbuf, off_n, cnt_n, eperm, N);
  }

  int nchunks = (N + 255) / 256;
  mean_kernel<<<nchunks, 256, 0, stream>>>(nf, part, N);
  final_kernel<<<1, 128, 0, stream>>>(part, nchunks, (float)N, fW0, fb0, fW1, fb1, fW2, fb2,
                                      (float*)d_out);
}

// Round 6
// 586.718 us; speedup vs baseline: 7.2872x; 1.2363x over previous
//
#include <hip/hip_runtime.h>
#include <stdint.h>

typedef __attribute__((ext_vector_type(8))) short bf16x8;
typedef __attribute__((ext_vector_type(4))) float f32x4;
typedef __attribute__((ext_vector_type(4))) uint32_t u32x4;

// ---------------- helpers ----------------
__device__ __forceinline__ float sigm(float x) { return __fdividef(1.0f, 1.0f + __expf(-x)); }
__device__ __forceinline__ float silu(float x) { return __fdividef(x, 1.0f + __expf(-x)); }
__device__ __forceinline__ short f2bf(float f) {  // RNE f32->bf16 (pack path)
  uint32_t u = __float_as_uint(f);
  u = (u + 0x7fffu + ((u >> 16) & 1u)) >> 16;
  return (short)u;
}
// packed f32x2 -> bf16x2 in one instruction
__device__ __forceinline__ uint32_t cvt2(float lo, float hi) {
  uint32_t d;
  asm("v_cvt_pk_bf16_f32 %0, %1, %2" : "=v"(d) : "v"(lo), "v"(hi));
  return d;
}
__device__ __forceinline__ short f2bf1(float f) { return (short)cvt2(f, f); }

// spherical bessel j_l, matches reference _jl
__device__ __forceinline__ float jl_eval(int l, float x) {
  float s, c;
  sincosf(x, &s, &c);
  float ix = 1.0f / x, ix2 = ix * ix;
  if (l == 0) return s * ix;
  if (l == 1) return s * ix2 - c * ix;
  if (l == 2) return (3.0f * ix2 * ix - ix) * s - 3.0f * ix2 * c;
  return (15.0f * ix2 * ix2 - 6.0f * ix2) * s - (15.0f * ix2 * ix - ix) * c;
}

// ---------------- init / geometry kernels ----------------
__global__ void node_init_kernel(const int* __restrict__ nt, const float* __restrict__ emb,
                                 float* __restrict__ nf, int N) {
  int i = blockIdx.x * 256 + threadIdx.x;
  if (i >= N * 128) return;
  int n = i >> 7, c = i & 127;
  nf[i] = emb[nt[n] * 128 + c];
}

__global__ void edge_geom_kernel(const float* __restrict__ pos, const int* __restrict__ src,
                                 const int* __restrict__ dst, float* __restrict__ bvec,
                                 float* __restrict__ bdist, float* __restrict__ rbf,
                                 float* __restrict__ cut3, int E) {
  int e = blockIdx.x * 256 + threadIdx.x;
  if (e >= E) return;
  int s = src[e], d = dst[e];
  float dx = pos[d * 3 + 0] - pos[s * 3 + 0];
  float dy = pos[d * 3 + 1] - pos[s * 3 + 1];
  float dz = pos[d * 3 + 2] - pos[s * 3 + 2];
  float r = sqrtf(dx * dx + dy * dy + dz * dz + 1e-12f);
  bvec[e * 3 + 0] = dx; bvec[e * 3 + 1] = dy; bvec[e * 3 + 2] = dz;
  bdist[e] = r;
  const float roots[3][3] = {
      {3.141592653589793f, 6.283185307179586f, 9.42477796076938f},
      {4.493409457909064f, 7.725251836937707f, 10.904121659428899f},
      {5.763459196894550f, 9.095011330476355f, 12.322940970566582f}};
#pragma unroll
  for (int l = 0; l < 3; ++l) {
#pragma unroll
    for (int n = 0; n < 3; ++n) {
      float root = roots[l][n];
      float x = r * (root * 0.2f);                  // r * root / CUTOFF(5)
      float norm = fabsf(jl_eval(l + 1, root));     // SBF_NORM
      rbf[e * 9 + l * 3 + n] = jl_eval(l, x) * (0.12649110640673518f / norm);
    }
  }
  float xx = r * 0.25f;  // r / TB_CUTOFF(4)
  float x3 = xx * xx * xx;
  cut3[e] = 1.0f - 6.0f * x3 * xx * xx + 15.0f * x3 * xx - 10.0f * x3;
}

__global__ void edge_emb_kernel(const float* __restrict__ rbf, const float* __restrict__ W,
                                const float* __restrict__ B, float* __restrict__ ef, int E) {
  int i = blockIdx.x * 256 + threadIdx.x;
  if (i >= E * 128) return;
  int e = i >> 7, c = i & 127;
  float acc = B[c];
#pragma unroll
  for (int d = 0; d < 9; ++d) acc += rbf[e * 9 + d] * W[d * 128 + c];
  ef[i] = silu(acc);
}

// ---------------- CSR build: count / scan / finalize ----------------
__global__ void count_kernel(const int* __restrict__ idx, int* __restrict__ cnt, int L) {
  int i = blockIdx.x * 256 + threadIdx.x;
  if (i < L) atomicAdd(&cnt[idx[i]], 1);
}

__global__ void scan_block_kernel(const int* __restrict__ in, int* __restrict__ incl,
                                  int* __restrict__ bsum, int L) {
  __shared__ int sm[256];
  int i = blockIdx.x * 256 + threadIdx.x;
  int v = i < L ? in[i] : 0;
  sm[threadIdx.x] = v;
  __syncthreads();
  for (int st = 1; st < 256; st <<= 1) {
    int t = threadIdx.x >= st ? sm[threadIdx.x - st] : 0;
    __syncthreads();
    sm[threadIdx.x] += t;
    __syncthreads();
  }
  if (i < L) incl[i] = sm[threadIdx.x];
  if (threadIdx.x == 255) bsum[blockIdx.x] = sm[255];
}

__global__ void scan_top_kernel(int* __restrict__ bsum, int nb) {  // in-place exclusive
  __shared__ int sm[1024];
  int tid = threadIdx.x;
  int orig = tid < nb ? bsum[tid] : 0;
  sm[tid] = orig;
  __syncthreads();
  for (int st = 1; st < 1024; st <<= 1) {
    int t = tid >= st ? sm[tid - st] : 0;
    __syncthreads();
    sm[tid] += t;
    __syncthreads();
  }
  if (tid < nb) bsum[tid] = sm[tid] - orig;
}

__global__ void scan_finalize_kernel(const int* __restrict__ cnt, const int* __restrict__ incl,
                                     const int* __restrict__ bexcl, int* __restrict__ off,
                                     int* __restrict__ cur, int L) {
  int i = blockIdx.x * 256 + threadIdx.x;
  if (i >= L) return;
  int o = incl[i] - cnt[i] + bexcl[blockIdx.x];
  off[i] = o;
  cur[i] = o;
}

__global__ void fill_eperm_kernel(const int* __restrict__ dst, int* __restrict__ cur_n,
                                  int* __restrict__ eperm, int E) {
  int e = blockIdx.x * 256 + threadIdx.x;
  if (e >= E) return;
  int pos = atomicAdd(&cur_n[dst[e]], 1);
  eperm[pos] = e;
}

// triplet precompute, written directly to CSR-sorted position (by t_src)
__global__ void trip_sorted_kernel(const int* __restrict__ t_src, const int* __restrict__ t_dst,
                                   const int* __restrict__ dst, const float* __restrict__ bvec,
                                   const float* __restrict__ bdist, const float* __restrict__ rbf,
                                   const float* __restrict__ cut3, int* __restrict__ cur_e,
                                   float* __restrict__ stbp, int* __restrict__ sa, int T) {
  int t = blockIdx.x * 256 + threadIdx.x;
  if (t >= T) return;
  int i = t_src[t], j = t_dst[t];
  float ax = bvec[i * 3], ay = bvec[i * 3 + 1], az = bvec[i * 3 + 2];
  float bx = bvec[j * 3], by = bvec[j * 3 + 1], bz = bvec[j * 3 + 2];
  float ct = (ax * bx + ay * by + az * bz) / (bdist[i] * bdist[j]);
  float tw = cut3[i] * cut3[j];
  float sh[3];
  sh[0] = 0.28209479177387814f * tw;
  sh[1] = 0.4886025119029199f * ct * tw;
  sh[2] = 0.31539156525252005f * (3.0f * ct * ct - 1.0f) * tw;
  int pos = atomicAdd(&cur_e[i], 1);
#pragma unroll
  for (int l = 0; l < 3; ++l)
#pragma unroll
    for (int n = 0; n < 3; ++n)
      stbp[(size_t)pos * 9 + l * 3 + n] = rbf[j * 9 + l * 3 + n] * sh[l];
  sa[pos] = dst[j];
}

// nb[e][d] = sum over triplets p of edge e: stbp[p][d] * atoms[sa[p]][d]
__global__ void nb_reduce_kernel(const float* __restrict__ stbp, const int* __restrict__ sa,
                                 const float* __restrict__ atoms, const int* __restrict__ off_e,
                                 const int* __restrict__ cnt_e, float* __restrict__ nb, int E) {
  int i = blockIdx.x * 256 + threadIdx.x;
  if (i >= E * 9) return;
  int e = i / 9, d = i - e * 9;
  int o = off_e[e], c = cnt_e[e];
  float acc = 0.f;
  for (int p = o; p < o + c; ++p) acc += stbp[(size_t)p * 9 + d] * atoms[sa[p] * 9 + d];
  nb[i] = acc;
}

__global__ void atoms_kernel(const float* __restrict__ nf, const float* __restrict__ W,
                             const float* __restrict__ B, float* __restrict__ atoms, int N) {
  int i = blockIdx.x * 256 + threadIdx.x;
  if (i >= N * 9) return;
  int n = i / 9, d = i - n * 9;
  float acc = B[d];
  for (int c = 0; c < 128; ++c) acc += nf[n * 128 + c] * W[c * 9 + d];
  atoms[i] = sigm(acc);
}

// ---------------- weight packing: f32 [K][128] -> bf16 fragment-major ----------------
__global__ void pack_kernel(const float* __restrict__ Wf, short* __restrict__ Wp, int K,
                            int units) {
  int per = 8 * (K / 32) * 64;
  int idx = blockIdx.x * 256 + threadIdx.x;
  if (idx >= units * per) return;
  int u = idx / per, r = idx - u * per;
  int lane = r & 63, tile = r >> 6;
  int kt = tile % (K / 32), nt = tile / (K / 32);
  int n = nt * 16 + (lane & 15);
  int k0 = kt * 32 + (lane >> 4) * 8;
  const float* src = Wf + (size_t)u * K * 128;
  bf16x8 v;
#pragma unroll
  for (int e = 0; e < 8; ++e) v[e] = f2bf(src[(size_t)(k0 + e) * 128 + n]);
  *(bf16x8*)(Wp + (size_t)u * K * 128 + (size_t)tile * 512 + lane * 8) = v;
}

// ---------------- fused gated-MLP on MFMA: 8 waves, wave owns 16 cols ----------------
#define TE 32

__device__ __forceinline__ f32x4 mfma16(bf16x8 a, bf16x8 b, f32x4 c) {
  return __builtin_amdgcn_mfma_f32_16x16x32_bf16(a, b, c, 0, 0, 0);
}

// K=128 layer for 8-wave layout: wave covers col-tile nt=wave.
__device__ __forceinline__ void layer128w(const short* hin, const short* gin,
                                          const short* __restrict__ pW,
                                          const short* __restrict__ pG,
                                          const float* __restrict__ Bh,
                                          const float* __restrict__ Bg, int wave, int lane,
                                          f32x4 (&aW)[2], f32x4 (&aG)[2]) {
  const int lrow = lane & 15, lk = lane >> 4;
  float bw = Bh[wave * 16 + lrow], bg = Bg[wave * 16 + lrow];
  aW[0] = {bw, bw, bw, bw}; aW[1] = aW[0];
  aG[0] = {bg, bg, bg, bg}; aG[1] = aG[0];
#pragma unroll
  for (int kt = 0; kt < 4; ++kt) {
    int aoff = kt * 32 + lk * 8;
    bf16x8 ah0 = *(const bf16x8*)(hin + (size_t)lrow * 136 + aoff);
    bf16x8 ah1 = *(const bf16x8*)(hin + (size_t)(16 + lrow) * 136 + aoff);
    bf16x8 ag0 = *(const bf16x8*)(gin + (size_t)lrow * 136 + aoff);
    bf16x8 ag1 = *(const bf16x8*)(gin + (size_t)(16 + lrow) * 136 + aoff);
    bf16x8 bw8 = *(const bf16x8*)(pW + ((size_t)(wave * 4 + kt)) * 512 + lane * 8);
    bf16x8 bg8 = *(const bf16x8*)(pG + ((size_t)(wave * 4 + kt)) * 512 + lane * 8);
    aW[0] = mfma16(ah0, bw8, aW[0]);
    aW[1] = mfma16(ah1, bw8, aW[1]);
    aG[0] = mfma16(ag0, bg8, aG[0]);
    aG[1] = mfma16(ag1, bg8, aG[1]);
  }
}

// 3-layer gated chain; xs (stride 392) preserved; hs/gs scratch (stride 136).
__device__ __forceinline__ void run_chain(
    const short* xsb, short* hsb, short* gsb,
    const short* __restrict__ pW0, const short* __restrict__ pG0,
    const short* __restrict__ pW1, const short* __restrict__ pG1,
    const short* __restrict__ pW2, const short* __restrict__ pG2,
    const float* __restrict__ B0, const float* __restrict__ Gb0,
    const float* __restrict__ B1, const float* __restrict__ Gb1,
    const float* __restrict__ B2, const float* __restrict__ Gb2,
    int wave, int lane, f32x4 (&aW)[2], f32x4 (&aG)[2]) {
  const int lrow = lane & 15, lk = lane >> 4;
  // ---- layer 0: K=384 ----
  {
    float bw = B0[wave * 16 + lrow], bg = Gb0[wave * 16 + lrow];
    aW[0] = {bw, bw, bw, bw}; aW[1] = aW[0];
    aG[0] = {bg, bg, bg, bg}; aG[1] = aG[0];
  }
  for (int kt = 0; kt < 12; ++kt) {
    int aoff = kt * 32 + lk * 8;
    bf16x8 a0 = *(const bf16x8*)(xsb + (size_t)lrow * 392 + aoff);
    bf16x8 a1 = *(const bf16x8*)(xsb + (size_t)(16 + lrow) * 392 + aoff);
    bf16x8 bw8 = *(const bf16x8*)(pW0 + ((size_t)(wave * 12 + kt)) * 512 + lane * 8);
    bf16x8 bg8 = *(const bf16x8*)(pG0 + ((size_t)(wave * 12 + kt)) * 512 + lane * 8);
    aW[0] = mfma16(a0, bw8, aW[0]);
    aW[1] = mfma16(a1, bw8, aW[1]);
    aG[0] = mfma16(a0, bg8, aG[0]);
    aG[1] = mfma16(a1, bg8, aG[1]);
  }
  {
    int col = wave * 16 + lrow;
#pragma unroll
    for (int mt = 0; mt < 2; ++mt)
#pragma unroll
      for (int rg = 0; rg < 4; ++rg) {
        int row = mt * 16 + lk * 4 + rg;
        hsb[row * 136 + col] = f2bf1(silu(aW[mt][rg]));
        gsb[row * 136 + col] = f2bf1(silu(aG[mt][rg]));
      }
  }
  __syncthreads();
  // ---- layer 1 ----
  layer128w(hsb, gsb, pW1, pG1, B1, Gb1, wave, lane, aW, aG);
  __syncthreads();
  {
    int col = wave * 16 + lrow;
#pragma unroll
    for (int mt = 0; mt < 2; ++mt)
#pragma unroll
      for (int rg = 0; rg < 4; ++rg) {
        int row = mt * 16 + lk * 4 + rg;
        hsb[row * 136 + col] = f2bf1(silu(aW[mt][rg]));
        gsb[row * 136 + col] = f2bf1(silu(aG[mt][rg]));
      }
  }
  __syncthreads();
  // ---- layer 2 ----
  layer128w(hsb, gsb, pW2, pG2, B2, Gb2, wave, lane, aW, aG);
}

// Fused: tb_update (in gather) + edge-update chain + ef store + node-update chain.
__global__ __launch_bounds__(512, 6) void gmlp_fused(
    const float* __restrict__ nf, float* __restrict__ ef, const float* __restrict__ rbf,
    const int* __restrict__ src, const int* __restrict__ dst,
    const float* __restrict__ nb, const float* __restrict__ tbW, const float* __restrict__ tbG,
    const short* __restrict__ pW0a, const short* __restrict__ pG0a,
    const short* __restrict__ pW1a, const short* __restrict__ pG1a,
    const short* __restrict__ pW2a, const short* __restrict__ pG2a,
    const float* __restrict__ B0a, const float* __restrict__ Gb0a,
    const float* __restrict__ B1a, const float* __restrict__ Gb1a,
    const float* __restrict__ B2a, const float* __restrict__ Gb2a,
    const float* __restrict__ WTa,
    const short* __restrict__ pW0b, const short* __restrict__ pG0b,
    const short* __restrict__ pW1b, const short* __restrict__ pG1b,
    const short* __restrict__ pW2b, const short* __restrict__ pG2b,
    const float* __restrict__ B0b, const float* __restrict__ Gb0b,
    const float* __restrict__ B1b, const float* __restrict__ Gb1b,
    const float* __restrict__ B2b, const float* __restrict__ Gb2b,
    const float* __restrict__ WTb,
    float* __restrict__ mbuf, int E) {
  __shared__ __align__(16) short xs[32][392];          // x bf16, persists both chains
  __shared__ __align__(16) char uni[32 * 136 * 2 * 2]; // hs+gs  UNION  stW+stG
  __shared__ float rs[32][12];
  short* hs = (short*)uni;
  short* gs = (short*)uni + 32 * 136;
  float* stW = (float*)uni;
  float* stG = (float*)uni + 9 * 128;
  const int tid = threadIdx.x;
  const int e0 = blockIdx.x * TE;
  const int r = tid >> 4, q = tid & 15;  // 32 rows x 16 col-groups of 8
  int eg = e0 + r; if (eg >= E) eg = E - 1;

  // stage tb weights (uni as stW/stG) + gather nf segments
  for (int i = tid; i < 9 * 128; i += 512) { stW[i] = tbW[i]; stG[i] = tbG[i]; }
  {
    const float* sp0 = nf + (size_t)src[eg] * 128;
    const float* sp1 = nf + (size_t)dst[eg] * 128;
#pragma unroll
    for (int seg = 0; seg < 2; ++seg) {
      const float* sp = seg == 0 ? sp0 : sp1;
      float4 f0 = *(const float4*)(sp + q * 8);
      float4 f1 = *(const float4*)(sp + q * 8 + 4);
      u32x4 v = {cvt2(f0.x, f0.y), cvt2(f0.z, f0.w), cvt2(f1.x, f1.y), cvt2(f1.z, f1.w)};
      *(u32x4*)&xs[r][seg * 128 + q * 8] = v;
    }
    for (int idx = tid; idx < 32 * 9; idx += 512) {
      int rr = idx / 9, d = idx - rr * 9;
      int ee = e0 + rr; if (ee >= E) ee = E - 1;
      rs[rr][d] = rbf[ee * 9 + d];
    }
  }
  __syncthreads();

  // ef segment with fused tb_update: ef_tb = ef + silu(nb@W)*sigm(nb@Wg)  (8 ch/thread)
  {
    float nb9[9];
#pragma unroll
    for (int d = 0; d < 9; ++d) nb9[d] = nb[eg * 9 + d];
    float fv[8];
    {
      float4 f0 = *(const float4*)(ef + (size_t)eg * 128 + q * 8);
      float4 f1 = *(const float4*)(ef + (size_t)eg * 128 + q * 8 + 4);
      fv[0]=f0.x; fv[1]=f0.y; fv[2]=f0.z; fv[3]=f0.w;
      fv[4]=f1.x; fv[5]=f1.y; fv[6]=f1.z; fv[7]=f1.w;
    }
    float a8[8], b8[8];
#pragma unroll
    for (int c = 0; c < 8; ++c) { a8[c] = 0.f; b8[c] = 0.f; }
#pragma unroll
    for (int d = 0; d < 9; ++d) {
      float nbd = nb9[d];
      float4 w0 = *(const float4*)&stW[d * 128 + q * 8];
      float4 w1 = *(const float4*)&stW[d * 128 + q * 8 + 4];
      float4 g0 = *(const float4*)&stG[d * 128 + q * 8];
      float4 g1 = *(const float4*)&stG[d * 128 + q * 8 + 4];
      a8[0] = fmaf(nbd, w0.x, a8[0]); a8[1] = fmaf(nbd, w0.y, a8[1]);
      a8[2] = fmaf(nbd, w0.z, a8[2]); a8[3] = fmaf(nbd, w0.w, a8[3]);
      a8[4] = fmaf(nbd, w1.x, a8[4]); a8[5] = fmaf(nbd, w1.y, a8[5]);
      a8[6] = fmaf(nbd, w1.z, a8[6]); a8[7] = fmaf(nbd, w1.w, a8[7]);
      b8[0] = fmaf(nbd, g0.x, b8[0]); b8[1] = fmaf(nbd, g0.y, b8[1]);
      b8[2] = fmaf(nbd, g0.z, b8[2]); b8[3] = fmaf(nbd, g0.w, b8[3]);
      b8[4] = fmaf(nbd, g1.x, b8[4]); b8[5] = fmaf(nbd, g1.y, b8[5]);
      b8[6] = fmaf(nbd, g1.z, b8[6]); b8[7] = fmaf(nbd, g1.w, b8[7]);
    }
    float vals[8];
#pragma unroll
    for (int c = 0; c < 8; ++c) vals[c] = fv[c] + silu(a8[c]) * sigm(b8[c]);
    u32x4 v = {cvt2(vals[0], vals[1]), cvt2(vals[2], vals[3]),
               cvt2(vals[4], vals[5]), cvt2(vals[6], vals[7])};
    *(u32x4*)&xs[r][256 + q * 8] = v;
  }
  __syncthreads();  // also guards: stW/stG reads done before hs/gs overwrite uni

  const int wave = tid >> 6;
  const int lane = tid & 63;
  const int lrow = lane & 15, lk = lane >> 4;
  const int col = wave * 16 + lrow;
  f32x4 aW[2], aG[2];

  // ---- chain 0: edge update ----
  run_chain(&xs[0][0], hs, gs, pW0a, pG0a, pW1a, pG1a, pW2a, pG2a,
            B0a, Gb0a, B1a, Gb1a, B2a, Gb2a, wave, lane, aW, aG);
  // epilogue 0: ef_new = ef_tb + silu*sigm*(rbf@wt); store ef, refresh xs ef-segment
  {
    float wtc[9];
#pragma unroll
    for (int d = 0; d < 9; ++d) wtc[d] = WTa[d * 128 + col];
#pragma unroll
    for (int mt = 0; mt < 2; ++mt)
#pragma unroll
      for (int rg = 0; rg < 4; ++rg) {
        int row = mt * 16 + lk * 4 + rg;
        int e = e0 + row;
        float wv = 0.f;
#pragma unroll
        for (int d = 0; d < 9; ++d) wv = fmaf(rs[row][d], wtc[d], wv);
        float v = silu(aW[mt][rg]) * sigm(aG[mt][rg]) * wv;
        uint32_t ub = ((uint32_t)(uint16_t)xs[row][256 + col]) << 16;
        float nv = __uint_as_float(ub) + v;
        if (e < E) ef[(size_t)e * 128 + col] = nv;
        xs[row][256 + col] = f2bf1(nv);
      }
  }
  __syncthreads();

  // ---- chain 1: node update ----
  run_chain(&xs[0][0], hs, gs, pW0b, pG0b, pW1b, pG1b, pW2b, pG2b,
            B0b, Gb0b, B1b, Gb1b, B2b, Gb2b, wave, lane, aW, aG);
  // epilogue 1: message -> mbuf
  {
    float wtc[9];
#pragma unroll
    for (int d = 0; d < 9; ++d) wtc[d] = WTb[d * 128 + col];
#pragma unroll
    for (int mt = 0; mt < 2; ++mt)
#pragma unroll
      for (int rg = 0; rg < 4; ++rg) {
        int row = mt * 16 + lk * 4 + rg;
        int e = e0 + row;
        float wv = 0.f;
#pragma unroll
        for (int d = 0; d < 9; ++d) wv = fmaf(rs[row][d], wtc[d], wv);
        float v = silu(aW[mt][rg]) * sigm(aG[mt][rg]) * wv;
        if (e < E) mbuf[(size_t)e * 128 + col] = v;
      }
  }
}

// nf[n] += sum over edges e with dst[e]==n of mbuf[e]
__global__ void node_gather_kernel(float* __restrict__ nf, const float* __restrict__ mbuf,
                                   const int* __restrict__ off_n, const int* __restrict__ cnt_n,
                                   const int* __restrict__ eperm, int N) {
  int n = blockIdx.x * 2 + (threadIdx.x >> 7);
  int c = threadIdx.x & 127;
  if (n >= N) return;
  int o = off_n[n], cnt = cnt_n[n];
  float acc = 0.f;
  for (int p = o; p < o + cnt; ++p) acc += mbuf[(size_t)eperm[p] * 128 + c];
  nf[(size_t)n * 128 + c] += acc;
}

// ---------------- readout ----------------
__global__ void mean_kernel(const float* __restrict__ nf, float* __restrict__ partial, int N) {
  __shared__ float sm[256];
  int n0 = blockIdx.x * 256;
  int col = threadIdx.x & 127, half = threadIdx.x >> 7;
  int nend = n0 + 256 < N ? n0 + 256 : N;
  float s = 0.f;
  for (int n = n0 + half; n < nend; n += 2) s += nf[n * 128 + col];
  sm[threadIdx.x] = s;
  __syncthreads();
  if (threadIdx.x < 128)
    partial[blockIdx.x * 128 + threadIdx.x] = sm[threadIdx.x] + sm[threadIdx.x + 128];
}

__global__ void final_kernel(const float* __restrict__ partial, int nchunks, float Nf,
                             const float* __restrict__ fW0, const float* __restrict__ fb0,
                             const float* __restrict__ fW1, const float* __restrict__ fb1,
                             const float* __restrict__ fW2, const float* __restrict__ fb2,
                             float* __restrict__ out) {
  __shared__ float v[128], h[128], red[128];
  int tid = threadIdx.x;  // 128 threads
  float s = 0.f;
  for (int b = 0; b < nchunks; ++b) s += partial[b * 128 + tid];
  v[tid] = s / Nf;
  __syncthreads();
  float acc = fb0[tid];
  for (int c = 0; c < 128; ++c) acc += v[c] * fW0[c * 128 + tid];
  h[tid] = silu(acc);
  __syncthreads();
  acc = fb1[tid];
  for (int c = 0; c < 128; ++c) acc += h[c] * fW1[c * 128 + tid];
  __syncthreads();
  v[tid] = silu(acc);
  __syncthreads();
  red[tid] = v[tid] * fW2[tid];
  __syncthreads();
  for (int st = 64; st > 0; st >>= 1) {
    if (tid < st) red[tid] += red[tid + st];
    __syncthreads();
  }
  if (tid == 0) out[0] = red[0] + fb2[0];
}

// ---------------- launch ----------------
extern "C" void kernel_launch(void* const* d_in, const int* in_sizes, int n_in,
                              void* d_out, int out_size, void* d_ws, size_t ws_size,
                              hipStream_t stream) {
  const float* pos = (const float*)d_in[0];
  const int* node_type = (const int*)d_in[1];
  const int* src = (const int*)d_in[2];
  const int* dst = (const int*)d_in[3];
  const int* t_src = (const int*)d_in[4];
  const int* t_dst = (const int*)d_in[5];
  const float* emb = (const float*)d_in[6];
  const float* eW = (const float*)d_in[7];
  const float* eB = (const float*)d_in[8];
  const float* taW = (const float*)d_in[9];
  const float* taB = (const float*)d_in[10];
  const float* tbW = (const float*)d_in[11];
  const float* tbG = (const float*)d_in[12];
  const float* W0 = (const float*)d_in[13]; const float* B0 = (const float*)d_in[14];
  const float* W1 = (const float*)d_in[15]; const float* B1 = (const float*)d_in[16];
  const float* W2 = (const float*)d_in[17]; const float* B2 = (const float*)d_in[18];
  const float* G0 = (const float*)d_in[19]; const float* Gb0 = (const float*)d_in[20];
  const float* G1 = (const float*)d_in[21]; const float* Gb1 = (const float*)d_in[22];
  const float* G2 = (const float*)d_in[23]; const float* Gb2 = (const float*)d_in[24];
  const float* WT = (const float*)d_in[25];
  const float* fW0 = (const float*)d_in[26]; const float* fb0 = (const float*)d_in[27];
  const float* fW1 = (const float*)d_in[28]; const float* fb1 = (const float*)d_in[29];
  const float* fW2 = (const float*)d_in[30]; const float* fb2 = (const float*)d_in[31];

  const int N = in_sizes[1];
  const int E = in_sizes[2];
  const int T = in_sizes[4];

  char* p = (char*)d_ws;
  auto alloc = [&](size_t bytes) -> char* {
    char* r = p;
    p += (bytes + 255) & ~(size_t)255;
    return r;
  };
  float* nf    = (float*)alloc((size_t)N * 128 * 4);
  float* ef    = (float*)alloc((size_t)E * 128 * 4);
  float* mbuf  = (float*)alloc((size_t)E * 128 * 4);
  float* rbf   = (float*)alloc((size_t)E * 9 * 4);
  float* bvec  = (float*)alloc((size_t)E * 3 * 4);
  float* bdist = (float*)alloc((size_t)E * 4);
  float* cut3  = (float*)alloc((size_t)E * 4);
  float* stbp  = (float*)alloc((size_t)T * 9 * 4);
  int*   sa    = (int*)alloc((size_t)T * 4);
  float* atoms = (float*)alloc((size_t)N * 9 * 4);
  float* nb    = (float*)alloc((size_t)E * 9 * 4);
  float* part  = (float*)alloc((size_t)64 * 128 * 4);
  int* cnt_e  = (int*)alloc((size_t)E * 4);
  int* incl_e = (int*)alloc((size_t)E * 4);
  int* off_e  = (int*)alloc((size_t)E * 4);
  int* cur_e  = (int*)alloc((size_t)E * 4);
  int* cnt_n  = (int*)alloc((size_t)N * 4);
  int* incl_n = (int*)alloc((size_t)N * 4);
  int* off_n  = (int*)alloc((size_t)N * 4);
  int* cur_n  = (int*)alloc((size_t)N * 4);
  int* eperm  = (int*)alloc((size_t)E * 4);
  int* bsum   = (int*)alloc((size_t)1024 * 4);
  short* pW0s = (short*)alloc((size_t)6 * 384 * 128 * 2);
  short* pG0s = (short*)alloc((size_t)6 * 384 * 128 * 2);
  short* pW1s = (short*)alloc((size_t)6 * 128 * 128 * 2);
  short* pG1s = (short*)alloc((size_t)6 * 128 * 128 * 2);
  short* pW2s = (short*)alloc((size_t)6 * 128 * 128 * 2);
  short* pG2s = (short*)alloc((size_t)6 * 128 * 128 * 2);
  (void)ws_size; (void)n_in; (void)out_size;

  {
    int t384 = 6 * 8 * 12 * 64, t128 = 6 * 8 * 4 * 64;
    pack_kernel<<<(t384 + 255) / 256, 256, 0, stream>>>(W0, pW0s, 384, 6);
    pack_kernel<<<(t384 + 255) / 256, 256, 0, stream>>>(G0, pG0s, 384, 6);
    pack_kernel<<<(t128 + 255) / 256, 256, 0, stream>>>(W1, pW1s, 128, 6);
    pack_kernel<<<(t128 + 255) / 256, 256, 0, stream>>>(G1, pG1s, 128, 6);
    pack_kernel<<<(t128 + 255) / 256, 256, 0, stream>>>(W2, pW2s, 128, 6);
    pack_kernel<<<(t128 + 255) / 256, 256, 0, stream>>>(G2, pG2s, 128, 6);
  }

  node_init_kernel<<<(N * 128 + 255) / 256, 256, 0, stream>>>(node_type, emb, nf, N);
  edge_geom_kernel<<<(E + 255) / 256, 256, 0, stream>>>(pos, src, dst, bvec, bdist, rbf, cut3, E);
  edge_emb_kernel<<<(E * 128 + 255) / 256, 256, 0, stream>>>(rbf, eW, eB, ef, E);

  const int ebk = (E + 255) / 256, nbk = (N + 255) / 256;
  hipMemsetAsync(cnt_e, 0, (size_t)E * 4, stream);
  hipMemsetAsync(cnt_n, 0, (size_t)N * 4, stream);
  count_kernel<<<(T + 255) / 256, 256, 0, stream>>>(t_src, cnt_e, T);
  count_kernel<<<ebk, 256, 0, stream>>>(dst, cnt_n, E);
  scan_block_kernel<<<ebk, 256, 0, stream>>>(cnt_e, incl_e, bsum, E);
  scan_top_kernel<<<1, 1024, 0, stream>>>(bsum, ebk);
  scan_finalize_kernel<<<ebk, 256, 0, stream>>>(cnt_e, incl_e, bsum, off_e, cur_e, E);
  scan_block_kernel<<<nbk, 256, 0, stream>>>(cnt_n, incl_n, bsum, N);
  scan_top_kernel<<<1, 1024, 0, stream>>>(bsum, nbk);
  scan_finalize_kernel<<<nbk, 256, 0, stream>>>(cnt_n, incl_n, bsum, off_n, cur_n, N);
  trip_sorted_kernel<<<(T + 255) / 256, 256, 0, stream>>>(t_src, t_dst, dst, bvec, bdist, rbf,
                                                          cut3, cur_e, stbp, sa, T);
  fill_eperm_kernel<<<ebk, 256, 0, stream>>>(dst, cur_n, eperm, E);

  const int gblocks = (E + TE - 1) / TE;
  for (int k = 0; k < 3; ++k) {
    atoms_kernel<<<(N * 9 + 255) / 256, 256, 0, stream>>>(nf, taW + (size_t)k * 128 * 9,
                                                          taB + (size_t)k * 9, atoms, N);
    nb_reduce_kernel<<<(E * 9 + 255) / 256, 256, 0, stream>>>(stbp, sa, atoms, off_e, cnt_e, nb, E);

    size_t u0 = (size_t)(k * 2 + 0), u1 = u0 + 1;
    gmlp_fused<<<gblocks, 512, 0, stream>>>(
        nf, ef, rbf, src, dst, nb, tbW + (size_t)k * 9 * 128, tbG + (size_t)k * 9 * 128,
        pW0s + u0 * 384 * 128, pG0s + u0 * 384 * 128, pW1s + u0 * 128 * 128,
        pG1s + u0 * 128 * 128, pW2s + u0 * 128 * 128, pG2s + u0 * 128 * 128,
        B0 + u0 * 128, Gb0 + u0 * 128, B1 + u0 * 128, Gb1 + u0 * 128, B2 + u0 * 128,
        Gb2 + u0 * 128, WT + u0 * 9 * 128,
        pW0s + u1 * 384 * 128, pG0s + u1 * 384 * 128, pW1s + u1 * 128 * 128,
        pG1s + u1 * 128 * 128, pW2s + u1 * 128 * 128, pG2s + u1 * 128 * 128,
        B0 + u1 * 128, Gb0 + u1 * 128, B1 + u1 * 128, Gb1 + u1 * 128, B2 + u1 * 128,
        Gb2 + u1 * 128, WT + u1 * 9 * 128,
        mbuf, E);
    node_gather_kernel<<<(N + 1) / 2, 256, 0, stream>>>(nf, mbuf, off_n, cnt_n, eperm, N);
  }

  int nchunks = (N + 255) / 256;
  mean_kernel<<<nchunks, 256, 0, stream>>>(nf, part, N);
  final_kernel<<<1, 128, 0, stream>>>(part, nchunks, (float)N, fW0, fb0, fW1, fb1, fW2, fb2,
                                      (float*)d_out);
}

// Round 7
// 556.590 us; speedup vs baseline: 7.6816x; 1.0541x over previous
//
#include <hip/hip_runtime.h>
#include <stdint.h>

typedef __attribute__((ext_vector_type(8))) short bf16x8;
typedef __attribute__((ext_vector_type(4))) float f32x4;
typedef __attribute__((ext_vector_type(4))) uint32_t u32x4;

#define XSS 408   // xs row stride (shorts): 204 dw = 12 mod 32, 16B-aligned
#define HSS 144   // hs/gs row stride (shorts): 72 dw, 16B-aligned; XOR-swizzled cols
#define TE 32

// ---------------- helpers ----------------
__device__ __forceinline__ float sigm(float x) { return __fdividef(1.0f, 1.0f + __expf(-x)); }
__device__ __forceinline__ float silu(float x) { return __fdividef(x, 1.0f + __expf(-x)); }
__device__ __forceinline__ short f2bf(float f) {  // RNE f32->bf16 (pack path)
  uint32_t u = __float_as_uint(f);
  u = (u + 0x7fffu + ((u >> 16) & 1u)) >> 16;
  return (short)u;
}
__device__ __forceinline__ uint32_t cvt2(float lo, float hi) {
  uint32_t d;
  asm("v_cvt_pk_bf16_f32 %0, %1, %2" : "=v"(d) : "v"(lo), "v"(hi));
  return d;
}
__device__ __forceinline__ short f2bf1(float f) { return (short)cvt2(f, f); }

__device__ __forceinline__ float jl_eval(int l, float x) {
  float s, c;
  sincosf(x, &s, &c);
  float ix = 1.0f / x, ix2 = ix * ix;
  if (l == 0) return s * ix;
  if (l == 1) return s * ix2 - c * ix;
  if (l == 2) return (3.0f * ix2 * ix - ix) * s - 3.0f * ix2 * c;
  return (15.0f * ix2 * ix2 - 6.0f * ix2) * s - (15.0f * ix2 * ix - ix) * c;
}

// ---------------- setup1: node_init + edge_geom + CSR counts ----------------
__global__ void setup1_kernel(const int* __restrict__ ntb, const float* __restrict__ emb,
                              float* __restrict__ nf, int N,
                              const float* __restrict__ pos, const int* __restrict__ src,
                              const int* __restrict__ dst, float* __restrict__ bvec,
                              float* __restrict__ bdist, float* __restrict__ rbf,
                              float* __restrict__ cut3, int E,
                              const int* __restrict__ t_src, int* __restrict__ cnt_e,
                              int* __restrict__ cnt_n, int T) {
  int i = blockIdx.x * 256 + threadIdx.x;
  if (i < N * 128) {
    int n = i >> 7, c = i & 127;
    nf[i] = emb[ntb[n] * 128 + c];
  }
  if (i < E) {
    int s = src[i], d = dst[i];
    float dx = pos[d * 3 + 0] - pos[s * 3 + 0];
    float dy = pos[d * 3 + 1] - pos[s * 3 + 1];
    float dz = pos[d * 3 + 2] - pos[s * 3 + 2];
    float r = sqrtf(dx * dx + dy * dy + dz * dz + 1e-12f);
    bvec[i * 3 + 0] = dx; bvec[i * 3 + 1] = dy; bvec[i * 3 + 2] = dz;
    bdist[i] = r;
    const float roots[3][3] = {
        {3.141592653589793f, 6.283185307179586f, 9.42477796076938f},
        {4.493409457909064f, 7.725251836937707f, 10.904121659428899f},
        {5.763459196894550f, 9.095011330476355f, 12.322940970566582f}};
#pragma unroll
    for (int l = 0; l < 3; ++l) {
#pragma unroll
      for (int n = 0; n < 3; ++n) {
        float root = roots[l][n];
        float x = r * (root * 0.2f);
        float norm = fabsf(jl_eval(l + 1, root));
        rbf[i * 9 + l * 3 + n] = jl_eval(l, x) * (0.12649110640673518f / norm);
      }
    }
    float xx = r * 0.25f;
    float x3 = xx * xx * xx;
    cut3[i] = 1.0f - 6.0f * x3 * xx * xx + 15.0f * x3 * xx - 10.0f * x3;
    atomicAdd(&cnt_n[d], 1);
  }
  if (i < T) atomicAdd(&cnt_e[t_src[i]], 1);
}

// ---------------- setup2: block scans + edge_emb + atoms(k=0) ----------------
__device__ void scan_chunk(const int* __restrict__ in, int* __restrict__ incl,
                           int* __restrict__ bsum, int L, int b) {
  __shared__ int sm[256];
  int i = b * 256 + threadIdx.x;
  int v = i < L ? in[i] : 0;
  sm[threadIdx.x] = v;
  __syncthreads();
  for (int st = 1; st < 256; st <<= 1) {
    int t = threadIdx.x >= st ? sm[threadIdx.x - st] : 0;
    __syncthreads();
    sm[threadIdx.x] += t;
    __syncthreads();
  }
  if (i < L) incl[i] = sm[threadIdx.x];
  if (threadIdx.x == 255) bsum[b] = sm[255];
}

__global__ void setup2_kernel(const float* __restrict__ rbf, const float* __restrict__ eW,
                              const float* __restrict__ eB, float* __restrict__ ef, int E,
                              const int* __restrict__ cnt_e, int* __restrict__ incl_e,
                              int* __restrict__ bsum_e, int ebk,
                              const int* __restrict__ cnt_n, int* __restrict__ incl_n,
                              int* __restrict__ bsum_n, int nbk, int N,
                              const float* __restrict__ nf, const float* __restrict__ taW,
                              const float* __restrict__ taB, float* __restrict__ atoms) {
  int b = blockIdx.x;
  if (b < ebk) scan_chunk(cnt_e, incl_e, bsum_e, E, b);
  else if (b < ebk + nbk) scan_chunk(cnt_n, incl_n, bsum_n, N, b - ebk);
  int i = b * 256 + threadIdx.x;
  if (i < E * 128) {
    int e = i >> 7, c = i & 127;
    float acc = eB[c];
#pragma unroll
    for (int d = 0; d < 9; ++d) acc += rbf[e * 9 + d] * eW[d * 128 + c];
    ef[i] = silu(acc);
  }
  if (i < N * 9) {
    int n = i / 9, d = i - n * 9;
    float acc = taB[d];
    for (int c = 0; c < 128; ++c) acc += nf[n * 128 + c] * taW[c * 9 + d];
    atoms[i] = sigm(acc);
  }
}

__global__ void scan_top2_kernel(int* __restrict__ bsum_e, int ne, int* __restrict__ bsum_n,
                                 int nn) {
  __shared__ int sm[1024];
  int* bs = blockIdx.x == 0 ? bsum_e : bsum_n;
  int nb = blockIdx.x == 0 ? ne : nn;
  int tid = threadIdx.x;
  int orig = tid < nb ? bs[tid] : 0;
  sm[tid] = orig;
  __syncthreads();
  for (int st = 1; st < 1024; st <<= 1) {
    int t = tid >= st ? sm[tid - st] : 0;
    __syncthreads();
    sm[tid] += t;
    __syncthreads();
  }
  if (tid < nb) bs[tid] = sm[tid] - orig;
}

__global__ void fin2_kernel(const int* __restrict__ cnt_e, const int* __restrict__ incl_e,
                            const int* __restrict__ bsum_e, int ebk, int* __restrict__ off_e,
                            int* __restrict__ cur_e, int E, const int* __restrict__ cnt_n,
                            const int* __restrict__ incl_n, const int* __restrict__ bsum_n,
                            int* __restrict__ off_n, int* __restrict__ cur_n, int N) {
  int b = blockIdx.x;
  if (b < ebk) {
    int i = b * 256 + threadIdx.x;
    if (i < E) {
      int o = incl_e[i] - cnt_e[i] + bsum_e[b];
      off_e[i] = o; cur_e[i] = o;
    }
  } else {
    int bb = b - ebk;
    int i = bb * 256 + threadIdx.x;
    if (i < N) {
      int o = incl_n[i] - cnt_n[i] + bsum_n[bb];
      off_n[i] = o; cur_n[i] = o;
    }
  }
}

// build: triplet precompute into CSR-sorted slots + edge permutation by dst
__global__ void build_kernel(const int* __restrict__ t_src, const int* __restrict__ t_dst,
                             const int* __restrict__ dst, const float* __restrict__ bvec,
                             const float* __restrict__ bdist, const float* __restrict__ rbf,
                             const float* __restrict__ cut3, int* __restrict__ cur_e,
                             float* __restrict__ stbp, int* __restrict__ sa, int T,
                             int* __restrict__ cur_n, int* __restrict__ eperm, int E) {
  int t = blockIdx.x * 256 + threadIdx.x;
  if (t < T) {
    int i = t_src[t], j = t_dst[t];
    float ax = bvec[i * 3], ay = bvec[i * 3 + 1], az = bvec[i * 3 + 2];
    float bx = bvec[j * 3], by = bvec[j * 3 + 1], bz = bvec[j * 3 + 2];
    float ct = (ax * bx + ay * by + az * bz) / (bdist[i] * bdist[j]);
    float tw = cut3[i] * cut3[j];
    float sh[3];
    sh[0] = 0.28209479177387814f * tw;
    sh[1] = 0.4886025119029199f * ct * tw;
    sh[2] = 0.31539156525252005f * (3.0f * ct * ct - 1.0f) * tw;
    int pos = atomicAdd(&cur_e[i], 1);
#pragma unroll
    for (int l = 0; l < 3; ++l)
#pragma unroll
      for (int n = 0; n < 3; ++n)
        stbp[(size_t)pos * 9 + l * 3 + n] = rbf[j * 9 + l * 3 + n] * sh[l];
    sa[pos] = dst[j];
  }
  if (t < E) {
    int pos = atomicAdd(&cur_n[dst[t]], 1);
    eperm[pos] = t;
  }
}

// ---------------- weight packing (all tensors, one launch) ----------------
__device__ void pack_one(const float* __restrict__ Wf, short* __restrict__ Wp, int K, int rr) {
  int per = 8 * (K / 32) * 64;
  int u = rr / per, r2 = rr - u * per;
  int lane = r2 & 63, tile = r2 >> 6;
  int kt = tile % (K / 32), nt = tile / (K / 32);
  int n = nt * 16 + (lane & 15);
  int k0 = kt * 32 + (lane >> 4) * 8;
  const float* s = Wf + (size_t)u * K * 128;
  bf16x8 v;
#pragma unroll
  for (int e = 0; e < 8; ++e) v[e] = f2bf(s[(size_t)(k0 + e) * 128 + n]);
  *(bf16x8*)(Wp + (size_t)u * K * 128 + (size_t)tile * 512 + lane * 8) = v;
}

__global__ void pack_all_kernel(const float* __restrict__ W0, const float* __restrict__ G0,
                                const float* __restrict__ W1, const float* __restrict__ G1,
                                const float* __restrict__ W2, const float* __restrict__ G2,
                                short* __restrict__ pW0, short* __restrict__ pG0,
                                short* __restrict__ pW1, short* __restrict__ pG1,
                                short* __restrict__ pW2, short* __restrict__ pG2) {
  int idx = blockIdx.x * 256 + threadIdx.x;
  const int t384 = 6 * 8 * 12 * 64, t128 = 6 * 8 * 4 * 64;
  if (idx < t384) pack_one(W0, pW0, 384, idx);
  else if (idx < 2 * t384) pack_one(G0, pG0, 384, idx - t384);
  else {
    int j = idx - 2 * t384;
    if (j < t128) pack_one(W1, pW1, 128, j);
    else if (j < 2 * t128) pack_one(G1, pG1, 128, j - t128);
    else if (j < 3 * t128) pack_one(W2, pW2, 128, j - 2 * t128);
    else if (j < 4 * t128) pack_one(G2, pG2, 128, j - 3 * t128);
  }
}

// ---------------- fused gated-MLP on MFMA ----------------
__device__ __forceinline__ f32x4 mfma16(bf16x8 a, bf16x8 b, f32x4 c) {
  return __builtin_amdgcn_mfma_f32_16x16x32_bf16(a, b, c, 0, 0, 0);
}

// hs/gs element (row,col) stored at col ^ (((row>>2)&3)<<4)
__device__ __forceinline__ void store_hg(short* hsb, short* gsb, int wave, int lane,
                                         const f32x4 (&aW)[2], const f32x4 (&aG)[2]) {
  const int lrow = lane & 15, lk = lane >> 4;
  const int colx = (wave * 16 + lrow) ^ (lk << 4);
#pragma unroll
  for (int mt = 0; mt < 2; ++mt)
#pragma unroll
    for (int rg = 0; rg < 4; ++rg) {
      int row = mt * 16 + lk * 4 + rg;
      hsb[row * HSS + colx] = f2bf1(silu(aW[mt][rg]));
      gsb[row * HSS + colx] = f2bf1(silu(aG[mt][rg]));
    }
}

__device__ __forceinline__ void layer128w(const short* hin, const short* gin,
                                          const short* __restrict__ pW,
                                          const short* __restrict__ pG,
                                          const float* __restrict__ Bh,
                                          const float* __restrict__ Bg, int wave, int lane,
                                          f32x4 (&aW)[2], f32x4 (&aG)[2]) {
  const int lrow = lane & 15, lk = lane >> 4;
  const int s0 = (lrow >> 2) & 3;
  float bw = Bh[wave * 16 + lrow], bg = Bg[wave * 16 + lrow];
  aW[0] = {bw, bw, bw, bw}; aW[1] = aW[0];
  aG[0] = {bg, bg, bg, bg}; aG[1] = aG[0];
#pragma unroll
  for (int kt = 0; kt < 4; ++kt) {
    int aoff = (kt * 32 + lk * 8) ^ (s0 << 4);
    bf16x8 ah0 = *(const bf16x8*)(hin + (size_t)lrow * HSS + aoff);
    bf16x8 ah1 = *(const bf16x8*)(hin + (size_t)(16 + lrow) * HSS + aoff);
    bf16x8 ag0 = *(const bf16x8*)(gin + (size_t)lrow * HSS + aoff);
    bf16x8 ag1 = *(const bf16x8*)(gin + (size_t)(16 + lrow) * HSS + aoff);
    bf16x8 bw8 = *(const bf16x8*)(pW + (size_t)(wave * 4 + kt) * 512 + lane * 8);
    bf16x8 bg8 = *(const bf16x8*)(pG + (size_t)(wave * 4 + kt) * 512 + lane * 8);
    aW[0] = mfma16(ah0, bw8, aW[0]);
    aW[1] = mfma16(ah1, bw8, aW[1]);
    aG[0] = mfma16(ag0, bg8, aG[0]);
    aG[1] = mfma16(ag1, bg8, aG[1]);
  }
}

__device__ __forceinline__ void run_chain(
    const short* xsb, short* hsb, short* gsb,
    const short* __restrict__ pW0, const short* __restrict__ pG0,
    const short* __restrict__ pW1, const short* __restrict__ pG1,
    const short* __restrict__ pW2, const short* __restrict__ pG2,
    const float* __restrict__ B0, const float* __restrict__ Gb0,
    const float* __restrict__ B1, const float* __restrict__ Gb1,
    const float* __restrict__ B2, const float* __restrict__ Gb2,
    int wave, int lane, f32x4 (&aW)[2], f32x4 (&aG)[2]) {
  const int lrow = lane & 15, lk = lane >> 4;
  const int s0 = (lrow >> 2) & 3;
  {
    float bw = B0[wave * 16 + lrow], bg = Gb0[wave * 16 + lrow];
    aW[0] = {bw, bw, bw, bw}; aW[1] = aW[0];
    aG[0] = {bg, bg, bg, bg}; aG[1] = aG[0];
  }
#pragma unroll
  for (int kt = 0; kt < 12; ++kt) {
    int al = kt * 32 + lk * 8;
    int aoff = (al < 256) ? al : (256 + ((al - 256) ^ (s0 << 4)));  // ef region swizzled
    bf16x8 a0 = *(const bf16x8*)(xsb + (size_t)lrow * XSS + aoff);
    bf16x8 a1 = *(const bf16x8*)(xsb + (size_t)(16 + lrow) * XSS + aoff);
    bf16x8 bw8 = *(const bf16x8*)(pW0 + (size_t)(wave * 12 + kt) * 512 + lane * 8);
    bf16x8 bg8 = *(const bf16x8*)(pG0 + (size_t)(wave * 12 + kt) * 512 + lane * 8);
    aW[0] = mfma16(a0, bw8, aW[0]);
    aW[1] = mfma16(a1, bw8, aW[1]);
    aG[0] = mfma16(a0, bg8, aG[0]);
    aG[1] = mfma16(a1, bg8, aG[1]);
  }
  store_hg(hsb, gsb, wave, lane, aW, aG);
  __syncthreads();
  layer128w(hsb, gsb, pW1, pG1, B1, Gb1, wave, lane, aW, aG);
  __syncthreads();
  store_hg(hsb, gsb, wave, lane, aW, aG);
  __syncthreads();
  layer128w(hsb, gsb, pW2, pG2, B2, Gb2, wave, lane, aW, aG);
}

__global__ __launch_bounds__(512, 6) void gmlp_fused(
    const float* __restrict__ nf, float* __restrict__ ef, const float* __restrict__ rbf,
    const int* __restrict__ src, const int* __restrict__ dst,
    const float* __restrict__ stbp, const int* __restrict__ sa,
    const int* __restrict__ off_e, const int* __restrict__ cnt_e,
    const float* __restrict__ atoms,
    const float* __restrict__ tbW, const float* __restrict__ tbG,
    const short* __restrict__ pW0a, const short* __restrict__ pG0a,
    const short* __restrict__ pW1a, const short* __restrict__ pG1a,
    const short* __restrict__ pW2a, const short* __restrict__ pG2a,
    const float* __restrict__ B0a, const float* __restrict__ Gb0a,
    const float* __restrict__ B1a, const float* __restrict__ Gb1a,
    const float* __restrict__ B2a, const float* __restrict__ Gb2a,
    const float* __restrict__ WTa,
    const short* __restrict__ pW0b, const short* __restrict__ pG0b,
    const short* __restrict__ pW1b, const short* __restrict__ pG1b,
    const short* __restrict__ pW2b, const short* __restrict__ pG2b,
    const float* __restrict__ B0b, const float* __restrict__ Gb0b,
    const float* __restrict__ B1b, const float* __restrict__ Gb1b,
    const float* __restrict__ B2b, const float* __restrict__ Gb2b,
    const float* __restrict__ WTb,
    float* __restrict__ mbuf, int E) {
  __shared__ __align__(16) short xs[32][XSS];
  __shared__ __align__(16) short hs[32 * HSS];
  __shared__ __align__(16) short gs[32 * HSS];
  __shared__ float rs[32][12];
  __shared__ float nbl[32][12];
  const int tid = threadIdx.x;
  const int e0 = blockIdx.x * TE;
  const int r = tid >> 4, q = tid & 15;
  const int sr = (r >> 2) & 3;
  int eg = e0 + r; if (eg >= E) eg = E - 1;

  // ---- fused nb_reduce: three-body aggregate for this block's edges ----
  if (q < 9) {
    int o = off_e[eg], c = cnt_e[eg];
    float acc = 0.f;
    for (int pp = o; pp < o + c; ++pp)
      acc += stbp[(size_t)pp * 9 + q] * atoms[(size_t)sa[pp] * 9 + q];
    nbl[r][q] = acc;
  }
  // ---- gather nf segments as bf16 ----
  {
    const float* sp0 = nf + (size_t)src[eg] * 128;
    const float* sp1 = nf + (size_t)dst[eg] * 128;
#pragma unroll
    for (int seg = 0; seg < 2; ++seg) {
      const float* sp = seg == 0 ? sp0 : sp1;
      float4 f0 = *(const float4*)(sp + q * 8);
      float4 f1 = *(const float4*)(sp + q * 8 + 4);
      u32x4 v = {cvt2(f0.x, f0.y), cvt2(f0.z, f0.w), cvt2(f1.x, f1.y), cvt2(f1.z, f1.w)};
      *(u32x4*)&xs[r][seg * 128 + q * 8] = v;
    }
    for (int idx = tid; idx < 32 * 9; idx += 512) {
      int rr = idx / 9, d = idx - rr * 9;
      int ee = e0 + rr; if (ee >= E) ee = E - 1;
      rs[rr][d] = rbf[ee * 9 + d];
    }
  }
  __syncthreads();

  // ---- ef segment with fused tb_update; tb weights straight from L2 ----
  {
    float nb9[9];
#pragma unroll
    for (int d = 0; d < 9; ++d) nb9[d] = nbl[r][d];
    float fv[8];
    {
      float4 f0 = *(const float4*)(ef + (size_t)eg * 128 + q * 8);
      float4 f1 = *(const float4*)(ef + (size_t)eg * 128 + q * 8 + 4);
      fv[0]=f0.x; fv[1]=f0.y; fv[2]=f0.z; fv[3]=f0.w;
      fv[4]=f1.x; fv[5]=f1.y; fv[6]=f1.z; fv[7]=f1.w;
    }
    float a8[8], b8[8];
#pragma unroll
    for (int c = 0; c < 8; ++c) { a8[c] = 0.f; b8[c] = 0.f; }
#pragma unroll
    for (int d = 0; d < 9; ++d) {
      float nbd = nb9[d];
      float4 w0 = *(const float4*)(tbW + d * 128 + q * 8);
      float4 w1 = *(const float4*)(tbW + d * 128 + q * 8 + 4);
      float4 g0 = *(const float4*)(tbG + d * 128 + q * 8);
      float4 g1 = *(const float4*)(tbG + d * 128 + q * 8 + 4);
      a8[0] = fmaf(nbd, w0.x, a8[0]); a8[1] = fmaf(nbd, w0.y, a8[1]);
      a8[2] = fmaf(nbd, w0.z, a8[2]); a8[3] = fmaf(nbd, w0.w, a8[3]);
      a8[4] = fmaf(nbd, w1.x, a8[4]); a8[5] = fmaf(nbd, w1.y, a8[5]);
      a8[6] = fmaf(nbd, w1.z, a8[6]); a8[7] = fmaf(nbd, w1.w, a8[7]);
      b8[0] = fmaf(nbd, g0.x, b8[0]); b8[1] = fmaf(nbd, g0.y, b8[1]);
      b8[2] = fmaf(nbd, g0.z, b8[2]); b8[3] = fmaf(nbd, g0.w, b8[3]);
      b8[4] = fmaf(nbd, g1.x, b8[4]); b8[5] = fmaf(nbd, g1.y, b8[5]);
      b8[6] = fmaf(nbd, g1.z, b8[6]); b8[7] = fmaf(nbd, g1.w, b8[7]);
    }
    float vals[8];
#pragma unroll
    for (int c = 0; c < 8; ++c) vals[c] = fv[c] + silu(a8[c]) * sigm(b8[c]);
    u32x4 v = {cvt2(vals[0], vals[1]), cvt2(vals[2], vals[3]),
               cvt2(vals[4], vals[5]), cvt2(vals[6], vals[7])};
    *(u32x4*)&xs[r][256 + ((q * 8) ^ (sr << 4))] = v;
  }
  __syncthreads();

  const int wave = tid >> 6;
  const int lane = tid & 63;
  const int lrow = lane & 15, lk = lane >> 4;
  const int col = wave * 16 + lrow;
  f32x4 aW[2], aG[2];

  // ---- chain 0: edge update ----
  run_chain(&xs[0][0], hs, gs, pW0a, pG0a, pW1a, pG1a, pW2a, pG2a,
            B0a, Gb0a, B1a, Gb1a, B2a, Gb2a, wave, lane, aW, aG);
  {
    float wtc[9];
#pragma unroll
    for (int d = 0; d < 9; ++d) wtc[d] = WTa[d * 128 + col];
    const int cs = 256 + (col ^ (lk << 4));
#pragma unroll
    for (int mt = 0; mt < 2; ++mt)
#pragma unroll
      for (int rg = 0; rg < 4; ++rg) {
        int row = mt * 16 + lk * 4 + rg;
        int e = e0 + row;
        float wv = 0.f;
#pragma unroll
        for (int d = 0; d < 9; ++d) wv = fmaf(rs[row][d], wtc[d], wv);
        float v = silu(aW[mt][rg]) * sigm(aG[mt][rg]) * wv;
        uint32_t ub = ((uint32_t)(uint16_t)xs[row][cs]) << 16;
        float nv = __uint_as_float(ub) + v;
        if (e < E) ef[(size_t)e * 128 + col] = nv;
        xs[row][cs] = f2bf1(nv);
      }
  }
  __syncthreads();

  // ---- chain 1: node update ----
  run_chain(&xs[0][0], hs, gs, pW0b, pG0b, pW1b, pG1b, pW2b, pG2b,
            B0b, Gb0b, B1b, Gb1b, B2b, Gb2b, wave, lane, aW, aG);
  {
    float wtc[9];
#pragma unroll
    for (int d = 0; d < 9; ++d) wtc[d] = WTb[d * 128 + col];
#pragma unroll
    for (int mt = 0; mt < 2; ++mt)
#pragma unroll
      for (int rg = 0; rg < 4; ++rg) {
        int row = mt * 16 + lk * 4 + rg;
        int e = e0 + row;
        float wv = 0.f;
#pragma unroll
        for (int d = 0; d < 9; ++d) wv = fmaf(rs[row][d], wtc[d], wv);
        float v = silu(aW[mt][rg]) * sigm(aG[mt][rg]) * wv;
        if (e < E) mbuf[(size_t)e * 128 + col] = v;
      }
  }
}

// ---- node gather + fused atoms for next block-iter ----
__global__ void node_gather_kernel(float* __restrict__ nf, const float* __restrict__ mbuf,
                                   const int* __restrict__ off_n, const int* __restrict__ cnt_n,
                                   const int* __restrict__ eperm, const float* __restrict__ taW,
                                   const float* __restrict__ taB, float* __restrict__ atoms,
                                   int N, int doAtoms) {
  __shared__ float sm[2][128];
  int half = threadIdx.x >> 7, c = threadIdx.x & 127;
  int n = blockIdx.x * 2 + half;
  float v = 0.f;
  if (n < N) {
    int o = off_n[n], cnt = cnt_n[n];
    float acc = 0.f;
    for (int p = o; p < o + cnt; ++p) acc += mbuf[(size_t)eperm[p] * 128 + c];
    v = nf[(size_t)n * 128 + c] + acc;
    nf[(size_t)n * 128 + c] = v;
  }
  if (doAtoms) {
    sm[half][c] = v;
    __syncthreads();
    if (n < N && c < 9) {
      float a = taB[c];
      for (int cc = 0; cc < 128; ++cc) a += sm[half][cc] * taW[cc * 9 + c];
      atoms[n * 9 + c] = sigm(a);
    }
  }
}

// ---------------- readout ----------------
__global__ void mean_kernel(const float* __restrict__ nf, float* __restrict__ partial, int N) {
  __shared__ float sm[256];
  int n0 = blockIdx.x * 256;
  int col = threadIdx.x & 127, half = threadIdx.x >> 7;
  int nend = n0 + 256 < N ? n0 + 256 : N;
  float s = 0.f;
  for (int n = n0 + half; n < nend; n += 2) s += nf[n * 128 + col];
  sm[threadIdx.x] = s;
  __syncthreads();
  if (threadIdx.x < 128)
    partial[blockIdx.x * 128 + threadIdx.x] = sm[threadIdx.x] + sm[threadIdx.x + 128];
}

__global__ void final_kernel(const float* __restrict__ partial, int nchunks, float Nf,
                             const float* __restrict__ fW0, const float* __restrict__ fb0,
                             const float* __restrict__ fW1, const float* __restrict__ fb1,
                             const float* __restrict__ fW2, const float* __restrict__ fb2,
                             float* __restrict__ out) {
  __shared__ float v[128], h[128], red[128];
  int tid = threadIdx.x;  // 128 threads
  float s = 0.f;
  for (int b = 0; b < nchunks; ++b) s += partial[b * 128 + tid];
  v[tid] = s / Nf;
  __syncthreads();
  float acc = fb0[tid];
  for (int c = 0; c < 128; ++c) acc += v[c] * fW0[c * 128 + tid];
  h[tid] = silu(acc);
  __syncthreads();
  acc = fb1[tid];
  for (int c = 0; c < 128; ++c) acc += h[c] * fW1[c * 128 + tid];
  __syncthreads();
  v[tid] = silu(acc);
  __syncthreads();
  red[tid] = v[tid] * fW2[tid];
  __syncthreads();
  for (int st = 64; st > 0; st >>= 1) {
    if (tid < st) red[tid] += red[tid + st];
    __syncthreads();
  }
  if (tid == 0) out[0] = red[0] + fb2[0];
}

// ---------------- launch ----------------
extern "C" void kernel_launch(void* const* d_in, const int* in_sizes, int n_in,
                              void* d_out, int out_size, void* d_ws, size_t ws_size,
                              hipStream_t stream) {
  const float* pos = (const float*)d_in[0];
  const int* node_type = (const int*)d_in[1];
  const int* src = (const int*)d_in[2];
  const int* dst = (const int*)d_in[3];
  const int* t_src = (const int*)d_in[4];
  const int* t_dst = (const int*)d_in[5];
  const float* emb = (const float*)d_in[6];
  const float* eW = (const float*)d_in[7];
  const float* eB = (const float*)d_in[8];
  const float* taW = (const float*)d_in[9];
  const float* taB = (const float*)d_in[10];
  const float* tbW = (const float*)d_in[11];
  const float* tbG = (const float*)d_in[12];
  const float* W0 = (const float*)d_in[13]; const float* B0 = (const float*)d_in[14];
  const float* W1 = (const float*)d_in[15]; const float* B1 = (const float*)d_in[16];
  const float* W2 = (const float*)d_in[17]; const float* B2 = (const float*)d_in[18];
  const float* G0 = (const float*)d_in[19]; const float* Gb0 = (const float*)d_in[20];
  const float* G1 = (const float*)d_in[21]; const float* Gb1 = (const float*)d_in[22];
  const float* G2 = (const float*)d_in[23]; const float* Gb2 = (const float*)d_in[24];
  const float* WT = (const float*)d_in[25];
  const float* fW0 = (const float*)d_in[26]; const float* fb0 = (const float*)d_in[27];
  const float* fW1 = (const float*)d_in[28]; const float* fb1 = (const float*)d_in[29];
  const float* fW2 = (const float*)d_in[30]; const float* fb2 = (const float*)d_in[31];

  const int N = in_sizes[1];
  const int E = in_sizes[2];
  const int T = in_sizes[4];

  char* p = (char*)d_ws;
  auto alloc = [&](size_t bytes) -> char* {
    char* r = p;
    p += (bytes + 255) & ~(size_t)255;
    return r;
  };
  float* nf    = (float*)alloc((size_t)N * 128 * 4);
  float* ef    = (float*)alloc((size_t)E * 128 * 4);
  float* mbuf  = (float*)alloc((size_t)E * 128 * 4);
  float* rbf   = (float*)alloc((size_t)E * 9 * 4);
  float* bvec  = (float*)alloc((size_t)E * 3 * 4);
  float* bdist = (float*)alloc((size_t)E * 4);
  float* cut3  = (float*)alloc((size_t)E * 4);
  float* stbp  = (float*)alloc((size_t)T * 9 * 4);
  int*   sa    = (int*)alloc((size_t)T * 4);
  float* atoms = (float*)alloc((size_t)N * 9 * 4);
  float* part  = (float*)alloc((size_t)64 * 128 * 4);
  int* cnt_all = (int*)alloc((size_t)(E + N) * 4);
  int* cnt_e = cnt_all, *cnt_n = cnt_all + E;
  int* incl_e = (int*)alloc((size_t)E * 4);
  int* incl_n = (int*)alloc((size_t)N * 4);
  int* off_e  = (int*)alloc((size_t)E * 4);
  int* off_n  = (int*)alloc((size_t)N * 4);
  int* cur_e  = (int*)alloc((size_t)E * 4);
  int* cur_n  = (int*)alloc((size_t)N * 4);
  int* eperm  = (int*)alloc((size_t)E * 4);
  int* bsum_e = (int*)alloc((size_t)1024 * 4);
  int* bsum_n = (int*)alloc((size_t)1024 * 4);
  short* pW0s = (short*)alloc((size_t)6 * 384 * 128 * 2);
  short* pG0s = (short*)alloc((size_t)6 * 384 * 128 * 2);
  short* pW1s = (short*)alloc((size_t)6 * 128 * 128 * 2);
  short* pG1s = (short*)alloc((size_t)6 * 128 * 128 * 2);
  short* pW2s = (short*)alloc((size_t)6 * 128 * 128 * 2);
  short* pG2s = (short*)alloc((size_t)6 * 128 * 128 * 2);
  (void)ws_size; (void)n_in; (void)out_size;

  const int ebk = (E + 255) / 256, nbk = (N + 255) / 256;

  pack_all_kernel<<<480, 256, 0, stream>>>(W0, G0, W1, G1, W2, G2, pW0s, pG0s, pW1s, pG1s,
                                           pW2s, pG2s);
  hipMemsetAsync(cnt_all, 0, (size_t)(E + N) * 4, stream);
  {
    int g1 = N * 128; if (E > g1) g1 = E; if (T > g1) g1 = T;
    setup1_kernel<<<(g1 + 255) / 256, 256, 0, stream>>>(
        node_type, emb, nf, N, pos, src, dst, bvec, bdist, rbf, cut3, E, t_src, cnt_e, cnt_n, T);
  }
  {
    int g2 = E * 128; int g2b = (ebk + nbk) * 256; if (g2b > g2) g2 = g2b;
    if (N * 9 > g2) g2 = N * 9;
    setup2_kernel<<<(g2 + 255) / 256, 256, 0, stream>>>(
        rbf, eW, eB, ef, E, cnt_e, incl_e, bsum_e, ebk, cnt_n, incl_n, bsum_n, nbk, N,
        nf, taW, taB, atoms);
  }
  scan_top2_kernel<<<2, 1024, 0, stream>>>(bsum_e, ebk, bsum_n, nbk);
  fin2_kernel<<<ebk + nbk, 256, 0, stream>>>(cnt_e, incl_e, bsum_e, ebk, off_e, cur_e, E,
                                             cnt_n, incl_n, bsum_n, off_n, cur_n, N);
  {
    int g3 = T > E ? T : E;
    build_kernel<<<(g3 + 255) / 256, 256, 0, stream>>>(t_src, t_dst, dst, bvec, bdist, rbf,
                                                       cut3, cur_e, stbp, sa, T, cur_n, eperm, E);
  }

  const int gblocks = (E + TE - 1) / TE;
  for (int k = 0; k < 3; ++k) {
    size_t u0 = (size_t)(k * 2 + 0), u1 = u0 + 1;
    gmlp_fused<<<gblocks, 512, 0, stream>>>(
        nf, ef, rbf, src, dst, stbp, sa, off_e, cnt_e, atoms,
        tbW + (size_t)k * 9 * 128, tbG + (size_t)k * 9 * 128,
        pW0s + u0 * 384 * 128, pG0s + u0 * 384 * 128, pW1s + u0 * 128 * 128,
        pG1s + u0 * 128 * 128, pW2s + u0 * 128 * 128, pG2s + u0 * 128 * 128,
        B0 + u0 * 128, Gb0 + u0 * 128, B1 + u0 * 128, Gb1 + u0 * 128, B2 + u0 * 128,
        Gb2 + u0 * 128, WT + u0 * 9 * 128,
        pW0s + u1 * 384 * 128, pG0s + u1 * 384 * 128, pW1s + u1 * 128 * 128,
        pG1s + u1 * 128 * 128, pW2s + u1 * 128 * 128, pG2s + u1 * 128 * 128,
        B0 + u1 * 128, Gb0 + u1 * 128, B1 + u1 * 128, Gb1 + u1 * 128, B2 + u1 * 128,
        Gb2 + u1 * 128, WT + u1 * 9 * 128,
        mbuf, E);
    int nk = k < 2 ? k + 1 : 0;
    node_gather_kernel<<<(N + 1) / 2, 256, 0, stream>>>(
        nf, mbuf, off_n, cnt_n, eperm, taW + (size_t)nk * 128 * 9, taB + (size_t)nk * 9,
        atoms, N, k < 2 ? 1 : 0);
  }

  int nchunks = (N + 255) / 256;
  mean_kernel<<<nchunks, 256, 0, stream>>>(nf, part, N);
  final_kernel<<<1, 128, 0, stream>>>(part, nchunks, (float)N, fW0, fb0, fW1, fb1, fW2, fb2,
                                      (float*)d_out);
}

// Round 8
// 521.344 us; speedup vs baseline: 8.2010x; 1.0676x over previous
//
#include <hip/hip_runtime.h>
#include <stdint.h>

typedef __attribute__((ext_vector_type(8))) short bf16x8;
typedef __attribute__((ext_vector_type(4))) float f32x4;
typedef __attribute__((ext_vector_type(4))) uint32_t u32x4;

#define XSS 392   // xs row stride (shorts): 49 x 16B (odd) -> 2-way max on b128
#define HSS 136   // hs/gs row stride (shorts): 17 x 16B (odd)
#define TE 32

// ---------------- helpers ----------------
__device__ __forceinline__ float sigm(float x) { return __fdividef(1.0f, 1.0f + __expf(-x)); }
__device__ __forceinline__ float silu(float x) { return __fdividef(x, 1.0f + __expf(-x)); }
__device__ __forceinline__ short f2bf(float f) {  // RNE f32->bf16 (pack path)
  uint32_t u = __float_as_uint(f);
  u = (u + 0x7fffu + ((u >> 16) & 1u)) >> 16;
  return (short)u;
}
__device__ __forceinline__ uint32_t cvt2(float lo, float hi) {
  uint32_t d;
  asm("v_cvt_pk_bf16_f32 %0, %1, %2" : "=v"(d) : "v"(lo), "v"(hi));
  return d;
}
__device__ __forceinline__ short f2bf1(float f) { return (short)cvt2(f, f); }

__device__ __forceinline__ float jl_eval(int l, float x) {
  float s, c;
  sincosf(x, &s, &c);
  float ix = 1.0f / x, ix2 = ix * ix;
  if (l == 0) return s * ix;
  if (l == 1) return s * ix2 - c * ix;
  if (l == 2) return (3.0f * ix2 * ix - ix) * s - 3.0f * ix2 * c;
  return (15.0f * ix2 * ix2 - 6.0f * ix2) * s - (15.0f * ix2 * ix - ix) * c;
}

// ---------------- setup1: node_init + edge_geom + CSR counts ----------------
__global__ void setup1_kernel(const int* __restrict__ ntb, const float* __restrict__ emb,
                              float* __restrict__ nf, int N,
                              const float* __restrict__ pos, const int* __restrict__ src,
                              const int* __restrict__ dst, float* __restrict__ bvec,
                              float* __restrict__ bdist, float* __restrict__ rbf,
                              float* __restrict__ cut3, int E,
                              const int* __restrict__ t_src, int* __restrict__ cnt_e,
                              int* __restrict__ cnt_n, int T) {
  int i = blockIdx.x * 256 + threadIdx.x;
  if (i < N * 128) {
    int n = i >> 7, c = i & 127;
    nf[i] = emb[ntb[n] * 128 + c];
  }
  if (i < E) {
    int s = src[i], d = dst[i];
    float dx = pos[d * 3 + 0] - pos[s * 3 + 0];
    float dy = pos[d * 3 + 1] - pos[s * 3 + 1];
    float dz = pos[d * 3 + 2] - pos[s * 3 + 2];
    float r = sqrtf(dx * dx + dy * dy + dz * dz + 1e-12f);
    bvec[i * 3 + 0] = dx; bvec[i * 3 + 1] = dy; bvec[i * 3 + 2] = dz;
    bdist[i] = r;
    const float roots[3][3] = {
        {3.141592653589793f, 6.283185307179586f, 9.42477796076938f},
        {4.493409457909064f, 7.725251836937707f, 10.904121659428899f},
        {5.763459196894550f, 9.095011330476355f, 12.322940970566582f}};
#pragma unroll
    for (int l = 0; l < 3; ++l) {
#pragma unroll
      for (int n = 0; n < 3; ++n) {
        float root = roots[l][n];
        float x = r * (root * 0.2f);
        float norm = fabsf(jl_eval(l + 1, root));
        rbf[i * 9 + l * 3 + n] = jl_eval(l, x) * (0.12649110640673518f / norm);
      }
    }
    float xx = r * 0.25f;
    float x3 = xx * xx * xx;
    cut3[i] = 1.0f - 6.0f * x3 * xx * xx + 15.0f * x3 * xx - 10.0f * x3;
    atomicAdd(&cnt_n[d], 1);
  }
  if (i < T) atomicAdd(&cnt_e[t_src[i]], 1);
}

// ---------------- setup2: block scans + edge_emb + atoms(k=0) ----------------
__device__ void scan_chunk(const int* __restrict__ in, int* __restrict__ incl,
                           int* __restrict__ bsum, int L, int b) {
  __shared__ int sm[256];
  int i = b * 256 + threadIdx.x;
  int v = i < L ? in[i] : 0;
  sm[threadIdx.x] = v;
  __syncthreads();
  for (int st = 1; st < 256; st <<= 1) {
    int t = threadIdx.x >= st ? sm[threadIdx.x - st] : 0;
    __syncthreads();
    sm[threadIdx.x] += t;
    __syncthreads();
  }
  if (i < L) incl[i] = sm[threadIdx.x];
  if (threadIdx.x == 255) bsum[b] = sm[255];
}

__global__ void setup2_kernel(const float* __restrict__ rbf, const float* __restrict__ eW,
                              const float* __restrict__ eB, float* __restrict__ ef, int E,
                              const int* __restrict__ cnt_e, int* __restrict__ incl_e,
                              int* __restrict__ bsum_e, int ebk,
                              const int* __restrict__ cnt_n, int* __restrict__ incl_n,
                              int* __restrict__ bsum_n, int nbk, int N,
                              const float* __restrict__ nf, const float* __restrict__ taW,
                              const float* __restrict__ taB, float* __restrict__ atoms) {
  int b = blockIdx.x;
  if (b < ebk) scan_chunk(cnt_e, incl_e, bsum_e, E, b);
  else if (b < ebk + nbk) scan_chunk(cnt_n, incl_n, bsum_n, N, b - ebk);
  int i = b * 256 + threadIdx.x;
  if (i < E * 128) {
    int e = i >> 7, c = i & 127;
    float acc = eB[c];
#pragma unroll
    for (int d = 0; d < 9; ++d) acc += rbf[e * 9 + d] * eW[d * 128 + c];
    ef[i] = silu(acc);
  }
  if (i < N * 9) {
    int n = i / 9, d = i - n * 9;
    float acc = taB[d];
    for (int c = 0; c < 128; ++c) acc += nf[n * 128 + c] * taW[c * 9 + d];
    atoms[i] = sigm(acc);
  }
}

__global__ void scan_top2_kernel(int* __restrict__ bsum_e, int ne, int* __restrict__ bsum_n,
                                 int nn) {
  __shared__ int sm[1024];
  int* bs = blockIdx.x == 0 ? bsum_e : bsum_n;
  int nb = blockIdx.x == 0 ? ne : nn;
  int tid = threadIdx.x;
  int orig = tid < nb ? bs[tid] : 0;
  sm[tid] = orig;
  __syncthreads();
  for (int st = 1; st < 1024; st <<= 1) {
    int t = tid >= st ? sm[tid - st] : 0;
    __syncthreads();
    sm[tid] += t;
    __syncthreads();
  }
  if (tid < nb) bs[tid] = sm[tid] - orig;
}

__global__ void fin2_kernel(const int* __restrict__ cnt_e, const int* __restrict__ incl_e,
                            const int* __restrict__ bsum_e, int ebk, int* __restrict__ off_e,
                            int* __restrict__ cur_e, int E, const int* __restrict__ cnt_n,
                            const int* __restrict__ incl_n, const int* __restrict__ bsum_n,
                            int* __restrict__ off_n, int* __restrict__ cur_n, int N) {
  int b = blockIdx.x;
  if (b < ebk) {
    int i = b * 256 + threadIdx.x;
    if (i < E) {
      int o = incl_e[i] - cnt_e[i] + bsum_e[b];
      off_e[i] = o; cur_e[i] = o;
    }
  } else {
    int bb = b - ebk;
    int i = bb * 256 + threadIdx.x;
    if (i < N) {
      int o = incl_n[i] - cnt_n[i] + bsum_n[bb];
      off_n[i] = o; cur_n[i] = o;
    }
  }
}

// build: triplet precompute into CSR-sorted slots + inverse dst-permutation
__global__ void build_kernel(const int* __restrict__ t_src, const int* __restrict__ t_dst,
                             const int* __restrict__ dst, const float* __restrict__ bvec,
                             const float* __restrict__ bdist, const float* __restrict__ rbf,
                             const float* __restrict__ cut3, int* __restrict__ cur_e,
                             float* __restrict__ stbp, int* __restrict__ sa, int T,
                             int* __restrict__ cur_n, int* __restrict__ invp, int E) {
  int t = blockIdx.x * 256 + threadIdx.x;
  if (t < T) {
    int i = t_src[t], j = t_dst[t];
    float ax = bvec[i * 3], ay = bvec[i * 3 + 1], az = bvec[i * 3 + 2];
    float bx = bvec[j * 3], by = bvec[j * 3 + 1], bz = bvec[j * 3 + 2];
    float ct = (ax * bx + ay * by + az * bz) / (bdist[i] * bdist[j]);
    float tw = cut3[i] * cut3[j];
    float sh[3];
    sh[0] = 0.28209479177387814f * tw;
    sh[1] = 0.4886025119029199f * ct * tw;
    sh[2] = 0.31539156525252005f * (3.0f * ct * ct - 1.0f) * tw;
    int pos = atomicAdd(&cur_e[i], 1);
#pragma unroll
    for (int l = 0; l < 3; ++l)
#pragma unroll
      for (int n = 0; n < 3; ++n)
        stbp[(size_t)pos * 9 + l * 3 + n] = rbf[j * 9 + l * 3 + n] * sh[l];
    sa[pos] = dst[j];
  }
  if (t < E) {
    int pos = atomicAdd(&cur_n[dst[t]], 1);
    invp[t] = pos;
  }
}

// ---------------- weight packing (all tensors incl. tb, one launch) ----------------
__device__ void pack_one(const float* __restrict__ Wf, short* __restrict__ Wp, int K, int rr) {
  int per = 8 * (K / 32) * 64;
  int u = rr / per, r2 = rr - u * per;
  int lane = r2 & 63, tile = r2 >> 6;
  int kt = tile % (K / 32), nt = tile / (K / 32);
  int n = nt * 16 + (lane & 15);
  int k0 = kt * 32 + (lane >> 4) * 8;
  const float* s = Wf + (size_t)u * K * 128;
  bf16x8 v;
#pragma unroll
  for (int e = 0; e < 8; ++e) v[e] = f2bf(s[(size_t)(k0 + e) * 128 + n]);
  *(bf16x8*)(Wp + (size_t)u * K * 128 + (size_t)tile * 512 + lane * 8) = v;
}

__global__ void pack_all_kernel(const float* __restrict__ W0, const float* __restrict__ G0,
                                const float* __restrict__ W1, const float* __restrict__ G1,
                                const float* __restrict__ W2, const float* __restrict__ G2,
                                const float* __restrict__ tbW, const float* __restrict__ tbG,
                                short* __restrict__ pW0, short* __restrict__ pG0,
                                short* __restrict__ pW1, short* __restrict__ pG1,
                                short* __restrict__ pW2, short* __restrict__ pG2,
                                short* __restrict__ ptbW, short* __restrict__ ptbG) {
  int idx = blockIdx.x * 256 + threadIdx.x;
  const int t384 = 6 * 8 * 12 * 64, t128 = 6 * 8 * 4 * 64;
  if (idx < t384) { pack_one(W0, pW0, 384, idx); return; }
  if (idx < 2 * t384) { pack_one(G0, pG0, 384, idx - t384); return; }
  int j = idx - 2 * t384;
  if (j < t128) { pack_one(W1, pW1, 128, j); return; }
  if (j < 2 * t128) { pack_one(G1, pG1, 128, j - t128); return; }
  if (j < 3 * t128) { pack_one(W2, pW2, 128, j - 2 * t128); return; }
  if (j < 4 * t128) { pack_one(G2, pG2, 128, j - 3 * t128); return; }
  j -= 4 * t128;
  if (j < 3072) {  // tb weights: 3 k-blocks x {W,G} x 8 tiles x 64 lanes, K padded 9->32
    int kb = j >> 10;
    int w2 = (j >> 9) & 1;
    int l2 = j & 511;
    int lane = l2 & 63, tile = l2 >> 6;
    int n = tile * 16 + (lane & 15);
    int k0 = (lane >> 4) * 8;
    const float* s = (w2 ? tbG : tbW) + (size_t)kb * 9 * 128;
    short* dp = (w2 ? ptbG : ptbW) + (size_t)kb * 4096 + tile * 512 + lane * 8;
    bf16x8 v;
#pragma unroll
    for (int e = 0; e < 8; ++e) v[e] = (k0 + e < 9) ? f2bf(s[(size_t)(k0 + e) * 128 + n]) : (short)0;
    *(bf16x8*)dp = v;
  }
}

// ---------------- fused gated-MLP on MFMA ----------------
__device__ __forceinline__ f32x4 mfma16(bf16x8 a, bf16x8 b, f32x4 c) {
  return __builtin_amdgcn_mfma_f32_16x16x32_bf16(a, b, c, 0, 0, 0);
}

// hs/gs element (row,col) stored at col ^ (((row>>2)&3)<<4)
__device__ __forceinline__ void store_hg(short* hsb, short* gsb, int wave, int lane,
                                         const f32x4 (&aW)[2], const f32x4 (&aG)[2]) {
  const int lrow = lane & 15, lk = lane >> 4;
  const int colx = (wave * 16 + lrow) ^ (lk << 4);
#pragma unroll
  for (int mt = 0; mt < 2; ++mt)
#pragma unroll
    for (int rg = 0; rg < 4; ++rg) {
      int row = mt * 16 + lk * 4 + rg;
      hsb[row * HSS + colx] = f2bf1(silu(aW[mt][rg]));
      gsb[row * HSS + colx] = f2bf1(silu(aG[mt][rg]));
    }
}

__device__ __forceinline__ void layer128w(const short* hin, const short* gin,
                                          const short* __restrict__ pW,
                                          const short* __restrict__ pG,
                                          const float* __restrict__ Bh,
                                          const float* __restrict__ Bg, int wave, int lane,
                                          f32x4 (&aW)[2], f32x4 (&aG)[2]) {
  const int lrow = lane & 15, lk = lane >> 4;
  const int s0 = (lrow >> 2) & 3;
  float bw = Bh[wave * 16 + lrow], bg = Bg[wave * 16 + lrow];
  aW[0] = {bw, bw, bw, bw}; aW[1] = aW[0];
  aG[0] = {bg, bg, bg, bg}; aG[1] = aG[0];
#pragma unroll
  for (int kt = 0; kt < 4; ++kt) {
    int aoff = (kt * 32 + lk * 8) ^ (s0 << 4);
    bf16x8 ah0 = *(const bf16x8*)(hin + (size_t)lrow * HSS + aoff);
    bf16x8 ah1 = *(const bf16x8*)(hin + (size_t)(16 + lrow) * HSS + aoff);
    bf16x8 ag0 = *(const bf16x8*)(gin + (size_t)lrow * HSS + aoff);
    bf16x8 ag1 = *(const bf16x8*)(gin + (size_t)(16 + lrow) * HSS + aoff);
    bf16x8 bw8 = *(const bf16x8*)(pW + (size_t)(wave * 4 + kt) * 512 + lane * 8);
    bf16x8 bg8 = *(const bf16x8*)(pG + (size_t)(wave * 4 + kt) * 512 + lane * 8);
    aW[0] = mfma16(ah0, bw8, aW[0]);
    aW[1] = mfma16(ah1, bw8, aW[1]);
    aG[0] = mfma16(ag0, bg8, aG[0]);
    aG[1] = mfma16(ag1, bg8, aG[1]);
  }
}

__device__ __forceinline__ void run_chain(
    const short* xsb, short* hsb, short* gsb,
    const short* __restrict__ pW0, const short* __restrict__ pG0,
    const short* __restrict__ pW1, const short* __restrict__ pG1,
    const short* __restrict__ pW2, const short* __restrict__ pG2,
    const float* __restrict__ B0, const float* __restrict__ Gb0,
    const float* __restrict__ B1, const float* __restrict__ Gb1,
    const float* __restrict__ B2, const float* __restrict__ Gb2,
    int wave, int lane, f32x4 (&aW)[2], f32x4 (&aG)[2]) {
  const int lrow = lane & 15, lk = lane >> 4;
  const int s0 = (lrow >> 2) & 3;
  {
    float bw = B0[wave * 16 + lrow], bg = Gb0[wave * 16 + lrow];
    aW[0] = {bw, bw, bw, bw}; aW[1] = aW[0];
    aG[0] = {bg, bg, bg, bg}; aG[1] = aG[0];
  }
#pragma unroll
  for (int kt = 0; kt < 12; ++kt) {
    int al = kt * 32 + lk * 8;
    int aoff = (al < 256) ? al : (256 + ((al - 256) ^ (s0 << 4)));  // ef region swizzled
    bf16x8 a0 = *(const bf16x8*)(xsb + (size_t)lrow * XSS + aoff);
    bf16x8 a1 = *(const bf16x8*)(xsb + (size_t)(16 + lrow) * XSS + aoff);
    bf16x8 bw8 = *(const bf16x8*)(pW0 + (size_t)(wave * 12 + kt) * 512 + lane * 8);
    bf16x8 bg8 = *(const bf16x8*)(pG0 + (size_t)(wave * 12 + kt) * 512 + lane * 8);
    aW[0] = mfma16(a0, bw8, aW[0]);
    aW[1] = mfma16(a1, bw8, aW[1]);
    aG[0] = mfma16(a0, bg8, aG[0]);
    aG[1] = mfma16(a1, bg8, aG[1]);
  }
  store_hg(hsb, gsb, wave, lane, aW, aG);
  __syncthreads();
  layer128w(hsb, gsb, pW1, pG1, B1, Gb1, wave, lane, aW, aG);
  __syncthreads();
  store_hg(hsb, gsb, wave, lane, aW, aG);
  __syncthreads();
  layer128w(hsb, gsb, pW2, pG2, B2, Gb2, wave, lane, aW, aG);
}

__global__ __launch_bounds__(512, 6) void gmlp_fused(
    const float* __restrict__ nf, float* __restrict__ ef, const float* __restrict__ rbf,
    const int* __restrict__ src, const int* __restrict__ dst,
    const float* __restrict__ stbp, const int* __restrict__ sa,
    const int* __restrict__ off_e, const int* __restrict__ cnt_e,
    const float* __restrict__ atoms, const int* __restrict__ invp,
    const short* __restrict__ ptbW, const short* __restrict__ ptbG,
    const short* __restrict__ pW0a, const short* __restrict__ pG0a,
    const short* __restrict__ pW1a, const short* __restrict__ pG1a,
    const short* __restrict__ pW2a, const short* __restrict__ pG2a,
    const float* __restrict__ B0a, const float* __restrict__ Gb0a,
    const float* __restrict__ B1a, const float* __restrict__ Gb1a,
    const float* __restrict__ B2a, const float* __restrict__ Gb2a,
    const float* __restrict__ WTa,
    const short* __restrict__ pW0b, const short* __restrict__ pG0b,
    const short* __restrict__ pW1b, const short* __restrict__ pG1b,
    const short* __restrict__ pW2b, const short* __restrict__ pG2b,
    const float* __restrict__ B0b, const float* __restrict__ Gb0b,
    const float* __restrict__ B1b, const float* __restrict__ Gb1b,
    const float* __restrict__ B2b, const float* __restrict__ Gb2b,
    const float* __restrict__ WTb,
    float* __restrict__ mbuf, int E, int writeEf) {
  __shared__ __align__(16) short xs[32][XSS];
  __shared__ __align__(16) short hs[32 * HSS];
  __shared__ __align__(16) short gs[32 * HSS];
  __shared__ float rs[32][12];
  __shared__ __align__(16) short nbl[32][40];  // K=32-padded nb, bf16
  __shared__ int invs[32];
  const int tid = threadIdx.x;
  const int e0 = blockIdx.x * TE;
  const int r = tid >> 4, q = tid & 15;
  int eg = e0 + r; if (eg >= E) eg = E - 1;

  // ---- fused nb_reduce -> bf16 nbl (cols q and q+16; zero-pad K 9..31) ----
  {
    float acc = 0.f;
    if (q < 9) {
      int o = off_e[eg], c = cnt_e[eg];
      for (int pp = o; pp < o + c; ++pp)
        acc += stbp[(size_t)pp * 9 + q] * atoms[(size_t)sa[pp] * 9 + q];
    }
    nbl[r][q] = (q < 9) ? f2bf1(acc) : (short)0;
    nbl[r][q + 16] = 0;
  }
  // ---- gather nf segments as bf16 ----
  {
    const float* sp0 = nf + (size_t)src[eg] * 128;
    const float* sp1 = nf + (size_t)dst[eg] * 128;
#pragma unroll
    for (int seg = 0; seg < 2; ++seg) {
      const float* sp = seg == 0 ? sp0 : sp1;
      float4 f0 = *(const float4*)(sp + q * 8);
      float4 f1 = *(const float4*)(sp + q * 8 + 4);
      u32x4 v = {cvt2(f0.x, f0.y), cvt2(f0.z, f0.w), cvt2(f1.x, f1.y), cvt2(f1.z, f1.w)};
      *(u32x4*)&xs[r][seg * 128 + q * 8] = v;
    }
    for (int idx = tid; idx < 32 * 9; idx += 512) {
      int rr = idx / 9, d = idx - rr * 9;
      int ee = e0 + rr; if (ee >= E) ee = E - 1;
      rs[rr][d] = rbf[ee * 9 + d];
    }
    if (tid < 32) {
      int ee = e0 + tid; if (ee >= E) ee = E - 1;
      invs[tid] = invp[ee];
    }
  }
  __syncthreads();

  const int wave = tid >> 6;
  const int lane = tid & 63;
  const int lrow = lane & 15, lk = lane >> 4;
  const int col = wave * 16 + lrow;
  f32x4 aW[2], aG[2];
  float efb[2][4];  // ef + tb_update base, carried in registers through chain 0

  // ---- tb_update via MFMA: ef_tb = ef + silu(nb@W)*sigm(nb@Wg) ----
  {
    bf16x8 ta0 = *(const bf16x8*)&nbl[lrow][lk * 8];
    bf16x8 ta1 = *(const bf16x8*)&nbl[16 + lrow][lk * 8];
    bf16x8 tbw = *(const bf16x8*)(ptbW + wave * 512 + lane * 8);
    bf16x8 tbg = *(const bf16x8*)(ptbG + wave * 512 + lane * 8);
    f32x4 z = {0.f, 0.f, 0.f, 0.f};
    f32x4 tW0 = mfma16(ta0, tbw, z), tW1 = mfma16(ta1, tbw, z);
    f32x4 tG0 = mfma16(ta0, tbg, z), tG1 = mfma16(ta1, tbg, z);
#pragma unroll
    for (int mt = 0; mt < 2; ++mt)
#pragma unroll
      for (int rg = 0; rg < 4; ++rg) {
        int row = mt * 16 + lk * 4 + rg;
        int ec = e0 + row; if (ec >= E) ec = E - 1;
        float tw = mt == 0 ? tW0[rg] : tW1[rg];
        float tg = mt == 0 ? tG0[rg] : tG1[rg];
        float base = ef[(size_t)ec * 128 + col] + silu(tw) * sigm(tg);
        efb[mt][rg] = base;
        xs[row][256 + (col ^ (lk << 4))] = f2bf1(base);
      }
  }
  __syncthreads();

  // ---- chain 0: edge update ----
  run_chain(&xs[0][0], hs, gs, pW0a, pG0a, pW1a, pG1a, pW2a, pG2a,
            B0a, Gb0a, B1a, Gb1a, B2a, Gb2a, wave, lane, aW, aG);
  {
    float wtc[9];
#pragma unroll
    for (int d = 0; d < 9; ++d) wtc[d] = WTa[d * 128 + col];
    const int cs = 256 + (col ^ (lk << 4));
#pragma unroll
    for (int mt = 0; mt < 2; ++mt)
#pragma unroll
      for (int rg = 0; rg < 4; ++rg) {
        int row = mt * 16 + lk * 4 + rg;
        int e = e0 + row;
        float wv = 0.f;
#pragma unroll
        for (int d = 0; d < 9; ++d) wv = fmaf(rs[row][d], wtc[d], wv);
        float v = silu(aW[mt][rg]) * sigm(aG[mt][rg]) * wv;
        float nv = efb[mt][rg] + v;
        if (e < E && writeEf) ef[(size_t)e * 128 + col] = nv;
        xs[row][cs] = f2bf1(nv);
      }
  }
  __syncthreads();

  // ---- chain 1: node update ----
  run_chain(&xs[0][0], hs, gs, pW0b, pG0b, pW1b, pG1b, pW2b, pG2b,
            B0b, Gb0b, B1b, Gb1b, B2b, Gb2b, wave, lane, aW, aG);
  {
    float wtc[9];
#pragma unroll
    for (int d = 0; d < 9; ++d) wtc[d] = WTb[d * 128 + col];
#pragma unroll
    for (int mt = 0; mt < 2; ++mt)
#pragma unroll
      for (int rg = 0; rg < 4; ++rg) {
        int row = mt * 16 + lk * 4 + rg;
        int e = e0 + row;
        float wv = 0.f;
#pragma unroll
        for (int d = 0; d < 9; ++d) wv = fmaf(rs[row][d], wtc[d], wv);
        float v = silu(aW[mt][rg]) * sigm(aG[mt][rg]) * wv;
        if (e < E) mbuf[(size_t)invs[row] * 128 + col] = v;  // dst-sorted position
      }
  }
}

// ---- node gather (sequential, dst-sorted mbuf) + fused atoms for next iter ----
__global__ void node_gather_kernel(float* __restrict__ nf, const float* __restrict__ mbuf,
                                   const int* __restrict__ off_n, const int* __restrict__ cnt_n,
                                   const float* __restrict__ taW, const float* __restrict__ taB,
                                   float* __restrict__ atoms, int N, int doAtoms) {
  __shared__ float sm[2][128];
  int half = threadIdx.x >> 7, c = threadIdx.x & 127;
  int n = blockIdx.x * 2 + half;
  float v = 0.f;
  if (n < N) {
    int o = off_n[n], cnt = cnt_n[n];
    float acc = 0.f;
    for (int p = 0; p < cnt; ++p) acc += mbuf[(size_t)(o + p) * 128 + c];
    v = nf[(size_t)n * 128 + c] + acc;
    nf[(size_t)n * 128 + c] = v;
  }
  if (doAtoms) {
    sm[half][c] = v;
    __syncthreads();
    if (n < N && c < 9) {
      float a = taB[c];
      for (int cc = 0; cc < 128; ++cc) a += sm[half][cc] * taW[cc * 9 + c];
      atoms[n * 9 + c] = sigm(a);
    }
  }
}

// ---------------- readout ----------------
__global__ void mean_kernel(const float* __restrict__ nf, float* __restrict__ partial, int N) {
  __shared__ float sm[256];
  int n0 = blockIdx.x * 256;
  int col = threadIdx.x & 127, half = threadIdx.x >> 7;
  int nend = n0 + 256 < N ? n0 + 256 : N;
  float s = 0.f;
  for (int n = n0 + half; n < nend; n += 2) s += nf[n * 128 + col];
  sm[threadIdx.x] = s;
  __syncthreads();
  if (threadIdx.x < 128)
    partial[blockIdx.x * 128 + threadIdx.x] = sm[threadIdx.x] + sm[threadIdx.x + 128];
}

__global__ void final_kernel(const float* __restrict__ partial, int nchunks, float Nf,
                             const float* __restrict__ fW0, const float* __restrict__ fb0,
                             const float* __restrict__ fW1, const float* __restrict__ fb1,
                             const float* __restrict__ fW2, const float* __restrict__ fb2,
                             float* __restrict__ out) {
  __shared__ float v[128], h[128], red[128];
  int tid = threadIdx.x;  // 128 threads
  float s = 0.f;
  for (int b = 0; b < nchunks; ++b) s += partial[b * 128 + tid];
  v[tid] = s / Nf;
  __syncthreads();
  float acc = fb0[tid];
  for (int c = 0; c < 128; ++c) acc += v[c] * fW0[c * 128 + tid];
  h[tid] = silu(acc);
  __syncthreads();
  acc = fb1[tid];
  for (int c = 0; c < 128; ++c) acc += h[c] * fW1[c * 128 + tid];
  __syncthreads();
  v[tid] = silu(acc);
  __syncthreads();
  red[tid] = v[tid] * fW2[tid];
  __syncthreads();
  for (int st = 64; st > 0; st >>= 1) {
    if (tid < st) red[tid] += red[tid + st];
    __syncthreads();
  }
  if (tid == 0) out[0] = red[0] + fb2[0];
}

// ---------------- launch ----------------
extern "C" void kernel_launch(void* const* d_in, const int* in_sizes, int n_in,
                              void* d_out, int out_size, void* d_ws, size_t ws_size,
                              hipStream_t stream) {
  const float* pos = (const float*)d_in[0];
  const int* node_type = (const int*)d_in[1];
  const int* src = (const int*)d_in[2];
  const int* dst = (const int*)d_in[3];
  const int* t_src = (const int*)d_in[4];
  const int* t_dst = (const int*)d_in[5];
  const float* emb = (const float*)d_in[6];
  const float* eW = (const float*)d_in[7];
  const float* eB = (const float*)d_in[8];
  const float* taW = (const float*)d_in[9];
  const float* taB = (const float*)d_in[10];
  const float* tbW = (const float*)d_in[11];
  const float* tbG = (const float*)d_in[12];
  const float* W0 = (const float*)d_in[13]; const float* B0 = (const float*)d_in[14];
  const float* W1 = (const float*)d_in[15]; const float* B1 = (const float*)d_in[16];
  const float* W2 = (const float*)d_in[17]; const float* B2 = (const float*)d_in[18];
  const float* G0 = (const float*)d_in[19]; const float* Gb0 = (const float*)d_in[20];
  const float* G1 = (const float*)d_in[21]; const float* Gb1 = (const float*)d_in[22];
  const float* G2 = (const float*)d_in[23]; const float* Gb2 = (const float*)d_in[24];
  const float* WT = (const float*)d_in[25];
  const float* fW0 = (const float*)d_in[26]; const float* fb0 = (const float*)d_in[27];
  const float* fW1 = (const float*)d_in[28]; const float* fb1 = (const float*)d_in[29];
  const float* fW2 = (const float*)d_in[30]; const float* fb2 = (const float*)d_in[31];

  const int N = in_sizes[1];
  const int E = in_sizes[2];
  const int T = in_sizes[4];

  char* p = (char*)d_ws;
  auto alloc = [&](size_t bytes) -> char* {
    char* r = p;
    p += (bytes + 255) & ~(size_t)255;
    return r;
  };
  float* nf    = (float*)alloc((size_t)N * 128 * 4);
  float* ef    = (float*)alloc((size_t)E * 128 * 4);
  float* mbuf  = (float*)alloc((size_t)E * 128 * 4);
  float* rbf   = (float*)alloc((size_t)E * 9 * 4);
  float* bvec  = (float*)alloc((size_t)E * 3 * 4);
  float* bdist = (float*)alloc((size_t)E * 4);
  float* cut3  = (float*)alloc((size_t)E * 4);
  float* stbp  = (float*)alloc((size_t)T * 9 * 4);
  int*   sa    = (int*)alloc((size_t)T * 4);
  float* atoms = (float*)alloc((size_t)N * 9 * 4);
  float* part  = (float*)alloc((size_t)64 * 128 * 4);
  int* cnt_all = (int*)alloc((size_t)(E + N) * 4);
  int* cnt_e = cnt_all, *cnt_n = cnt_all + E;
  int* incl_e = (int*)alloc((size_t)E * 4);
  int* incl_n = (int*)alloc((size_t)N * 4);
  int* off_e  = (int*)alloc((size_t)E * 4);
  int* off_n  = (int*)alloc((size_t)N * 4);
  int* cur_e  = (int*)alloc((size_t)E * 4);
  int* cur_n  = (int*)alloc((size_t)N * 4);
  int* invp   = (int*)alloc((size_t)E * 4);
  int* bsum_e = (int*)alloc((size_t)1024 * 4);
  int* bsum_n = (int*)alloc((size_t)1024 * 4);
  short* pW0s = (short*)alloc((size_t)6 * 384 * 128 * 2);
  short* pG0s = (short*)alloc((size_t)6 * 384 * 128 * 2);
  short* pW1s = (short*)alloc((size_t)6 * 128 * 128 * 2);
  short* pG1s = (short*)alloc((size_t)6 * 128 * 128 * 2);
  short* pW2s = (short*)alloc((size_t)6 * 128 * 128 * 2);
  short* pG2s = (short*)alloc((size_t)6 * 128 * 128 * 2);
  short* ptbWs = (short*)alloc((size_t)3 * 4096 * 2);
  short* ptbGs = (short*)alloc((size_t)3 * 4096 * 2);
  (void)ws_size; (void)n_in; (void)out_size;

  const int ebk = (E + 255) / 256, nbk = (N + 255) / 256;

  pack_all_kernel<<<492, 256, 0, stream>>>(W0, G0, W1, G1, W2, G2, tbW, tbG,
                                           pW0s, pG0s, pW1s, pG1s, pW2s, pG2s, ptbWs, ptbGs);
  hipMemsetAsync(cnt_all, 0, (size_t)(E + N) * 4, stream);
  {
    int g1 = N * 128; if (E > g1) g1 = E; if (T > g1) g1 = T;
    setup1_kernel<<<(g1 + 255) / 256, 256, 0, stream>>>(
        node_type, emb, nf, N, pos, src, dst, bvec, bdist, rbf, cut3, E, t_src, cnt_e, cnt_n, T);
  }
  {
    int g2 = E * 128; int g2b = (ebk + nbk) * 256; if (g2b > g2) g2 = g2b;
    if (N * 9 > g2) g2 = N * 9;
    setup2_kernel<<<(g2 + 255) / 256, 256, 0, stream>>>(
        rbf, eW, eB, ef, E, cnt_e, incl_e, bsum_e, ebk, cnt_n, incl_n, bsum_n, nbk, N,
        nf, taW, taB, atoms);
  }
  scan_top2_kernel<<<2, 1024, 0, stream>>>(bsum_e, ebk, bsum_n, nbk);
  fin2_kernel<<<ebk + nbk, 256, 0, stream>>>(cnt_e, incl_e, bsum_e, ebk, off_e, cur_e, E,
                                             cnt_n, incl_n, bsum_n, off_n, cur_n, N);
  {
    int g3 = T > E ? T : E;
    build_kernel<<<(g3 + 255) / 256, 256, 0, stream>>>(t_src, t_dst, dst, bvec, bdist, rbf,
                                                       cut3, cur_e, stbp, sa, T, cur_n, invp, E);
  }

  const int gblocks = (E + TE - 1) / TE;
  for (int k = 0; k < 3; ++k) {
    size_t u0 = (size_t)(k * 2 + 0), u1 = u0 + 1;
    gmlp_fused<<<gblocks, 512, 0, stream>>>(
        nf, ef, rbf, src, dst, stbp, sa, off_e, cnt_e, atoms, invp,
        ptbWs + (size_t)k * 4096, ptbGs + (size_t)k * 4096,
        pW0s + u0 * 384 * 128, pG0s + u0 * 384 * 128, pW1s + u0 * 128 * 128,
        pG1s + u0 * 128 * 128, pW2s + u0 * 128 * 128, pG2s + u0 * 128 * 128,
        B0 + u0 * 128, Gb0 + u0 * 128, B1 + u0 * 128, Gb1 + u0 * 128, B2 + u0 * 128,
        Gb2 + u0 * 128, WT + u0 * 9 * 128,
        pW0s + u1 * 384 * 128, pG0s + u1 * 384 * 128, pW1s + u1 * 128 * 128,
        pG1s + u1 * 128 * 128, pW2s + u1 * 128 * 128, pG2s + u1 * 128 * 128,
        B0 + u1 * 128, Gb0 + u1 * 128, B1 + u1 * 128, Gb1 + u1 * 128, B2 + u1 * 128,
        Gb2 + u1 * 128, WT + u1 * 9 * 128,
        mbuf, E, k < 2 ? 1 : 0);
    int nk = k < 2 ? k + 1 : 0;
    node_gather_kernel<<<(N + 1) / 2, 256, 0, stream>>>(
        nf, mbuf, off_n, cnt_n, taW + (size_t)nk * 128 * 9, taB + (size_t)nk * 9,
        atoms, N, k < 2 ? 1 : 0);
  }

  int nchunks = (N + 255) / 256;
  mean_kernel<<<nchunks, 256, 0, stream>>>(nf, part, N);
  final_kernel<<<1, 128, 0, stream>>>(part, nchunks, (float)N, fW0, fb0, fW1, fb1, fW2, fb2,
                                      (float*)d_out);
}

// Round 9
// 516.307 us; speedup vs baseline: 8.2810x; 1.0098x over previous
//
#include <hip/hip_runtime.h>
#include <stdint.h>

typedef __attribute__((ext_vector_type(8))) short bf16x8;
typedef __attribute__((ext_vector_type(4))) float f32x4;
typedef __attribute__((ext_vector_type(4))) uint32_t u32x4;

#define XSS 392   // xs row stride (shorts)
#define HSS 144   // hs/gs row stride (shorts) + XOR swizzle: measured-best combo (r7)
#define TE 32

// ---------------- helpers ----------------
__device__ __forceinline__ float sigm(float x) { return __fdividef(1.0f, 1.0f + __expf(-x)); }
__device__ __forceinline__ float silu(float x) { return __fdividef(x, 1.0f + __expf(-x)); }
__device__ __forceinline__ short f2bf(float f) {  // RNE f32->bf16 (pack path)
  uint32_t u = __float_as_uint(f);
  u = (u + 0x7fffu + ((u >> 16) & 1u)) >> 16;
  return (short)u;
}
__device__ __forceinline__ uint32_t cvt2(float lo, float hi) {
  uint32_t d;
  asm("v_cvt_pk_bf16_f32 %0, %1, %2" : "=v"(d) : "v"(lo), "v"(hi));
  return d;
}
__device__ __forceinline__ short f2bf1(float f) { return (short)cvt2(f, f); }

__device__ __forceinline__ float jl_eval(int l, float x) {
  float s, c;
  sincosf(x, &s, &c);
  float ix = 1.0f / x, ix2 = ix * ix;
  if (l == 0) return s * ix;
  if (l == 1) return s * ix2 - c * ix;
  if (l == 2) return (3.0f * ix2 * ix - ix) * s - 3.0f * ix2 * c;
  return (15.0f * ix2 * ix2 - 6.0f * ix2) * s - (15.0f * ix2 * ix - ix) * c;
}

// ---------------- setup1: node_init + edge_geom + CSR counts ----------------
__global__ void setup1_kernel(const int* __restrict__ ntb, const float* __restrict__ emb,
                              float* __restrict__ nf, int N,
                              const float* __restrict__ pos, const int* __restrict__ src,
                              const int* __restrict__ dst, float* __restrict__ bvec,
                              float* __restrict__ bdist, float* __restrict__ rbf,
                              float* __restrict__ cut3, int E,
                              const int* __restrict__ t_src, int* __restrict__ cnt_e,
                              int* __restrict__ cnt_n, int T) {
  int i = blockIdx.x * 256 + threadIdx.x;
  if (i < N * 128) {
    int n = i >> 7, c = i & 127;
    nf[i] = emb[ntb[n] * 128 + c];
  }
  if (i < E) {
    int s = src[i], d = dst[i];
    float dx = pos[d * 3 + 0] - pos[s * 3 + 0];
    float dy = pos[d * 3 + 1] - pos[s * 3 + 1];
    float dz = pos[d * 3 + 2] - pos[s * 3 + 2];
    float r = sqrtf(dx * dx + dy * dy + dz * dz + 1e-12f);
    bvec[i * 3 + 0] = dx; bvec[i * 3 + 1] = dy; bvec[i * 3 + 2] = dz;
    bdist[i] = r;
    const float roots[3][3] = {
        {3.141592653589793f, 6.283185307179586f, 9.42477796076938f},
        {4.493409457909064f, 7.725251836937707f, 10.904121659428899f},
        {5.763459196894550f, 9.095011330476355f, 12.322940970566582f}};
#pragma unroll
    for (int l = 0; l < 3; ++l) {
#pragma unroll
      for (int n = 0; n < 3; ++n) {
        float root = roots[l][n];
        float x = r * (root * 0.2f);
        float norm = fabsf(jl_eval(l + 1, root));
        rbf[i * 9 + l * 3 + n] = jl_eval(l, x) * (0.12649110640673518f / norm);
      }
    }
    float xx = r * 0.25f;
    float x3 = xx * xx * xx;
    cut3[i] = 1.0f - 6.0f * x3 * xx * xx + 15.0f * x3 * xx - 10.0f * x3;
    atomicAdd(&cnt_n[d], 1);
  }
  if (i < T) atomicAdd(&cnt_e[t_src[i]], 1);
}

// ---------------- setup2: block scans + edge_emb + atoms(k=0) ----------------
__device__ void scan_chunk(const int* __restrict__ in, int* __restrict__ incl,
                           int* __restrict__ bsum, int L, int b) {
  __shared__ int sm[256];
  int i = b * 256 + threadIdx.x;
  int v = i < L ? in[i] : 0;
  sm[threadIdx.x] = v;
  __syncthreads();
  for (int st = 1; st < 256; st <<= 1) {
    int t = threadIdx.x >= st ? sm[threadIdx.x - st] : 0;
    __syncthreads();
    sm[threadIdx.x] += t;
    __syncthreads();
  }
  if (i < L) incl[i] = sm[threadIdx.x];
  if (threadIdx.x == 255) bsum[b] = sm[255];
}

__global__ void setup2_kernel(const float* __restrict__ rbf, const float* __restrict__ eW,
                              const float* __restrict__ eB, float* __restrict__ ef, int E,
                              const int* __restrict__ cnt_e, int* __restrict__ incl_e,
                              int* __restrict__ bsum_e, int ebk,
                              const int* __restrict__ cnt_n, int* __restrict__ incl_n,
                              int* __restrict__ bsum_n, int nbk, int N,
                              const float* __restrict__ nf, const float* __restrict__ taW,
                              const float* __restrict__ taB, float* __restrict__ atoms) {
  int b = blockIdx.x;
  if (b < ebk) scan_chunk(cnt_e, incl_e, bsum_e, E, b);
  else if (b < ebk + nbk) scan_chunk(cnt_n, incl_n, bsum_n, N, b - ebk);
  int i = b * 256 + threadIdx.x;
  if (i < E * 128) {
    int e = i >> 7, c = i & 127;
    float acc = eB[c];
#pragma unroll
    for (int d = 0; d < 9; ++d) acc += rbf[e * 9 + d] * eW[d * 128 + c];
    ef[i] = silu(acc);
  }
  if (i < N * 9) {
    int n = i / 9, d = i - n * 9;
    float acc = taB[d];
    for (int c = 0; c < 128; ++c) acc += nf[n * 128 + c] * taW[c * 9 + d];
    atoms[i] = sigm(acc);
  }
}

__global__ void scan_top2_kernel(int* __restrict__ bsum_e, int ne, int* __restrict__ bsum_n,
                                 int nn) {
  __shared__ int sm[1024];
  int* bs = blockIdx.x == 0 ? bsum_e : bsum_n;
  int nb = blockIdx.x == 0 ? ne : nn;
  int tid = threadIdx.x;
  int orig = tid < nb ? bs[tid] : 0;
  sm[tid] = orig;
  __syncthreads();
  for (int st = 1; st < 1024; st <<= 1) {
    int t = tid >= st ? sm[tid - st] : 0;
    __syncthreads();
    sm[tid] += t;
    __syncthreads();
  }
  if (tid < nb) bs[tid] = sm[tid] - orig;
}

__global__ void fin2_kernel(const int* __restrict__ cnt_e, const int* __restrict__ incl_e,
                            const int* __restrict__ bsum_e, int ebk, int* __restrict__ off_e,
                            int* __restrict__ cur_e, int E, const int* __restrict__ cnt_n,
                            const int* __restrict__ incl_n, const int* __restrict__ bsum_n,
                            int* __restrict__ off_n, int* __restrict__ cur_n, int N) {
  int b = blockIdx.x;
  if (b < ebk) {
    int i = b * 256 + threadIdx.x;
    if (i < E) {
      int o = incl_e[i] - cnt_e[i] + bsum_e[b];
      off_e[i] = o; cur_e[i] = o;
    }
  } else {
    int bb = b - ebk;
    int i = bb * 256 + threadIdx.x;
    if (i < N) {
      int o = incl_n[i] - cnt_n[i] + bsum_n[bb];
      off_n[i] = o; cur_n[i] = o;
    }
  }
}

// build: triplet precompute into CSR-sorted slots + inverse dst-permutation
__global__ void build_kernel(const int* __restrict__ t_src, const int* __restrict__ t_dst,
                             const int* __restrict__ dst, const float* __restrict__ bvec,
                             const float* __restrict__ bdist, const float* __restrict__ rbf,
                             const float* __restrict__ cut3, int* __restrict__ cur_e,
                             float* __restrict__ stbp, int* __restrict__ sa, int T,
                             int* __restrict__ cur_n, int* __restrict__ invp, int E) {
  int t = blockIdx.x * 256 + threadIdx.x;
  if (t < T) {
    int i = t_src[t], j = t_dst[t];
    float ax = bvec[i * 3], ay = bvec[i * 3 + 1], az = bvec[i * 3 + 2];
    float bx = bvec[j * 3], by = bvec[j * 3 + 1], bz = bvec[j * 3 + 2];
    float ct = (ax * bx + ay * by + az * bz) / (bdist[i] * bdist[j]);
    float tw = cut3[i] * cut3[j];
    float sh[3];
    sh[0] = 0.28209479177387814f * tw;
    sh[1] = 0.4886025119029199f * ct * tw;
    sh[2] = 0.31539156525252005f * (3.0f * ct * ct - 1.0f) * tw;
    int pos = atomicAdd(&cur_e[i], 1);
#pragma unroll
    for (int l = 0; l < 3; ++l)
#pragma unroll
      for (int n = 0; n < 3; ++n)
        stbp[(size_t)pos * 9 + l * 3 + n] = rbf[j * 9 + l * 3 + n] * sh[l];
    sa[pos] = dst[j];
  }
  if (t < E) {
    int pos = atomicAdd(&cur_n[dst[t]], 1);
    invp[t] = pos;
  }
}

// ---------------- weight packing (gmlp + tb + WT, one launch) ----------------
__device__ void pack_one(const float* __restrict__ Wf, short* __restrict__ Wp, int K, int rr) {
  int per = 8 * (K / 32) * 64;
  int u = rr / per, r2 = rr - u * per;
  int lane = r2 & 63, tile = r2 >> 6;
  int kt = tile % (K / 32), nt = tile / (K / 32);
  int n = nt * 16 + (lane & 15);
  int k0 = kt * 32 + (lane >> 4) * 8;
  const float* s = Wf + (size_t)u * K * 128;
  bf16x8 v;
#pragma unroll
  for (int e = 0; e < 8; ++e) v[e] = f2bf(s[(size_t)(k0 + e) * 128 + n]);
  *(bf16x8*)(Wp + (size_t)u * K * 128 + (size_t)tile * 512 + lane * 8) = v;
}

// K=9 -> 32 zero-padded pack (tb weights, WT): per unit 8 tiles x 64 lanes
__device__ void pack_pad9(const float* __restrict__ s, short* __restrict__ dp9, int l2) {
  int lane = l2 & 63, tile = l2 >> 6;
  int n = tile * 16 + (lane & 15);
  int k0 = (lane >> 4) * 8;
  bf16x8 v;
#pragma unroll
  for (int e = 0; e < 8; ++e)
    v[e] = (k0 + e < 9) ? f2bf(s[(size_t)(k0 + e) * 128 + n]) : (short)0;
  *(bf16x8*)(dp9 + tile * 512 + lane * 8) = v;
}

__global__ void pack_all_kernel(const float* __restrict__ W0, const float* __restrict__ G0,
                                const float* __restrict__ W1, const float* __restrict__ G1,
                                const float* __restrict__ W2, const float* __restrict__ G2,
                                const float* __restrict__ tbW, const float* __restrict__ tbG,
                                const float* __restrict__ WT,
                                short* __restrict__ pW0, short* __restrict__ pG0,
                                short* __restrict__ pW1, short* __restrict__ pG1,
                                short* __restrict__ pW2, short* __restrict__ pG2,
                                short* __restrict__ ptbW, short* __restrict__ ptbG,
                                short* __restrict__ pWT) {
  int idx = blockIdx.x * 256 + threadIdx.x;
  const int t384 = 6 * 8 * 12 * 64, t128 = 6 * 8 * 4 * 64;
  if (idx < t384) { pack_one(W0, pW0, 384, idx); return; }
  if (idx < 2 * t384) { pack_one(G0, pG0, 384, idx - t384); return; }
  int j = idx - 2 * t384;
  if (j < t128) { pack_one(W1, pW1, 128, j); return; }
  if (j < 2 * t128) { pack_one(G1, pG1, 128, j - t128); return; }
  if (j < 3 * t128) { pack_one(W2, pW2, 128, j - 2 * t128); return; }
  if (j < 4 * t128) { pack_one(G2, pG2, 128, j - 3 * t128); return; }
  j -= 4 * t128;
  if (j < 3072) {  // tb weights: 3 k-blocks x {W,G} x 512
    int kb = j >> 10;
    int w2 = (j >> 9) & 1;
    int l2 = j & 511;
    const float* s = (w2 ? tbG : tbW) + (size_t)kb * 9 * 128;
    short* dp = (w2 ? ptbG : ptbW) + (size_t)kb * 4096;
    pack_pad9(s, dp, l2);
    return;
  }
  j -= 3072;
  if (j < 3072) {  // WT: 6 units x 512
    int u = j >> 9;
    pack_pad9(WT + (size_t)u * 9 * 128, pWT + (size_t)u * 4096, j & 511);
  }
}

// ---------------- fused gated-MLP on MFMA ----------------
__device__ __forceinline__ f32x4 mfma16(bf16x8 a, bf16x8 b, f32x4 c) {
  return __builtin_amdgcn_mfma_f32_16x16x32_bf16(a, b, c, 0, 0, 0);
}

// hs/gs element (row,col) stored at col ^ (((row>>2)&3)<<4)
__device__ __forceinline__ void store_hg(short* hsb, short* gsb, int wave, int lane,
                                         const f32x4 (&aW)[2], const f32x4 (&aG)[2]) {
  const int lrow = lane & 15, lk = lane >> 4;
  const int colx = (wave * 16 + lrow) ^ (lk << 4);
#pragma unroll
  for (int mt = 0; mt < 2; ++mt)
#pragma unroll
    for (int rg = 0; rg < 4; ++rg) {
      int row = mt * 16 + lk * 4 + rg;
      hsb[row * HSS + colx] = f2bf1(silu(aW[mt][rg]));
      gsb[row * HSS + colx] = f2bf1(silu(aG[mt][rg]));
    }
}

__device__ __forceinline__ void layer128w(const short* hin, const short* gin,
                                          const short* __restrict__ pW,
                                          const short* __restrict__ pG,
                                          const float* __restrict__ Bh,
                                          const float* __restrict__ Bg, int wave, int lane,
                                          f32x4 (&aW)[2], f32x4 (&aG)[2]) {
  const int lrow = lane & 15, lk = lane >> 4;
  const int s0 = (lrow >> 2) & 3;
  float bw = Bh[wave * 16 + lrow], bg = Bg[wave * 16 + lrow];
  aW[0] = {bw, bw, bw, bw}; aW[1] = aW[0];
  aG[0] = {bg, bg, bg, bg}; aG[1] = aG[0];
#pragma unroll
  for (int kt = 0; kt < 4; ++kt) {
    int aoff = (kt * 32 + lk * 8) ^ (s0 << 4);
    bf16x8 ah0 = *(const bf16x8*)(hin + (size_t)lrow * HSS + aoff);
    bf16x8 ah1 = *(const bf16x8*)(hin + (size_t)(16 + lrow) * HSS + aoff);
    bf16x8 ag0 = *(const bf16x8*)(gin + (size_t)lrow * HSS + aoff);
    bf16x8 ag1 = *(const bf16x8*)(gin + (size_t)(16 + lrow) * HSS + aoff);
    bf16x8 bw8 = *(const bf16x8*)(pW + (size_t)(wave * 4 + kt) * 512 + lane * 8);
    bf16x8 bg8 = *(const bf16x8*)(pG + (size_t)(wave * 4 + kt) * 512 + lane * 8);
    aW[0] = mfma16(ah0, bw8, aW[0]);
    aW[1] = mfma16(ah1, bw8, aW[1]);
    aG[0] = mfma16(ag0, bg8, aG[0]);
    aG[1] = mfma16(ag1, bg8, aG[1]);
  }
}

__device__ __forceinline__ void run_chain(
    const short* xsb, short* hsb, short* gsb,
    const short* __restrict__ pW0, const short* __restrict__ pG0,
    const short* __restrict__ pW1, const short* __restrict__ pG1,
    const short* __restrict__ pW2, const short* __restrict__ pG2,
    const float* __restrict__ B0, const float* __restrict__ Gb0,
    const float* __restrict__ B1, const float* __restrict__ Gb1,
    const float* __restrict__ B2, const float* __restrict__ Gb2,
    int wave, int lane, f32x4 (&aW)[2], f32x4 (&aG)[2]) {
  const int lrow = lane & 15, lk = lane >> 4;
  const int s0 = (lrow >> 2) & 3;
  {
    float bw = B0[wave * 16 + lrow], bg = Gb0[wave * 16 + lrow];
    aW[0] = {bw, bw, bw, bw}; aW[1] = aW[0];
    aG[0] = {bg, bg, bg, bg}; aG[1] = aG[0];
  }
#pragma unroll
  for (int kt = 0; kt < 12; ++kt) {
    int al = kt * 32 + lk * 8;
    int aoff = (al < 256) ? al : (256 + ((al - 256) ^ (s0 << 4)));  // ef region swizzled
    bf16x8 a0 = *(const bf16x8*)(xsb + (size_t)lrow * XSS + aoff);
    bf16x8 a1 = *(const bf16x8*)(xsb + (size_t)(16 + lrow) * XSS + aoff);
    bf16x8 bw8 = *(const bf16x8*)(pW0 + (size_t)(wave * 12 + kt) * 512 + lane * 8);
    bf16x8 bg8 = *(const bf16x8*)(pG0 + (size_t)(wave * 12 + kt) * 512 + lane * 8);
    aW[0] = mfma16(a0, bw8, aW[0]);
    aW[1] = mfma16(a1, bw8, aW[1]);
    aG[0] = mfma16(a0, bg8, aG[0]);
    aG[1] = mfma16(a1, bg8, aG[1]);
  }
  store_hg(hsb, gsb, wave, lane, aW, aG);
  __syncthreads();
  layer128w(hsb, gsb, pW1, pG1, B1, Gb1, wave, lane, aW, aG);
  __syncthreads();
  store_hg(hsb, gsb, wave, lane, aW, aG);
  __syncthreads();
  layer128w(hsb, gsb, pW2, pG2, B2, Gb2, wave, lane, aW, aG);
}

__global__ __launch_bounds__(512, 6) void gmlp_fused(
    const float* __restrict__ nf, float* __restrict__ ef, const float* __restrict__ rbf,
    const int* __restrict__ src, const int* __restrict__ dst,
    const float* __restrict__ stbp, const int* __restrict__ sa,
    const int* __restrict__ off_e, const int* __restrict__ cnt_e,
    const float* __restrict__ atoms, const int* __restrict__ invp,
    const short* __restrict__ ptbW, const short* __restrict__ ptbG,
    const short* __restrict__ pW0a, const short* __restrict__ pG0a,
    const short* __restrict__ pW1a, const short* __restrict__ pG1a,
    const short* __restrict__ pW2a, const short* __restrict__ pG2a,
    const float* __restrict__ B0a, const float* __restrict__ Gb0a,
    const float* __restrict__ B1a, const float* __restrict__ Gb1a,
    const float* __restrict__ B2a, const float* __restrict__ Gb2a,
    const short* __restrict__ pWTa,
    const short* __restrict__ pW0b, const short* __restrict__ pG0b,
    const short* __restrict__ pW1b, const short* __restrict__ pG1b,
    const short* __restrict__ pW2b, const short* __restrict__ pG2b,
    const float* __restrict__ B0b, const float* __restrict__ Gb0b,
    const float* __restrict__ B1b, const float* __restrict__ Gb1b,
    const float* __restrict__ B2b, const float* __restrict__ Gb2b,
    const short* __restrict__ pWTb,
    float* __restrict__ mbuf, int E, int writeEf) {
  __shared__ __align__(16) short xs[32][XSS];
  __shared__ __align__(16) short hs[32 * HSS];
  __shared__ __align__(16) short gs[32 * HSS];
  __shared__ __align__(16) short nbl[32][40];  // K=32-padded nb, bf16
  __shared__ __align__(16) short rbl[32][40];  // K=32-padded rbf, bf16
  __shared__ int invs[32];
  const int tid = threadIdx.x;
  const int e0 = blockIdx.x * TE;
  const int r = tid >> 4, q = tid & 15;
  int eg = e0 + r; if (eg >= E) eg = E - 1;

  // ---- fused nb_reduce -> bf16 nbl (zero-pad K 9..31) ----
  {
    float acc = 0.f;
    if (q < 9) {
      int o = off_e[eg], c = cnt_e[eg];
      for (int pp = o; pp < o + c; ++pp)
        acc += stbp[(size_t)pp * 9 + q] * atoms[(size_t)sa[pp] * 9 + q];
    }
    nbl[r][q] = (q < 9) ? f2bf1(acc) : (short)0;
    nbl[r][q + 16] = 0;
  }
  // ---- gather nf segments as bf16; rbf -> rbl bf16 ----
  {
    const float* sp0 = nf + (size_t)src[eg] * 128;
    const float* sp1 = nf + (size_t)dst[eg] * 128;
#pragma unroll
    for (int seg = 0; seg < 2; ++seg) {
      const float* sp = seg == 0 ? sp0 : sp1;
      float4 f0 = *(const float4*)(sp + q * 8);
      float4 f1 = *(const float4*)(sp + q * 8 + 4);
      u32x4 v = {cvt2(f0.x, f0.y), cvt2(f0.z, f0.w), cvt2(f1.x, f1.y), cvt2(f1.z, f1.w)};
      *(u32x4*)&xs[r][seg * 128 + q * 8] = v;
    }
    for (int idx = tid; idx < 32 * 32; idx += 512) {
      int rr = idx >> 5, d = idx & 31;
      int ee = e0 + rr; if (ee >= E) ee = E - 1;
      rbl[rr][d] = (d < 9) ? f2bf1(rbf[ee * 9 + d]) : (short)0;
    }
    if (tid < 32) {
      int ee = e0 + tid; if (ee >= E) ee = E - 1;
      invs[tid] = invp[ee];
    }
  }
  __syncthreads();

  const int wave = tid >> 6;
  const int lane = tid & 63;
  const int lrow = lane & 15, lk = lane >> 4;
  const int col = wave * 16 + lrow;
  f32x4 aW[2], aG[2];
  float efb[2][4];  // ef + tb_update base, carried in registers through chain 0

  // ---- tb_update via MFMA: ef_tb = ef + silu(nb@W)*sigm(nb@Wg) ----
  {
    bf16x8 ta0 = *(const bf16x8*)&nbl[lrow][lk * 8];
    bf16x8 ta1 = *(const bf16x8*)&nbl[16 + lrow][lk * 8];
    bf16x8 tbw = *(const bf16x8*)(ptbW + wave * 512 + lane * 8);
    bf16x8 tbg = *(const bf16x8*)(ptbG + wave * 512 + lane * 8);
    f32x4 z = {0.f, 0.f, 0.f, 0.f};
    f32x4 tW0 = mfma16(ta0, tbw, z), tW1 = mfma16(ta1, tbw, z);
    f32x4 tG0 = mfma16(ta0, tbg, z), tG1 = mfma16(ta1, tbg, z);
#pragma unroll
    for (int mt = 0; mt < 2; ++mt)
#pragma unroll
      for (int rg = 0; rg < 4; ++rg) {
        int row = mt * 16 + lk * 4 + rg;
        int ec = e0 + row; if (ec >= E) ec = E - 1;
        float tw = mt == 0 ? tW0[rg] : tW1[rg];
        float tg = mt == 0 ? tG0[rg] : tG1[rg];
        float base = ef[(size_t)ec * 128 + col] + silu(tw) * sigm(tg);
        efb[mt][rg] = base;
        xs[row][256 + (col ^ (lk << 4))] = f2bf1(base);
      }
  }
  __syncthreads();

  // ---- chain 0: edge update ----
  run_chain(&xs[0][0], hs, gs, pW0a, pG0a, pW1a, pG1a, pW2a, pG2a,
            B0a, Gb0a, B1a, Gb1a, B2a, Gb2a, wave, lane, aW, aG);
  {
    // wv = rbf @ wt via MFMA
    bf16x8 ra0 = *(const bf16x8*)&rbl[lrow][lk * 8];
    bf16x8 ra1 = *(const bf16x8*)&rbl[16 + lrow][lk * 8];
    bf16x8 wtb = *(const bf16x8*)(pWTa + wave * 512 + lane * 8);
    f32x4 z = {0.f, 0.f, 0.f, 0.f};
    f32x4 wv0 = mfma16(ra0, wtb, z), wv1 = mfma16(ra1, wtb, z);
    const int cs = 256 + (col ^ (lk << 4));
#pragma unroll
    for (int mt = 0; mt < 2; ++mt)
#pragma unroll
      for (int rg = 0; rg < 4; ++rg) {
        int row = mt * 16 + lk * 4 + rg;
        int e = e0 + row;
        float wv = mt == 0 ? wv0[rg] : wv1[rg];
        float v = silu(aW[mt][rg]) * sigm(aG[mt][rg]) * wv;
        float nv = efb[mt][rg] + v;
        if (e < E && writeEf) ef[(size_t)e * 128 + col] = nv;
        xs[row][cs] = f2bf1(nv);
      }
  }
  __syncthreads();

  // ---- chain 1: node update ----
  run_chain(&xs[0][0], hs, gs, pW0b, pG0b, pW1b, pG1b, pW2b, pG2b,
            B0b, Gb0b, B1b, Gb1b, B2b, Gb2b, wave, lane, aW, aG);
  {
    bf16x8 ra0 = *(const bf16x8*)&rbl[lrow][lk * 8];
    bf16x8 ra1 = *(const bf16x8*)&rbl[16 + lrow][lk * 8];
    bf16x8 wtb = *(const bf16x8*)(pWTb + wave * 512 + lane * 8);
    f32x4 z = {0.f, 0.f, 0.f, 0.f};
    f32x4 wv0 = mfma16(ra0, wtb, z), wv1 = mfma16(ra1, wtb, z);
#pragma unroll
    for (int mt = 0; mt < 2; ++mt)
#pragma unroll
      for (int rg = 0; rg < 4; ++rg) {
        int row = mt * 16 + lk * 4 + rg;
        int e = e0 + row;
        float wv = mt == 0 ? wv0[rg] : wv1[rg];
        float v = silu(aW[mt][rg]) * sigm(aG[mt][rg]) * wv;
        if (e < E) mbuf[(size_t)invs[row] * 128 + col] = v;  // dst-sorted position
      }
  }
}

// ---- node gather (sequential, dst-sorted mbuf) + fused atoms for next iter ----
__global__ void node_gather_kernel(float* __restrict__ nf, const float* __restrict__ mbuf,
                                   const int* __restrict__ off_n, const int* __restrict__ cnt_n,
                                   const float* __restrict__ taW, const float* __restrict__ taB,
                                   float* __restrict__ atoms, int N, int doAtoms) {
  __shared__ float sm[2][128];
  int half = threadIdx.x >> 7, c = threadIdx.x & 127;
  int n = blockIdx.x * 2 + half;
  float v = 0.f;
  if (n < N) {
    int o = off_n[n], cnt = cnt_n[n];
    float acc = 0.f;
    for (int p = 0; p < cnt; ++p) acc += mbuf[(size_t)(o + p) * 128 + c];
    v = nf[(size_t)n * 128 + c] + acc;
    nf[(size_t)n * 128 + c] = v;
  }
  if (doAtoms) {
    sm[half][c] = v;
    __syncthreads();
    if (n < N && c < 9) {
      float a = taB[c];
      for (int cc = 0; cc < 128; ++cc) a += sm[half][cc] * taW[cc * 9 + c];
      atoms[n * 9 + c] = sigm(a);
    }
  }
}

// ---------------- readout ----------------
__global__ void mean_kernel(const float* __restrict__ nf, float* __restrict__ partial, int N) {
  __shared__ float sm[256];
  int n0 = blockIdx.x * 256;
  int col = threadIdx.x & 127, half = threadIdx.x >> 7;
  int nend = n0 + 256 < N ? n0 + 256 : N;
  float s = 0.f;
  for (int n = n0 + half; n < nend; n += 2) s += nf[n * 128 + col];
  sm[threadIdx.x] = s;
  __syncthreads();
  if (threadIdx.x < 128)
    partial[blockIdx.x * 128 + threadIdx.x] = sm[threadIdx.x] + sm[threadIdx.x + 128];
}

__global__ void final_kernel(const float* __restrict__ partial, int nchunks, float Nf,
                             const float* __restrict__ fW0, const float* __restrict__ fb0,
                             const float* __restrict__ fW1, const float* __restrict__ fb1,
                             const float* __restrict__ fW2, const float* __restrict__ fb2,
                             float* __restrict__ out) {
  __shared__ float v[128], h[128], red[128];
  int tid = threadIdx.x;  // 128 threads
  float s = 0.f;
  for (int b = 0; b < nchunks; ++b) s += partial[b * 128 + tid];
  v[tid] = s / Nf;
  __syncthreads();
  float acc = fb0[tid];
  for (int c = 0; c < 128; ++c) acc += v[c] * fW0[c * 128 + tid];
  h[tid] = silu(acc);
  __syncthreads();
  acc = fb1[tid];
  for (int c = 0; c < 128; ++c) acc += h[c] * fW1[c * 128 + tid];
  __syncthreads();
  v[tid] = silu(acc);
  __syncthreads();
  red[tid] = v[tid] * fW2[tid];
  __syncthreads();
  for (int st = 64; st > 0; st >>= 1) {
    if (tid < st) red[tid] += red[tid + st];
    __syncthreads();
  }
  if (tid == 0) out[0] = red[0] + fb2[0];
}

// ---------------- launch ----------------
extern "C" void kernel_launch(void* const* d_in, const int* in_sizes, int n_in,
                              void* d_out, int out_size, void* d_ws, size_t ws_size,
                              hipStream_t stream) {
  const float* pos = (const float*)d_in[0];
  const int* node_type = (const int*)d_in[1];
  const int* src = (const int*)d_in[2];
  const int* dst = (const int*)d_in[3];
  const int* t_src = (const int*)d_in[4];
  const int* t_dst = (const int*)d_in[5];
  const float* emb = (const float*)d_in[6];
  const float* eW = (const float*)d_in[7];
  const float* eB = (const float*)d_in[8];
  const float* taW = (const float*)d_in[9];
  const float* taB = (const float*)d_in[10];
  const float* tbW = (const float*)d_in[11];
  const float* tbG = (const float*)d_in[12];
  const float* W0 = (const float*)d_in[13]; const float* B0 = (const float*)d_in[14];
  const float* W1 = (const float*)d_in[15]; const float* B1 = (const float*)d_in[16];
  const float* W2 = (const float*)d_in[17]; const float* B2 = (const float*)d_in[18];
  const float* G0 = (const float*)d_in[19]; const float* Gb0 = (const float*)d_in[20];
  const float* G1 = (const float*)d_in[21]; const float* Gb1 = (const float*)d_in[22];
  const float* G2 = (const float*)d_in[23]; const float* Gb2 = (const float*)d_in[24];
  const float* WT = (const float*)d_in[25];
  const float* fW0 = (const float*)d_in[26]; const float* fb0 = (const float*)d_in[27];
  const float* fW1 = (const float*)d_in[28]; const float* fb1 = (const float*)d_in[29];
  const float* fW2 = (const float*)d_in[30]; const float* fb2 = (const float*)d_in[31];

  const int N = in_sizes[1];
  const int E = in_sizes[2];
  const int T = in_sizes[4];

  char* p = (char*)d_ws;
  auto alloc = [&](size_t bytes) -> char* {
    char* r = p;
    p += (bytes + 255) & ~(size_t)255;
    return r;
  };
  float* nf    = (float*)alloc((size_t)N * 128 * 4);
  float* ef    = (float*)alloc((size_t)E * 128 * 4);
  float* mbuf  = (float*)alloc((size_t)E * 128 * 4);
  float* rbf   = (float*)alloc((size_t)E * 9 * 4);
  float* bvec  = (float*)alloc((size_t)E * 3 * 4);
  float* bdist = (float*)alloc((size_t)E * 4);
  float* cut3  = (float*)alloc((size_t)E * 4);
  float* stbp  = (float*)alloc((size_t)T * 9 * 4);
  int*   sa    = (int*)alloc((size_t)T * 4);
  float* atoms = (float*)alloc((size_t)N * 9 * 4);
  float* part  = (float*)alloc((size_t)64 * 128 * 4);
  int* cnt_all = (int*)alloc((size_t)(E + N) * 4);
  int* cnt_e = cnt_all, *cnt_n = cnt_all + E;
  int* incl_e = (int*)alloc((size_t)E * 4);
  int* incl_n = (int*)alloc((size_t)N * 4);
  int* off_e  = (int*)alloc((size_t)E * 4);
  int* off_n  = (int*)alloc((size_t)N * 4);
  int* cur_e  = (int*)alloc((size_t)E * 4);
  int* cur_n  = (int*)alloc((size_t)N * 4);
  int* invp   = (int*)alloc((size_t)E * 4);
  int* bsum_e = (int*)alloc((size_t)1024 * 4);
  int* bsum_n = (int*)alloc((size_t)1024 * 4);
  short* pW0s = (short*)alloc((size_t)6 * 384 * 128 * 2);
  short* pG0s = (short*)alloc((size_t)6 * 384 * 128 * 2);
  short* pW1s = (short*)alloc((size_t)6 * 128 * 128 * 2);
  short* pG1s = (short*)alloc((size_t)6 * 128 * 128 * 2);
  short* pW2s = (short*)alloc((size_t)6 * 128 * 128 * 2);
  short* pG2s = (short*)alloc((size_t)6 * 128 * 128 * 2);
  short* ptbWs = (short*)alloc((size_t)3 * 4096 * 2);
  short* ptbGs = (short*)alloc((size_t)3 * 4096 * 2);
  short* pWTs  = (short*)alloc((size_t)6 * 4096 * 2);
  (void)ws_size; (void)n_in; (void)out_size;

  const int ebk = (E + 255) / 256, nbk = (N + 255) / 256;

  pack_all_kernel<<<504, 256, 0, stream>>>(W0, G0, W1, G1, W2, G2, tbW, tbG, WT,
                                           pW0s, pG0s, pW1s, pG1s, pW2s, pG2s,
                                           ptbWs, ptbGs, pWTs);
  hipMemsetAsync(cnt_all, 0, (size_t)(E + N) * 4, stream);
  {
    int g1 = N * 128; if (E > g1) g1 = E; if (T > g1) g1 = T;
    setup1_kernel<<<(g1 + 255) / 256, 256, 0, stream>>>(
        node_type, emb, nf, N, pos, src, dst, bvec, bdist, rbf, cut3, E, t_src, cnt_e, cnt_n, T);
  }
  {
    int g2 = E * 128; int g2b = (ebk + nbk) * 256; if (g2b > g2) g2 = g2b;
    if (N * 9 > g2) g2 = N * 9;
    setup2_kernel<<<(g2 + 255) / 256, 256, 0, stream>>>(
        rbf, eW, eB, ef, E, cnt_e, incl_e, bsum_e, ebk, cnt_n, incl_n, bsum_n, nbk, N,
        nf, taW, taB, atoms);
  }
  scan_top2_kernel<<<2, 1024, 0, stream>>>(bsum_e, ebk, bsum_n, nbk);
  fin2_kernel<<<ebk + nbk, 256, 0, stream>>>(cnt_e, incl_e, bsum_e, ebk, off_e, cur_e, E,
                                             cnt_n, incl_n, bsum_n, off_n, cur_n, N);
  {
    int g3 = T > E ? T : E;
    build_kernel<<<(g3 + 255) / 256, 256, 0, stream>>>(t_src, t_dst, dst, bvec, bdist, rbf,
                                                       cut3, cur_e, stbp, sa, T, cur_n, invp, E);
  }

  const int gblocks = (E + TE - 1) / TE;
  for (int k = 0; k < 3; ++k) {
    size_t u0 = (size_t)(k * 2 + 0), u1 = u0 + 1;
    gmlp_fused<<<gblocks, 512, 0, stream>>>(
        nf, ef, rbf, src, dst, stbp, sa, off_e, cnt_e, atoms, invp,
        ptbWs + (size_t)k * 4096, ptbGs + (size_t)k * 4096,
        pW0s + u0 * 384 * 128, pG0s + u0 * 384 * 128, pW1s + u0 * 128 * 128,
        pG1s + u0 * 128 * 128, pW2s + u0 * 128 * 128, pG2s + u0 * 128 * 128,
        B0 + u0 * 128, Gb0 + u0 * 128, B1 + u0 * 128, Gb1 + u0 * 128, B2 + u0 * 128,
        Gb2 + u0 * 128, pWTs + u0 * 4096,
        pW0s + u1 * 384 * 128, pG0s + u1 * 384 * 128, pW1s + u1 * 128 * 128,
        pG1s + u1 * 128 * 128, pW2s + u1 * 128 * 128, pG2s + u1 * 128 * 128,
        B0 + u1 * 128, Gb0 + u1 * 128, B1 + u1 * 128, Gb1 + u1 * 128, B2 + u1 * 128,
        Gb2 + u1 * 128, pWTs + u1 * 4096,
        mbuf, E, k < 2 ? 1 : 0);
    int nk = k < 2 ? k + 1 : 0;
    node_gather_kernel<<<(N + 1) / 2, 256, 0, stream>>>(
        nf, mbuf, off_n, cnt_n, taW + (size_t)nk * 128 * 9, taB + (size_t)nk * 9,
        atoms, N, k < 2 ? 1 : 0);
  }

  int nchunks = (N + 255) / 256;
  mean_kernel<<<nchunks, 256, 0, stream>>>(nf, part, N);
  final_kernel<<<1, 128, 0, stream>>>(part, nchunks, (float)N, fW0, fb0, fW1, fb1, fW2, fb2,
                                      (float*)d_out);
}